// Round 7
// baseline (51623.151 us; speedup 1.0000x reference)
//
#include <hip/hip_runtime.h>
#include <math.h>

// ---------------------------------------------------------------------------
// PTB LN-LSTM stack: B=128, T=100, E=128, F=700, S=400, V=10000.
// Round 7: attack the measured bottleneck (GEMM phases ~100us each at
// 105 GB/s, ~1-3 loads in flight per wave). Changes:
//   - 512-thr blocks (2048 waves), per-wave 16x64 tiles (2x concurrency)
//   - register double-buffer of B-planes (next k-tile prefetch)
//   - x-projection hoisted: zx[t] = x_t @ W0x + b0 precomputed in parallel
//   - flag-based grid barrier (release-store + poll; no RMW contention)
// Split-precision 3-plane bf16 math (proven r4-r6) unchanged.
// ---------------------------------------------------------------------------

#define B_ 128
#define T_ 100
#define E_ 128
#define F_ 700
#define S_ 400
#define V_ 10000

#define FP_ 704    // F padded
#define SP_ 416    // S padded
#define G_  256    // mega blocks
#define TPB_ 512   // threads per mega block (8 waves)
#define NW_ (G_ * 8)

using v8s = __attribute__((ext_vector_type(8))) short;
using v4f = __attribute__((ext_vector_type(4))) float;
typedef unsigned short u16;

__device__ __forceinline__ u16 f2bf(float x) {
    unsigned int u = __float_as_uint(x);
    u += 0x7FFFu + ((u >> 16) & 1u);
    return (u16)(u >> 16);
}
__device__ __forceinline__ float bf2f(u16 h) {
    return __uint_as_float(((unsigned int)h) << 16);
}
__device__ __forceinline__ void split3f(float x, u16& h, u16& m, u16& l) {
    h = f2bf(x); float r  = x - bf2f(h);
    m = f2bf(r); float r2 = r - bf2f(m);
    l = f2bf(r2);
}
__device__ __forceinline__ float sigm(float x) { return 1.0f / (1.0f + expf(-x)); }

// ---------------------------------------------------------------------------
// Grid barrier: per-block flag lines (64B apart). Arrival = release store of
// monotonically increasing target; wave 0 polls 4 flags/lane. No RMW chain.
// ---------------------------------------------------------------------------
__device__ __forceinline__ void gbar(unsigned* flags, unsigned target) {
    __syncthreads();
    if (threadIdx.x == 0) {
        __threadfence();
        __hip_atomic_store(flags + (size_t)blockIdx.x * 16, target,
                           __ATOMIC_RELEASE, __HIP_MEMORY_SCOPE_AGENT);
    }
    if (threadIdx.x < 64) {
        #pragma unroll
        for (int j = 0; j < 4; ++j) {
            const unsigned* f = flags + (size_t)(threadIdx.x * 4 + j) * 16;
            while (__hip_atomic_load(f, __ATOMIC_ACQUIRE, __HIP_MEMORY_SCOPE_AGENT) < target)
                __builtin_amdgcn_s_sleep(2);
        }
    }
    __syncthreads();
    __threadfence();
}

// ---------------------------------------------------------------------------
// Standalone transpose+split kernels (run before mega; r5-proven, 256 thr).
// Full-coverage writes (pads -> 0): replay-safe.
// ---------------------------------------------------------------------------
__global__ __launch_bounds__(256) void wtrans3(
    const float* __restrict__ W, int K, int N,
    u16* __restrict__ WtH, u16* __restrict__ WtM, u16* __restrict__ WtL,
    int Kp, int K1, int K1pad)
{
    __shared__ float t[32][33];
    const int c0 = blockIdx.x * 32, kp0 = blockIdx.y * 32;
    const int tx = threadIdx.x & 31, ty = threadIdx.x >> 5;
    #pragma unroll
    for (int i = 0; i < 4; ++i) {
        int kpos = kp0 + ty + i * 8, c = c0 + tx;
        int k = (kpos < K1) ? kpos : (kpos >= K1pad ? K1 + (kpos - K1pad) : -1);
        t[ty + i * 8][tx] = (k >= 0 && k < K && c < N) ? W[(size_t)k * N + c] : 0.f;
    }
    __syncthreads();
    #pragma unroll
    for (int i = 0; i < 4; ++i) {
        int r = c0 + ty + i * 8;
        u16 h, m, l;
        split3f(t[tx][ty + i * 8], h, m, l);
        size_t idx = (size_t)r * Kp + kp0 + tx;
        WtH[idx] = h; WtM[idx] = m; WtL[idx] = l;
    }
}

__global__ __launch_bounds__(256) void wtrans(
    const float* __restrict__ W, int K, int N,
    u16* __restrict__ Wt, int Kpad)
{
    __shared__ float t[32][33];
    const int c0 = blockIdx.x * 32, k0 = blockIdx.y * 32;
    const int tx = threadIdx.x & 31, ty = threadIdx.x >> 5;
    #pragma unroll
    for (int i = 0; i < 4; ++i) {
        int k = k0 + ty + i * 8, c = c0 + tx;
        t[ty + i * 8][tx] = (k < K && c < N) ? W[(size_t)k * N + c] : 0.f;
    }
    __syncthreads();
    #pragma unroll
    for (int i = 0; i < 4; ++i) {
        int r = c0 + ty + i * 8;
        Wt[(size_t)r * Kpad + k0 + tx] = f2bf(t[tx][ty + i * 8]);
    }
}

// ---------------------------------------------------------------------------
// zx precompute: zx[t][b][col] = x[b,t,:] @ W0[:128,col] + b0[col]
// (3-plane split MFMA, x split in registers). Parallel over 175x100 tiles.
// ---------------------------------------------------------------------------
__global__ __launch_bounds__(512, 2) void zxpre(
    const float* __restrict__ inputs,
    const u16* __restrict__ WH, const u16* __restrict__ WM,
    const u16* __restrict__ WL,           // W0 planes, Kp=832, k<128 region
    const float* __restrict__ b0, float* __restrict__ zx)
{
    const int lane = threadIdx.x & 63, wid = threadIdx.x >> 6;
    const int lo = lane & 15, hi = lane >> 4;
    const int ntiles = 175 * 100;
    for (int i = blockIdx.x * 8 + wid; i < ntiles; i += gridDim.x * 8) {
        const int t = i / 175, ct = i % 175;
        v4f acc[8];
        #pragma unroll
        for (int m = 0; m < 8; ++m) acc[m] = (v4f)0.f;
        const size_t bb = (size_t)(ct * 16 + lo) * 832 + hi * 8;
        for (int kt = 0; kt < 4; ++kt) {
            const size_t bo = bb + kt * 32;
            v8s bh = *(const v8s*)(WH + bo);
            v8s bm = *(const v8s*)(WM + bo);
            v8s bl = *(const v8s*)(WL + bo);
            #pragma unroll
            for (int m = 0; m < 8; ++m) {
                const float* p = inputs + (size_t)(m * 16 + lo) * (T_ * E_)
                               + (size_t)t * E_ + kt * 32 + hi * 8;
                float v0[8];
                *(float4*)(v0)     = *(const float4*)(p);
                *(float4*)(v0 + 4) = *(const float4*)(p + 4);
                v8s ah, am, al;
                #pragma unroll
                for (int j = 0; j < 8; ++j) {
                    u16 H, M, L; split3f(v0[j], H, M, L);
                    ah[j] = (short)H; am[j] = (short)M; al[j] = (short)L;
                }
                acc[m] = __builtin_amdgcn_mfma_f32_16x16x32_bf16(ah, bh, acc[m], 0, 0, 0);
                acc[m] = __builtin_amdgcn_mfma_f32_16x16x32_bf16(ah, bm, acc[m], 0, 0, 0);
                acc[m] = __builtin_amdgcn_mfma_f32_16x16x32_bf16(am, bh, acc[m], 0, 0, 0);
                acc[m] = __builtin_amdgcn_mfma_f32_16x16x32_bf16(ah, bl, acc[m], 0, 0, 0);
                acc[m] = __builtin_amdgcn_mfma_f32_16x16x32_bf16(al, bh, acc[m], 0, 0, 0);
                acc[m] = __builtin_amdgcn_mfma_f32_16x16x32_bf16(am, bm, acc[m], 0, 0, 0);
            }
        }
        const int col = ct * 16 + lo;
        const float bb0 = b0[col];
        #pragma unroll
        for (int m = 0; m < 8; ++m)
            #pragma unroll
            for (int r = 0; r < 4; ++r) {
                int row = m * 16 + hi * 4 + r;
                zx[((size_t)t * B_ + row) * 2800 + col] = acc[m][r] + bb0;
            }
    }
}

// ---------------------------------------------------------------------------
// GEMM phase (device): Z[128,N] = concat(A1,A2) @ Wt^T (+ bias | + zadd)
// Per-wave 16-col x 64-row tile; wave-tiles spread as gw = wid*G_ + bid.
// B-planes double-buffered in registers (next k-tile prefetch).
// ---------------------------------------------------------------------------
__device__ void gemm_phase(
    const u16* __restrict__ A1H, const u16* __restrict__ A1M,
    const u16* __restrict__ A1L, int lda1, int K1pad,
    const u16* __restrict__ A2H, const u16* __restrict__ A2M,
    const u16* __restrict__ A2L, int lda2,
    const u16* __restrict__ WH, const u16* __restrict__ WM,
    const u16* __restrict__ WL, int Kp, int NT,
    const float* __restrict__ bias, const float* __restrict__ zadd,
    float* __restrict__ z, int N)
{
    const int lane = threadIdx.x & 63, wid = threadIdx.x >> 6;
    const int lo = lane & 15, hi = lane >> 4;
    const int ncol = N >> 4;
    const int ntiles = ncol * 2;                 // 2 M-halves of 64 rows
    for (int i = wid * G_ + blockIdx.x; i < ntiles; i += NW_) {
        const int ct = i >> 1, r0 = (i & 1) * 64;
        v4f acc[4];
        #pragma unroll
        for (int m = 0; m < 4; ++m) acc[m] = (v4f)0.f;
        const size_t bb = (size_t)(ct * 16 + lo) * Kp + hi * 8;
        v8s bh = *(const v8s*)(WH + bb);
        v8s bm = *(const v8s*)(WM + bb);
        v8s bl = *(const v8s*)(WL + bb);
        for (int kt = 0; kt < NT; ++kt) {
            v8s nh = bh, nm = bm, nl = bl;
            if (kt + 1 < NT) {
                const size_t nb = bb + (size_t)(kt + 1) * 32;
                nh = *(const v8s*)(WH + nb);
                nm = *(const v8s*)(WM + nb);
                nl = *(const v8s*)(WL + nb);
            }
            const int kb = kt * 32;
            const bool s1 = kb < K1pad;
            const u16* pH = s1 ? A1H : A2H;
            const u16* pM = s1 ? A1M : A2M;
            const u16* pL = s1 ? A1L : A2L;
            const int lda = s1 ? lda1 : lda2;
            const int ko = s1 ? kb : kb - K1pad;
            #pragma unroll
            for (int m = 0; m < 4; ++m) {
                size_t ao = (size_t)(r0 + m * 16 + lo) * lda + ko + hi * 8;
                v8s ah = *(const v8s*)(pH + ao);
                v8s am = *(const v8s*)(pM + ao);
                v8s al = *(const v8s*)(pL + ao);
                acc[m] = __builtin_amdgcn_mfma_f32_16x16x32_bf16(ah, bh, acc[m], 0, 0, 0);
                acc[m] = __builtin_amdgcn_mfma_f32_16x16x32_bf16(ah, bm, acc[m], 0, 0, 0);
                acc[m] = __builtin_amdgcn_mfma_f32_16x16x32_bf16(am, bh, acc[m], 0, 0, 0);
                acc[m] = __builtin_amdgcn_mfma_f32_16x16x32_bf16(ah, bl, acc[m], 0, 0, 0);
                acc[m] = __builtin_amdgcn_mfma_f32_16x16x32_bf16(al, bh, acc[m], 0, 0, 0);
                acc[m] = __builtin_amdgcn_mfma_f32_16x16x32_bf16(am, bm, acc[m], 0, 0, 0);
            }
            bh = nh; bm = nm; bl = nl;
        }
        const int col = ct * 16 + lo;
        if (zadd) {
            #pragma unroll
            for (int m = 0; m < 4; ++m)
                #pragma unroll
                for (int r = 0; r < 4; ++r) {
                    int row = r0 + m * 16 + hi * 4 + r;
                    z[(size_t)row * N + col] = acc[m][r] + zadd[(size_t)row * N + col];
                }
        } else {
            const float bv = bias[col];
            #pragma unroll
            for (int m = 0; m < 4; ++m)
                #pragma unroll
                for (int r = 0; r < 4; ++r) {
                    int row = r0 + m * 16 + hi * 4 + r;
                    z[(size_t)row * N + col] = acc[m][r] + bv;
                }
        }
    }
}

// Block-wide sum over 512 threads (8 waves), broadcast.
__device__ __forceinline__ float blockSum(float v, volatile float* red) {
    #pragma unroll
    for (int off = 32; off > 0; off >>= 1) v += __shfl_down(v, off, 64);
    int w = threadIdx.x >> 6, lane = threadIdx.x & 63;
    __syncthreads();
    if (lane == 0) red[w] = v;
    __syncthreads();
    float r = 0.f;
    #pragma unroll
    for (int j = 0; j < 8; ++j) r += red[j];
    return r;
}

// ---------------------------------------------------------------------------
// Pointwise phase (512 thr): LN4 + gates + c-LN + zoneout; one row/block.
// ---------------------------------------------------------------------------
template <int FF>
__device__ void pw_phase(const float* __restrict__ z,
    const float* __restrict__ gg, const float* __restrict__ bg,
    const float* __restrict__ gc, const float* __restrict__ bc,
    float* __restrict__ h, float* __restrict__ c,
    u16* __restrict__ hpH, u16* __restrict__ hpM, u16* __restrict__ hpL,
    int hstride, u16* __restrict__ hist, int t, volatile float* red)
{
    const int tid = threadIdx.x;
    constexpr int NU = (FF + TPB_ - 1) / TPB_;
    for (int b = blockIdx.x; b < B_; b += G_) {
        const float* zr = z + (size_t)b * 4 * FF;
        float* hr = h + (size_t)b * FF;
        float* cr = c + (size_t)b * FF;

        float s[4] = {0, 0, 0, 0}, q[4] = {0, 0, 0, 0};
        #pragma unroll
        for (int i = 0; i < NU; ++i) {
            int u = tid + i * TPB_;
            if (u < FF) {
                #pragma unroll
                for (int g = 0; g < 4; ++g) { float v = zr[g * FF + u]; s[g] += v; q[g] += v * v; }
            }
        }
        float mu[4], rs[4];
        #pragma unroll
        for (int g = 0; g < 4; ++g) {
            float S = blockSum(s[g], red);
            float Q = blockSum(q[g], red);
            mu[g] = S / FF;
            rs[g] = rsqrtf(Q / FF - mu[g] * mu[g] + 1e-5f);
        }

        float nc[NU], og[NU], ho[NU], co[NU];
        float cs = 0.f, cq = 0.f;
        #pragma unroll
        for (int i = 0; i < NU; ++i) {
            int u = tid + i * TPB_;
            if (u < FF) {
                float zi = (zr[u]          - mu[0]) * rs[0] * gg[u]          + bg[u];
                float zj = (zr[FF + u]     - mu[1]) * rs[1] * gg[FF + u]     + bg[FF + u];
                float zf = (zr[2 * FF + u] - mu[2]) * rs[2] * gg[2 * FF + u] + bg[2 * FF + u];
                float zo = (zr[3 * FF + u] - mu[3]) * rs[3] * gg[3 * FF + u] + bg[3 * FF + u];
                float cold = cr[u];
                float ncv = cold * sigm(zf + 1.0f) + sigm(zi) * tanhf(zj);
                nc[i] = ncv; og[i] = sigm(zo); co[i] = cold; ho[i] = hr[u];
                cs += ncv; cq += ncv * ncv;
            } else { nc[i] = 0.f; og[i] = 0.f; co[i] = 0.f; ho[i] = 0.f; }
        }
        float CS = blockSum(cs, red);
        float CQ = blockSum(cq, red);
        float muc = CS / FF;
        float rsc = rsqrtf(CQ / FF - muc * muc + 1e-5f);

        #pragma unroll
        for (int i = 0; i < NU; ++i) {
            int u = tid + i * TPB_;
            if (u < FF) {
                float nh = tanhf((nc[i] - muc) * rsc * gc[u] + bc[u]) * og[i];
                float hout = 0.9f * nh + 0.1f * ho[i];
                float cout = 0.5f * nc[i] + 0.5f * co[i];
                hr[u] = hout;
                cr[u] = cout;
                u16 H, M, L;
                split3f(hout, H, M, L);
                size_t po = (size_t)b * hstride + u;
                hpH[po] = H; hpM[po] = M; hpL[po] = L;
                if (hist) hist[((size_t)b * T_ + t) * FP_ + u] = H;
            }
        }
        if (hist && tid < FP_ - FF)
            hist[((size_t)b * T_ + t) * FP_ + FF + tid] = 0;
    }
}

// ---------------------------------------------------------------------------
// Mega: init -> 100 x (GEMM0|PW0|GEMMS|PWS|GEMM1|PW1) -> states tail.
// ---------------------------------------------------------------------------
__global__ __launch_bounds__(TPB_, 2) void mega(
    const float* __restrict__ b0, const float* __restrict__ g0,
    const float* __restrict__ bg0, const float* __restrict__ gc0,
    const float* __restrict__ bc0,
    const float* __restrict__ b1, const float* __restrict__ g1,
    const float* __restrict__ bg1, const float* __restrict__ gc1,
    const float* __restrict__ bc1,
    const float* __restrict__ bS, const float* __restrict__ gS,
    const float* __restrict__ bgS, const float* __restrict__ gcS,
    const float* __restrict__ bcS,
    const float* __restrict__ zx,
    float* fh, float* fc, float* sh, float* sc, float* z, u16* hist,
    u16* fhH, u16* fhM, u16* fhL, u16* shH, u16* shM, u16* shL,
    u16* W0H, u16* W0M, u16* W0L, u16* WSH, u16* WSM, u16* WSL,
    u16* W1H, u16* W1M, u16* W1L,
    float* outTail, unsigned* flags)
{
    __shared__ float red[8];
    const int gtid = blockIdx.x * TPB_ + threadIdx.x;
    unsigned tgt = 0;

    // init: zero f32 states and h/s planes
    for (int i = gtid; i < 2 * B_ * F_ + 2 * B_ * S_; i += G_ * TPB_) fh[i] = 0.f;
    for (int i = gtid; i < 3 * B_ * FP_ + 3 * B_ * SP_; i += G_ * TPB_) fhH[i] = 0;
    gbar(flags, ++tgt);

    for (int t = 0; t < T_; ++t) {
        // cell 0 (h-part only; x-part precomputed in zx): K=704
        gemm_phase(fhH, fhM, fhL, FP_, FP_, fhH, fhM, fhL, FP_,
                   W0H + 128, W0M + 128, W0L + 128, 832, FP_ / 32,
                   nullptr, zx + (size_t)t * B_ * 2800, z, 4 * F_);
        gbar(flags, ++tgt);
        pw_phase<F_>(z, g0, bg0, gc0, bc0, fh, fc, fhH, fhM, fhL, FP_, nullptr, 0, red);
        gbar(flags, ++tgt);
        // slow: A = [fh | sh], K = 1120
        gemm_phase(fhH, fhM, fhL, FP_, FP_, shH, shM, shL, SP_,
                   WSH, WSM, WSL, 1120, 1120 / 32, bS, nullptr, z, 4 * S_);
        gbar(flags, ++tgt);
        pw_phase<S_>(z, gS, bgS, gcS, bcS, sh, sc, shH, shM, shL, SP_, nullptr, 0, red);
        gbar(flags, ++tgt);
        // cell 1: A = [sh | fh], K = 1120
        gemm_phase(shH, shM, shL, SP_, SP_, fhH, fhM, fhL, FP_,
                   W1H, W1M, W1L, 1120, 1120 / 32, b1, nullptr, z, 4 * F_);
        gbar(flags, ++tgt);
        pw_phase<F_>(z, g1, bg1, gc1, bc1, fh, fc, fhH, fhM, fhL, FP_, hist, t, red);
        gbar(flags, ++tgt);
    }

    // tail: final states -> d_out tail
    const int NF = B_ * F_, NS = B_ * S_;
    for (int i = gtid; i < 2 * NF + 2 * NS; i += G_ * TPB_) {
        float v = (i < NF) ? fh[i] : (i < 2 * NF) ? fc[i - NF]
                : (i < 2 * NF + NS) ? sh[i - 2 * NF] : sc[i - 2 * NF - NS];
        outTail[i] = v;
    }
}

// ---------------------------------------------------------------------------
// Output projection (r5-proven): C = hist[12800,704] @ Wtout^T + bout
// ---------------------------------------------------------------------------
__global__ __launch_bounds__(512) void ogemm(
    const u16* __restrict__ A, const u16* __restrict__ Bt,
    const float* __restrict__ bias, float* __restrict__ C)
{
    const int N = V_;
    const int tid = threadIdx.x, lane = tid & 63, wid = tid >> 6;
    const int wm = wid >> 1, wn = wid & 1;
    const int row0 = blockIdx.y * 256 + wm * 64;
    const int col0 = blockIdx.x * 128 + wn * 64;
    const int lo = lane & 15, hi = lane >> 4;
    const int NT = FP_ / 32;

    v4f acc[4][4];
    #pragma unroll
    for (int i = 0; i < 4; ++i)
        #pragma unroll
        for (int j = 0; j < 4; ++j) acc[i][j] = (v4f)0.f;

    for (int kt = 0; kt < NT; ++kt) {
        const int kb = kt * 32 + hi * 8;
        v8s a[4], b[4];
        #pragma unroll
        for (int i = 0; i < 4; ++i) {
            a[i] = *(const v8s*)(A  + (size_t)(row0 + i * 16 + lo) * FP_ + kb);
            b[i] = *(const v8s*)(Bt + (size_t)(col0 + i * 16 + lo) * FP_ + kb);
        }
        #pragma unroll
        for (int mf = 0; mf < 4; ++mf)
            #pragma unroll
            for (int nf = 0; nf < 4; ++nf)
                acc[mf][nf] = __builtin_amdgcn_mfma_f32_16x16x32_bf16(a[mf], b[nf], acc[mf][nf], 0, 0, 0);
    }

    #pragma unroll
    for (int mf = 0; mf < 4; ++mf) {
        #pragma unroll
        for (int nf = 0; nf < 4; ++nf) {
            int col = col0 + nf * 16 + lo;
            if (col < N) {
                float bb = bias[col];
                #pragma unroll
                for (int r = 0; r < 4; ++r) {
                    int row = row0 + mf * 16 + hi * 4 + r;
                    C[(size_t)row * N + col] = acc[mf][nf][r] + bb;
                }
            }
        }
    }
}

extern "C" void kernel_launch(void* const* d_in, const int* in_sizes, int n_in,
                              void* d_out, int out_size, void* d_ws, size_t ws_size,
                              hipStream_t stream) {
    const float* inputs = (const float*)d_in[0];
    const float* W0   = (const float*)d_in[1];
    const float* b0   = (const float*)d_in[2];
    const float* g0   = (const float*)d_in[3];
    const float* bg0  = (const float*)d_in[4];
    const float* gc0  = (const float*)d_in[5];
    const float* bc0  = (const float*)d_in[6];
    const float* W1   = (const float*)d_in[7];
    const float* b1   = (const float*)d_in[8];
    const float* g1   = (const float*)d_in[9];
    const float* bg1  = (const float*)d_in[10];
    const float* gc1  = (const float*)d_in[11];
    const float* bc1  = (const float*)d_in[12];
    const float* WS   = (const float*)d_in[13];
    const float* bS   = (const float*)d_in[14];
    const float* gS   = (const float*)d_in[15];
    const float* bgS  = (const float*)d_in[16];
    const float* gcS  = (const float*)d_in[17];
    const float* bcS  = (const float*)d_in[18];
    const float* Wout = (const float*)d_in[19];
    const float* bout = (const float*)d_in[20];

    // ---- ws: states + z + hist + Wtout + flags (~34.9 MB, known-safe)
    float* ws = (float*)d_ws;
    float* fh = ws;
    float* fc = fh + B_ * F_;
    float* sh = fc + B_ * F_;
    float* sc = sh + B_ * S_;
    float* z  = sc + B_ * S_;
    u16* hist = (u16*)(z + (size_t)B_ * 4 * F_);
    u16* Wtout = hist + (size_t)12800 * FP_;
    unsigned* flags = (unsigned*)(Wtout + (size_t)10112 * FP_);   // 16 KB

    // ---- d_out scratch (fully rewritten every call; dead before ogemm)
    const size_t P0 = (size_t)2816 * 832;
    const size_t PS = (size_t)1664 * 1120;
    const size_t P1 = (size_t)2816 * 1120;
    const size_t HF = (size_t)B_ * FP_;
    const size_t HS = (size_t)B_ * SP_;
    u16* dp  = (u16*)d_out;
    u16* W0H = dp;          u16* W0M = W0H + P0;  u16* W0L = W0M + P0;
    u16* WSH = W0L + P0;    u16* WSM = WSH + PS;  u16* WSL = WSM + PS;
    u16* W1H = WSL + PS;    u16* W1M = W1H + P1;  u16* W1L = W1M + P1;
    u16* fhH = W1L + P1;    u16* fhM = fhH + HF;  u16* fhL = fhM + HF;
    u16* shH = fhL + HF;    u16* shM = shH + HS;  u16* shL = shM + HS;
    float* zx = (float*)(shL + HS);               // 143.4 MB

    hipMemsetAsync(flags, 0, G_ * 16 * sizeof(unsigned), stream);

    // weight transposes+splits
    wtrans3<<<dim3(88, 26), 256, 0, stream>>>(W0, E_ + F_, 4 * F_, W0H, W0M, W0L, 832, 128, 128);
    wtrans3<<<dim3(52, 35), 256, 0, stream>>>(WS, F_ + S_, 4 * S_, WSH, WSM, WSL, 1120, F_, FP_);
    wtrans3<<<dim3(88, 35), 256, 0, stream>>>(W1, S_ + F_, 4 * F_, W1H, W1M, W1L, 1120, S_, SP_);
    wtrans<<<dim3(316, 22), 256, 0, stream>>>(Wout, F_, V_, Wtout, FP_);

    // x-projection for all t (parallel)
    zxpre<<<2188, 512, 0, stream>>>(inputs, W0H, W0M, W0L, b0, zx);

    // recurrence
    mega<<<G_, TPB_, 0, stream>>>(
        b0, g0, bg0, gc0, bc0,
        b1, g1, bg1, gc1, bc1,
        bS, gS, bgS, gcS, bcS,
        zx,
        fh, fc, sh, sc, z, hist,
        fhH, fhM, fhL, shH, shM, shL,
        W0H, W0M, W0L, WSH, WSM, WSL, W1H, W1M, W1L,
        (float*)d_out + (size_t)B_ * T_ * V_, flags);

    // logits
    ogemm<<<dim3(79, 50), 512, 0, stream>>>(hist, Wtout, bout, (float*)d_out);
}

// Round 8
// 33503.345 us; speedup vs baseline: 1.5408x; 1.5408x over previous
//
#include <hip/hip_runtime.h>
#include <math.h>

// ---------------------------------------------------------------------------
// PTB LN-LSTM stack: B=128, T=100, E=128, F=700, S=400, V=10000.
// Round 8: fix the two measured killers from r7:
//   (1) barrier: two-level, RELAXED polling (one acquire fence per block per
//       barrier) instead of 256-blocks x 256-flags ACQUIRE polling storm.
//   (2) gemm_phase: depth-4 register ring prefetch of B-planes + ping-pong
//       A prefetch -> ~12KB/wave outstanding (vs ~1 load) during GEMM bursts.
// Split-precision 3-plane bf16 MFMA math bit-identical to r5/r6/r7.
// ---------------------------------------------------------------------------

#define B_ 128
#define T_ 100
#define E_ 128
#define F_ 700
#define S_ 400
#define V_ 10000

#define FP_ 704    // F padded
#define SP_ 416    // S padded
#define G_  256    // mega blocks
#define TPB_ 512   // threads per mega block (8 waves)
#define NW_ (G_ * 8)

using v8s = __attribute__((ext_vector_type(8))) short;
using v4f = __attribute__((ext_vector_type(4))) float;
typedef unsigned short u16;

__device__ __forceinline__ u16 f2bf(float x) {
    unsigned int u = __float_as_uint(x);
    u += 0x7FFFu + ((u >> 16) & 1u);
    return (u16)(u >> 16);
}
__device__ __forceinline__ float bf2f(u16 h) {
    return __uint_as_float(((unsigned int)h) << 16);
}
__device__ __forceinline__ void split3f(float x, u16& h, u16& m, u16& l) {
    h = f2bf(x); float r  = x - bf2f(h);
    m = f2bf(r); float r2 = r - bf2f(m);
    l = f2bf(r2);
}
__device__ __forceinline__ float sigm(float x) { return 1.0f / (1.0f + expf(-x)); }

// ---------------------------------------------------------------------------
// Two-level grid barrier.
//   arrive : block -> release-store(target) to its own flag line
//   gather : block 0 only, threads 0..G_-1 RELAXED-poll one flag each
//   publish: block 0 thread 0 release-store(target) to single `go` word
//   wait   : other blocks' thread 0 RELAXED-poll `go`
//   acquire: one __threadfence() per block at the end
// ---------------------------------------------------------------------------
__device__ __forceinline__ void gbar(unsigned* flags, unsigned* go, unsigned target) {
    __syncthreads();
    if (threadIdx.x == 0) {
        __threadfence();   // release: drain this block's prior writes
        __hip_atomic_store(flags + (size_t)blockIdx.x * 16, target,
                           __ATOMIC_RELEASE, __HIP_MEMORY_SCOPE_AGENT);
    }
    if (blockIdx.x == 0) {
        if (threadIdx.x < G_) {
            const unsigned* f = flags + (size_t)threadIdx.x * 16;
            while (__hip_atomic_load(f, __ATOMIC_RELAXED, __HIP_MEMORY_SCOPE_AGENT) < target)
                __builtin_amdgcn_s_sleep(2);
        }
        __syncthreads();
        if (threadIdx.x == 0)
            __hip_atomic_store(go, target, __ATOMIC_RELEASE, __HIP_MEMORY_SCOPE_AGENT);
    } else {
        if (threadIdx.x == 0) {
            while (__hip_atomic_load(go, __ATOMIC_RELAXED, __HIP_MEMORY_SCOPE_AGENT) < target)
                __builtin_amdgcn_s_sleep(2);
        }
    }
    __syncthreads();
    __threadfence();       // acquire: invalidate stale cached data once
}

// ---------------------------------------------------------------------------
// Standalone transpose+split kernels (r5-proven; full-coverage writes).
// ---------------------------------------------------------------------------
__global__ __launch_bounds__(256) void wtrans3(
    const float* __restrict__ W, int K, int N,
    u16* __restrict__ WtH, u16* __restrict__ WtM, u16* __restrict__ WtL,
    int Kp, int K1, int K1pad)
{
    __shared__ float t[32][33];
    const int c0 = blockIdx.x * 32, kp0 = blockIdx.y * 32;
    const int tx = threadIdx.x & 31, ty = threadIdx.x >> 5;
    #pragma unroll
    for (int i = 0; i < 4; ++i) {
        int kpos = kp0 + ty + i * 8, c = c0 + tx;
        int k = (kpos < K1) ? kpos : (kpos >= K1pad ? K1 + (kpos - K1pad) : -1);
        t[ty + i * 8][tx] = (k >= 0 && k < K && c < N) ? W[(size_t)k * N + c] : 0.f;
    }
    __syncthreads();
    #pragma unroll
    for (int i = 0; i < 4; ++i) {
        int r = c0 + ty + i * 8;
        u16 h, m, l;
        split3f(t[tx][ty + i * 8], h, m, l);
        size_t idx = (size_t)r * Kp + kp0 + tx;
        WtH[idx] = h; WtM[idx] = m; WtL[idx] = l;
    }
}

__global__ __launch_bounds__(256) void wtrans(
    const float* __restrict__ W, int K, int N,
    u16* __restrict__ Wt, int Kpad)
{
    __shared__ float t[32][33];
    const int c0 = blockIdx.x * 32, k0 = blockIdx.y * 32;
    const int tx = threadIdx.x & 31, ty = threadIdx.x >> 5;
    #pragma unroll
    for (int i = 0; i < 4; ++i) {
        int k = k0 + ty + i * 8, c = c0 + tx;
        t[ty + i * 8][tx] = (k < K && c < N) ? W[(size_t)k * N + c] : 0.f;
    }
    __syncthreads();
    #pragma unroll
    for (int i = 0; i < 4; ++i) {
        int r = c0 + ty + i * 8;
        Wt[(size_t)r * Kpad + k0 + tx] = f2bf(t[tx][ty + i * 8]);
    }
}

// ---------------------------------------------------------------------------
// zx precompute: zx[t][b][col] = x[b,t,:] @ W0[:128,col] + b0[col]  (r7-proven)
// ---------------------------------------------------------------------------
__global__ __launch_bounds__(512, 2) void zxpre(
    const float* __restrict__ inputs,
    const u16* __restrict__ WH, const u16* __restrict__ WM,
    const u16* __restrict__ WL, const float* __restrict__ b0,
    float* __restrict__ zx)
{
    const int lane = threadIdx.x & 63, wid = threadIdx.x >> 6;
    const int lo = lane & 15, hi = lane >> 4;
    const int ntiles = 175 * 100;
    for (int i = blockIdx.x * 8 + wid; i < ntiles; i += gridDim.x * 8) {
        const int t = i / 175, ct = i % 175;
        v4f acc[8];
        #pragma unroll
        for (int m = 0; m < 8; ++m) acc[m] = (v4f)0.f;
        const size_t bb = (size_t)(ct * 16 + lo) * 832 + hi * 8;
        for (int kt = 0; kt < 4; ++kt) {
            const size_t bo = bb + kt * 32;
            v8s bh = *(const v8s*)(WH + bo);
            v8s bm = *(const v8s*)(WM + bo);
            v8s bl = *(const v8s*)(WL + bo);
            #pragma unroll
            for (int m = 0; m < 8; ++m) {
                const float* p = inputs + (size_t)(m * 16 + lo) * (T_ * E_)
                               + (size_t)t * E_ + kt * 32 + hi * 8;
                float v0[8];
                *(float4*)(v0)     = *(const float4*)(p);
                *(float4*)(v0 + 4) = *(const float4*)(p + 4);
                v8s ah, am, al;
                #pragma unroll
                for (int j = 0; j < 8; ++j) {
                    u16 H, M, L; split3f(v0[j], H, M, L);
                    ah[j] = (short)H; am[j] = (short)M; al[j] = (short)L;
                }
                acc[m] = __builtin_amdgcn_mfma_f32_16x16x32_bf16(ah, bh, acc[m], 0, 0, 0);
                acc[m] = __builtin_amdgcn_mfma_f32_16x16x32_bf16(ah, bm, acc[m], 0, 0, 0);
                acc[m] = __builtin_amdgcn_mfma_f32_16x16x32_bf16(am, bh, acc[m], 0, 0, 0);
                acc[m] = __builtin_amdgcn_mfma_f32_16x16x32_bf16(ah, bl, acc[m], 0, 0, 0);
                acc[m] = __builtin_amdgcn_mfma_f32_16x16x32_bf16(al, bh, acc[m], 0, 0, 0);
                acc[m] = __builtin_amdgcn_mfma_f32_16x16x32_bf16(am, bm, acc[m], 0, 0, 0);
            }
        }
        const int col = ct * 16 + lo;
        const float bb0 = b0[col];
        #pragma unroll
        for (int m = 0; m < 8; ++m)
            #pragma unroll
            for (int r = 0; r < 4; ++r) {
                int row = m * 16 + hi * 4 + r;
                zx[((size_t)t * B_ + row) * 2800 + col] = acc[m][r] + bb0;
            }
    }
}

// ---------------------------------------------------------------------------
// GEMM phase: Z[128,N] = concat(A1,A2) @ Wt^T (+ bias | + zadd).
// Per-wave 16-col x 64-row tile. Depth-4 B-plane register ring + ping-pong
// A prefetch (all indices compile-time static). MFMA order identical to r7.
// ---------------------------------------------------------------------------
__device__ void gemm_phase(
    const u16* __restrict__ A1H, const u16* __restrict__ A1M,
    const u16* __restrict__ A1L, int lda1, int K1pad,
    const u16* __restrict__ A2H, const u16* __restrict__ A2M,
    const u16* __restrict__ A2L, int lda2,
    const u16* __restrict__ WH, const u16* __restrict__ WM,
    const u16* __restrict__ WL, int Kp, int NT,
    const float* __restrict__ bias, const float* __restrict__ zadd,
    float* __restrict__ z, int N)
{
    const int lane = threadIdx.x & 63, wid = threadIdx.x >> 6;
    const int lo = lane & 15, hi = lane >> 4;
    const int ntiles = (N >> 4) * 2;                 // 16-col x 64-row tiles
    for (int i = wid * G_ + blockIdx.x; i < ntiles; i += NW_) {
        const int ct = i >> 1, r0 = (i & 1) * 64;
        v4f acc[4];
        #pragma unroll
        for (int m = 0; m < 4; ++m) acc[m] = (v4f)0.f;

        const size_t bb = (size_t)(ct * 16 + lo) * Kp + hi * 8;

        // B ring: k-tiles kt..kt+3 resident
        v8s BH[4], BM[4], BL[4];
        #pragma unroll
        for (int j = 0; j < 4; ++j) {
            const size_t o = bb + (size_t)((j < NT) ? j : 0) * 32;
            BH[j] = *(const v8s*)(WH + o);
            BM[j] = *(const v8s*)(WM + o);
            BL[j] = *(const v8s*)(WL + o);
        }
        // A ping-pong: kt=0 into buffer 0 (kt=0 is always in segment 1)
        v8s AH[2][4], AM[2][4], AL[2][4];
        #pragma unroll
        for (int m = 0; m < 4; ++m) {
            size_t ao = (size_t)(r0 + m * 16 + lo) * lda1 + hi * 8;
            AH[0][m] = *(const v8s*)(A1H + ao);
            AM[0][m] = *(const v8s*)(A1M + ao);
            AL[0][m] = *(const v8s*)(A1L + ao);
        }

        for (int kt0 = 0; kt0 < NT; kt0 += 4) {
            #pragma unroll
            for (int j = 0; j < 4; ++j) {
                const int kt = kt0 + j;
                if (kt < NT) {
                    const int cb = j & 1, nb = (j & 1) ^ 1;
                    // prefetch A for kt+1 (issues before MFMAs -> overlaps)
                    const int ka = kt + 1;
                    if (ka < NT) {
                        const int kb2 = ka * 32;
                        const bool s1 = kb2 < K1pad;
                        const u16* pH = s1 ? A1H : A2H;
                        const u16* pM = s1 ? A1M : A2M;
                        const u16* pL = s1 ? A1L : A2L;
                        const int lda = s1 ? lda1 : lda2;
                        const int ko = s1 ? kb2 : kb2 - K1pad;
                        #pragma unroll
                        for (int m = 0; m < 4; ++m) {
                            size_t ao = (size_t)(r0 + m * 16 + lo) * lda + ko + hi * 8;
                            AH[nb][m] = *(const v8s*)(pH + ao);
                            AM[nb][m] = *(const v8s*)(pM + ao);
                            AL[nb][m] = *(const v8s*)(pL + ao);
                        }
                    }
                    // MFMAs for kt (order identical to r5/r6/r7)
                    #pragma unroll
                    for (int m = 0; m < 4; ++m) {
                        acc[m] = __builtin_amdgcn_mfma_f32_16x16x32_bf16(AH[cb][m], BH[j], acc[m], 0, 0, 0);
                        acc[m] = __builtin_amdgcn_mfma_f32_16x16x32_bf16(AH[cb][m], BM[j], acc[m], 0, 0, 0);
                        acc[m] = __builtin_amdgcn_mfma_f32_16x16x32_bf16(AM[cb][m], BH[j], acc[m], 0, 0, 0);
                        acc[m] = __builtin_amdgcn_mfma_f32_16x16x32_bf16(AH[cb][m], BL[j], acc[m], 0, 0, 0);
                        acc[m] = __builtin_amdgcn_mfma_f32_16x16x32_bf16(AL[cb][m], BH[j], acc[m], 0, 0, 0);
                        acc[m] = __builtin_amdgcn_mfma_f32_16x16x32_bf16(AM[cb][m], BM[j], acc[m], 0, 0, 0);
                    }
                    // refill B[j] <- kt+4
                    const int kn = kt + 4;
                    if (kn < NT) {
                        const size_t o = bb + (size_t)kn * 32;
                        BH[j] = *(const v8s*)(WH + o);
                        BM[j] = *(const v8s*)(WM + o);
                        BL[j] = *(const v8s*)(WL + o);
                    }
                }
            }
        }

        const int col = ct * 16 + lo;
        if (zadd) {
            #pragma unroll
            for (int m = 0; m < 4; ++m)
                #pragma unroll
                for (int r = 0; r < 4; ++r) {
                    int row = r0 + m * 16 + hi * 4 + r;
                    z[(size_t)row * N + col] = acc[m][r] + zadd[(size_t)row * N + col];
                }
        } else {
            const float bv = bias[col];
            #pragma unroll
            for (int m = 0; m < 4; ++m)
                #pragma unroll
                for (int r = 0; r < 4; ++r) {
                    int row = r0 + m * 16 + hi * 4 + r;
                    z[(size_t)row * N + col] = acc[m][r] + bv;
                }
        }
    }
}

// Block-wide sum over 512 threads (8 waves), broadcast.
__device__ __forceinline__ float blockSum(float v, volatile float* red) {
    #pragma unroll
    for (int off = 32; off > 0; off >>= 1) v += __shfl_down(v, off, 64);
    int w = threadIdx.x >> 6, lane = threadIdx.x & 63;
    __syncthreads();
    if (lane == 0) red[w] = v;
    __syncthreads();
    float r = 0.f;
    #pragma unroll
    for (int j = 0; j < 8; ++j) r += red[j];
    return r;
}

// ---------------------------------------------------------------------------
// Pointwise phase (512 thr): LN4 + gates + c-LN + zoneout; one row/block.
// ---------------------------------------------------------------------------
template <int FF>
__device__ void pw_phase(const float* __restrict__ z,
    const float* __restrict__ gg, const float* __restrict__ bg,
    const float* __restrict__ gc, const float* __restrict__ bc,
    float* __restrict__ h, float* __restrict__ c,
    u16* __restrict__ hpH, u16* __restrict__ hpM, u16* __restrict__ hpL,
    int hstride, u16* __restrict__ hist, int t, volatile float* red)
{
    const int tid = threadIdx.x;
    constexpr int NU = (FF + TPB_ - 1) / TPB_;
    for (int b = blockIdx.x; b < B_; b += G_) {
        const float* zr = z + (size_t)b * 4 * FF;
        float* hr = h + (size_t)b * FF;
        float* cr = c + (size_t)b * FF;

        float s[4] = {0, 0, 0, 0}, q[4] = {0, 0, 0, 0};
        #pragma unroll
        for (int i = 0; i < NU; ++i) {
            int u = tid + i * TPB_;
            if (u < FF) {
                #pragma unroll
                for (int g = 0; g < 4; ++g) { float v = zr[g * FF + u]; s[g] += v; q[g] += v * v; }
            }
        }
        float mu[4], rs[4];
        #pragma unroll
        for (int g = 0; g < 4; ++g) {
            float S = blockSum(s[g], red);
            float Q = blockSum(q[g], red);
            mu[g] = S / FF;
            rs[g] = rsqrtf(Q / FF - mu[g] * mu[g] + 1e-5f);
        }

        float nc[NU], og[NU], ho[NU], co[NU];
        float cs = 0.f, cq = 0.f;
        #pragma unroll
        for (int i = 0; i < NU; ++i) {
            int u = tid + i * TPB_;
            if (u < FF) {
                float zi = (zr[u]          - mu[0]) * rs[0] * gg[u]          + bg[u];
                float zj = (zr[FF + u]     - mu[1]) * rs[1] * gg[FF + u]     + bg[FF + u];
                float zf = (zr[2 * FF + u] - mu[2]) * rs[2] * gg[2 * FF + u] + bg[2 * FF + u];
                float zo = (zr[3 * FF + u] - mu[3]) * rs[3] * gg[3 * FF + u] + bg[3 * FF + u];
                float cold = cr[u];
                float ncv = cold * sigm(zf + 1.0f) + sigm(zi) * tanhf(zj);
                nc[i] = ncv; og[i] = sigm(zo); co[i] = cold; ho[i] = hr[u];
                cs += ncv; cq += ncv * ncv;
            } else { nc[i] = 0.f; og[i] = 0.f; co[i] = 0.f; ho[i] = 0.f; }
        }
        float CS = blockSum(cs, red);
        float CQ = blockSum(cq, red);
        float muc = CS / FF;
        float rsc = rsqrtf(CQ / FF - muc * muc + 1e-5f);

        #pragma unroll
        for (int i = 0; i < NU; ++i) {
            int u = tid + i * TPB_;
            if (u < FF) {
                float nh = tanhf((nc[i] - muc) * rsc * gc[u] + bc[u]) * og[i];
                float hout = 0.9f * nh + 0.1f * ho[i];
                float cout = 0.5f * nc[i] + 0.5f * co[i];
                hr[u] = hout;
                cr[u] = cout;
                u16 H, M, L;
                split3f(hout, H, M, L);
                size_t po = (size_t)b * hstride + u;
                hpH[po] = H; hpM[po] = M; hpL[po] = L;
                if (hist) hist[((size_t)b * T_ + t) * FP_ + u] = H;
            }
        }
        if (hist && tid < FP_ - FF)
            hist[((size_t)b * T_ + t) * FP_ + FF + tid] = 0;
    }
}

// ---------------------------------------------------------------------------
// Mega: init -> 100 x (GEMM0|PW0|GEMMS|PWS|GEMM1|PW1) -> states tail.
// ---------------------------------------------------------------------------
__global__ __launch_bounds__(TPB_, 2) void mega(
    const float* __restrict__ b0, const float* __restrict__ g0,
    const float* __restrict__ bg0, const float* __restrict__ gc0,
    const float* __restrict__ bc0,
    const float* __restrict__ b1, const float* __restrict__ g1,
    const float* __restrict__ bg1, const float* __restrict__ gc1,
    const float* __restrict__ bc1,
    const float* __restrict__ bS, const float* __restrict__ gS,
    const float* __restrict__ bgS, const float* __restrict__ gcS,
    const float* __restrict__ bcS,
    const float* __restrict__ zx,
    float* fh, float* fc, float* sh, float* sc, float* z, u16* hist,
    u16* fhH, u16* fhM, u16* fhL, u16* shH, u16* shM, u16* shL,
    u16* W0H, u16* W0M, u16* W0L, u16* WSH, u16* WSM, u16* WSL,
    u16* W1H, u16* W1M, u16* W1L,
    float* outTail, unsigned* flags, unsigned* go)
{
    __shared__ float red[8];
    const int gtid = blockIdx.x * TPB_ + threadIdx.x;
    unsigned tgt = 0;

    // init: zero f32 states and h/s planes
    for (int i = gtid; i < 2 * B_ * F_ + 2 * B_ * S_; i += G_ * TPB_) fh[i] = 0.f;
    for (int i = gtid; i < 3 * B_ * FP_ + 3 * B_ * SP_; i += G_ * TPB_) fhH[i] = 0;
    gbar(flags, go, ++tgt);

    for (int t = 0; t < T_; ++t) {
        // cell 0 (h-part only; x-part precomputed in zx): K=704
        gemm_phase(fhH, fhM, fhL, FP_, FP_, fhH, fhM, fhL, FP_,
                   W0H + 128, W0M + 128, W0L + 128, 832, FP_ / 32,
                   nullptr, zx + (size_t)t * B_ * 2800, z, 4 * F_);
        gbar(flags, go, ++tgt);
        pw_phase<F_>(z, g0, bg0, gc0, bc0, fh, fc, fhH, fhM, fhL, FP_, nullptr, 0, red);
        gbar(flags, go, ++tgt);
        // slow: A = [fh | sh], K = 1120
        gemm_phase(fhH, fhM, fhL, FP_, FP_, shH, shM, shL, SP_,
                   WSH, WSM, WSL, 1120, 1120 / 32, bS, nullptr, z, 4 * S_);
        gbar(flags, go, ++tgt);
        pw_phase<S_>(z, gS, bgS, gcS, bcS, sh, sc, shH, shM, shL, SP_, nullptr, 0, red);
        gbar(flags, go, ++tgt);
        // cell 1: A = [sh | fh], K = 1120
        gemm_phase(shH, shM, shL, SP_, SP_, fhH, fhM, fhL, FP_,
                   W1H, W1M, W1L, 1120, 1120 / 32, b1, nullptr, z, 4 * F_);
        gbar(flags, go, ++tgt);
        pw_phase<F_>(z, g1, bg1, gc1, bc1, fh, fc, fhH, fhM, fhL, FP_, hist, t, red);
        gbar(flags, go, ++tgt);
    }

    // tail: final states -> d_out tail
    const int NF = B_ * F_, NS = B_ * S_;
    for (int i = gtid; i < 2 * NF + 2 * NS; i += G_ * TPB_) {
        float v = (i < NF) ? fh[i] : (i < 2 * NF) ? fc[i - NF]
                : (i < 2 * NF + NS) ? sh[i - 2 * NF] : sc[i - 2 * NF - NS];
        outTail[i] = v;
    }
}

// ---------------------------------------------------------------------------
// Output projection (r5-proven): C = hist[12800,704] @ Wtout^T + bout
// ---------------------------------------------------------------------------
__global__ __launch_bounds__(512) void ogemm(
    const u16* __restrict__ A, const u16* __restrict__ Bt,
    const float* __restrict__ bias, float* __restrict__ C)
{
    const int N = V_;
    const int tid = threadIdx.x, lane = tid & 63, wid = tid >> 6;
    const int wm = wid >> 1, wn = wid & 1;
    const int row0 = blockIdx.y * 256 + wm * 64;
    const int col0 = blockIdx.x * 128 + wn * 64;
    const int lo = lane & 15, hi = lane >> 4;
    const int NT = FP_ / 32;

    v4f acc[4][4];
    #pragma unroll
    for (int i = 0; i < 4; ++i)
        #pragma unroll
        for (int j = 0; j < 4; ++j) acc[i][j] = (v4f)0.f;

    for (int kt = 0; kt < NT; ++kt) {
        const int kb = kt * 32 + hi * 8;
        v8s a[4], b[4];
        #pragma unroll
        for (int i = 0; i < 4; ++i) {
            a[i] = *(const v8s*)(A  + (size_t)(row0 + i * 16 + lo) * FP_ + kb);
            b[i] = *(const v8s*)(Bt + (size_t)(col0 + i * 16 + lo) * FP_ + kb);
        }
        #pragma unroll
        for (int mf = 0; mf < 4; ++mf)
            #pragma unroll
            for (int nf = 0; nf < 4; ++nf)
                acc[mf][nf] = __builtin_amdgcn_mfma_f32_16x16x32_bf16(a[mf], b[nf], acc[mf][nf], 0, 0, 0);
    }

    #pragma unroll
    for (int mf = 0; mf < 4; ++mf) {
        #pragma unroll
        for (int nf = 0; nf < 4; ++nf) {
            int col = col0 + nf * 16 + lo;
            if (col < N) {
                float bb = bias[col];
                #pragma unroll
                for (int r = 0; r < 4; ++r) {
                    int row = row0 + mf * 16 + hi * 4 + r;
                    C[(size_t)row * N + col] = acc[mf][nf][r] + bb;
                }
            }
        }
    }
}

extern "C" void kernel_launch(void* const* d_in, const int* in_sizes, int n_in,
                              void* d_out, int out_size, void* d_ws, size_t ws_size,
                              hipStream_t stream) {
    const float* inputs = (const float*)d_in[0];
    const float* W0   = (const float*)d_in[1];
    const float* b0   = (const float*)d_in[2];
    const float* g0   = (const float*)d_in[3];
    const float* bg0  = (const float*)d_in[4];
    const float* gc0  = (const float*)d_in[5];
    const float* bc0  = (const float*)d_in[6];
    const float* W1   = (const float*)d_in[7];
    const float* b1   = (const float*)d_in[8];
    const float* g1   = (const float*)d_in[9];
    const float* bg1  = (const float*)d_in[10];
    const float* gc1  = (const float*)d_in[11];
    const float* bc1  = (const float*)d_in[12];
    const float* WS   = (const float*)d_in[13];
    const float* bS   = (const float*)d_in[14];
    const float* gS   = (const float*)d_in[15];
    const float* bgS  = (const float*)d_in[16];
    const float* gcS  = (const float*)d_in[17];
    const float* bcS  = (const float*)d_in[18];
    const float* Wout = (const float*)d_in[19];
    const float* bout = (const float*)d_in[20];

    // ---- ws: states + z + hist + Wtout + flags/go (~34.9 MB, known-safe)
    float* ws = (float*)d_ws;
    float* fh = ws;
    float* fc = fh + B_ * F_;
    float* sh = fc + B_ * F_;
    float* sc = sh + B_ * S_;
    float* z  = sc + B_ * S_;
    u16* hist = (u16*)(z + (size_t)B_ * 4 * F_);
    u16* Wtout = hist + (size_t)12800 * FP_;
    unsigned* flags = (unsigned*)(Wtout + (size_t)10112 * FP_);   // G_*16 u32
    unsigned* go    = flags + G_ * 16;                            // 1 u32 (own line)

    // ---- d_out scratch (fully rewritten every call; dead before ogemm)
    const size_t P0 = (size_t)2816 * 832;
    const size_t PS = (size_t)1664 * 1120;
    const size_t P1 = (size_t)2816 * 1120;
    const size_t HF = (size_t)B_ * FP_;
    const size_t HS = (size_t)B_ * SP_;
    u16* dp  = (u16*)d_out;
    u16* W0H = dp;          u16* W0M = W0H + P0;  u16* W0L = W0M + P0;
    u16* WSH = W0L + P0;    u16* WSM = WSH + PS;  u16* WSL = WSM + PS;
    u16* W1H = WSL + PS;    u16* W1M = W1H + P1;  u16* W1L = W1M + P1;
    u16* fhH = W1L + P1;    u16* fhM = fhH + HF;  u16* fhL = fhM + HF;
    u16* shH = fhL + HF;    u16* shM = shH + HS;  u16* shL = shM + HS;
    float* zx = (float*)(shL + HS);               // 143.4 MB

    hipMemsetAsync(flags, 0, (G_ * 16 + 16) * sizeof(unsigned), stream);

    // weight transposes+splits
    wtrans3<<<dim3(88, 26), 256, 0, stream>>>(W0, E_ + F_, 4 * F_, W0H, W0M, W0L, 832, 128, 128);
    wtrans3<<<dim3(52, 35), 256, 0, stream>>>(WS, F_ + S_, 4 * S_, WSH, WSM, WSL, 1120, F_, FP_);
    wtrans3<<<dim3(88, 35), 256, 0, stream>>>(W1, S_ + F_, 4 * F_, W1H, W1M, W1L, 1120, S_, SP_);
    wtrans<<<dim3(316, 22), 256, 0, stream>>>(Wout, F_, V_, Wtout, FP_);

    // x-projection for all t (parallel)
    zxpre<<<2188, 512, 0, stream>>>(inputs, W0H, W0M, W0L, b0, zx);

    // recurrence
    mega<<<G_, TPB_, 0, stream>>>(
        b0, g0, bg0, gc0, bc0,
        b1, g1, bg1, gc1, bc1,
        bS, gS, bgS, gcS, bcS,
        zx,
        fh, fc, sh, sc, z, hist,
        fhH, fhM, fhL, shH, shM, shL,
        W0H, W0M, W0L, WSH, WSM, WSL, W1H, W1M, W1L,
        (float*)d_out + (size_t)B_ * T_ * V_, flags, go);

    // logits
    ogemm<<<dim3(79, 50), 512, 0, stream>>>(hist, Wtout, bout, (float*)d_out);
}

// Round 9
// 18935.246 us; speedup vs baseline: 2.7263x; 1.7694x over previous
//
#include <hip/hip_runtime.h>
#include <math.h>

// ---------------------------------------------------------------------------
// PTB LN-LSTM stack: B=128, T=100, E=128, F=700, S=400, V=10000.
// Round 9: kill the measured fence cost (r8: WRITE 5.0GB from per-phase
// buffer_wbl2 of dirty L2; L3 thrash -> weights re-fetch from HBM at 373GB/s):
//   (1) ALL cross-phase data written with nontemporal (write-through) stores
//       -> release fence has nothing to write back; L3 keeps weights.
//   (2) acquire fence (L2 inv) executed once per block, immediately after
//       arrival, overlapping the go-wait (polls are device-scope, L2-bypass).
// Math/order identical to r5-r8 (absmax 0.03125 proven).
// ---------------------------------------------------------------------------

#define B_ 128
#define T_ 100
#define E_ 128
#define F_ 700
#define S_ 400
#define V_ 10000

#define FP_ 704    // F padded
#define SP_ 416    // S padded
#define G_  256    // mega blocks
#define TPB_ 512   // threads per mega block (8 waves)
#define NW_ (G_ * 8)

using v8s = __attribute__((ext_vector_type(8))) short;
using v4f = __attribute__((ext_vector_type(4))) float;
typedef unsigned short u16;

#define NTS(p, v) __builtin_nontemporal_store((v), (p))
#define NTL(p)    __builtin_nontemporal_load((p))

__device__ __forceinline__ u16 f2bf(float x) {
    unsigned int u = __float_as_uint(x);
    u += 0x7FFFu + ((u >> 16) & 1u);
    return (u16)(u >> 16);
}
__device__ __forceinline__ float bf2f(u16 h) {
    return __uint_as_float(((unsigned int)h) << 16);
}
__device__ __forceinline__ void split3f(float x, u16& h, u16& m, u16& l) {
    h = f2bf(x); float r  = x - bf2f(h);
    m = f2bf(r); float r2 = r - bf2f(m);
    l = f2bf(r2);
}
__device__ __forceinline__ float sigm(float x) { return 1.0f / (1.0f + expf(-x)); }

// ---------------------------------------------------------------------------
// Grid barrier, fence-lean:
//   __syncthreads (drains each wave's stores; nt stores are already
//   write-through) -> tid0: release fence + arrive store + acquire fence
//   (L2/L1 inv overlaps the wait; no other line touched until go) ->
//   block0 gathers flags RELAXED, publishes go (release) -> others poll go
//   RELAXED (device-scope, L2-bypass) -> __syncthreads orders the block.
// ---------------------------------------------------------------------------
__device__ __forceinline__ void gbar(unsigned* flags, unsigned* go, unsigned target) {
    __syncthreads();
    if (threadIdx.x == 0) {
        __threadfence();   // release (wbl2: ~empty thanks to nt stores)
        __hip_atomic_store(flags + (size_t)blockIdx.x * 16, target,
                           __ATOMIC_RELEASE, __HIP_MEMORY_SCOPE_AGENT);
        __threadfence();   // acquire early: inv L1/L2 now, overlap the wait
    }
    if (blockIdx.x == 0) {
        if (threadIdx.x < G_) {
            const unsigned* f = flags + (size_t)threadIdx.x * 16;
            while (__hip_atomic_load(f, __ATOMIC_RELAXED, __HIP_MEMORY_SCOPE_AGENT) < target)
                __builtin_amdgcn_s_sleep(1);
        }
        __syncthreads();
        if (threadIdx.x == 0)
            __hip_atomic_store(go, target, __ATOMIC_RELEASE, __HIP_MEMORY_SCOPE_AGENT);
    } else {
        if (threadIdx.x == 0) {
            while (__hip_atomic_load(go, __ATOMIC_RELAXED, __HIP_MEMORY_SCOPE_AGENT) < target)
                __builtin_amdgcn_s_sleep(1);
        }
    }
    __syncthreads();
}

// ---------------------------------------------------------------------------
// Standalone transpose+split kernels (r5-proven; full-coverage writes).
// ---------------------------------------------------------------------------
__global__ __launch_bounds__(256) void wtrans3(
    const float* __restrict__ W, int K, int N,
    u16* __restrict__ WtH, u16* __restrict__ WtM, u16* __restrict__ WtL,
    int Kp, int K1, int K1pad)
{
    __shared__ float t[32][33];
    const int c0 = blockIdx.x * 32, kp0 = blockIdx.y * 32;
    const int tx = threadIdx.x & 31, ty = threadIdx.x >> 5;
    #pragma unroll
    for (int i = 0; i < 4; ++i) {
        int kpos = kp0 + ty + i * 8, c = c0 + tx;
        int k = (kpos < K1) ? kpos : (kpos >= K1pad ? K1 + (kpos - K1pad) : -1);
        t[ty + i * 8][tx] = (k >= 0 && k < K && c < N) ? W[(size_t)k * N + c] : 0.f;
    }
    __syncthreads();
    #pragma unroll
    for (int i = 0; i < 4; ++i) {
        int r = c0 + ty + i * 8;
        u16 h, m, l;
        split3f(t[tx][ty + i * 8], h, m, l);
        size_t idx = (size_t)r * Kp + kp0 + tx;
        WtH[idx] = h; WtM[idx] = m; WtL[idx] = l;
    }
}

__global__ __launch_bounds__(256) void wtrans(
    const float* __restrict__ W, int K, int N,
    u16* __restrict__ Wt, int Kpad)
{
    __shared__ float t[32][33];
    const int c0 = blockIdx.x * 32, k0 = blockIdx.y * 32;
    const int tx = threadIdx.x & 31, ty = threadIdx.x >> 5;
    #pragma unroll
    for (int i = 0; i < 4; ++i) {
        int k = k0 + ty + i * 8, c = c0 + tx;
        t[ty + i * 8][tx] = (k < K && c < N) ? W[(size_t)k * N + c] : 0.f;
    }
    __syncthreads();
    #pragma unroll
    for (int i = 0; i < 4; ++i) {
        int r = c0 + ty + i * 8;
        Wt[(size_t)r * Kpad + k0 + tx] = f2bf(t[tx][ty + i * 8]);
    }
}

// ---------------------------------------------------------------------------
// zx precompute: zx[t][b][col] = x[b,t,:] @ W0[:128,col] + b0[col]  (r7-proven)
// ---------------------------------------------------------------------------
__global__ __launch_bounds__(512, 2) void zxpre(
    const float* __restrict__ inputs,
    const u16* __restrict__ WH, const u16* __restrict__ WM,
    const u16* __restrict__ WL, const float* __restrict__ b0,
    float* __restrict__ zx)
{
    const int lane = threadIdx.x & 63, wid = threadIdx.x >> 6;
    const int lo = lane & 15, hi = lane >> 4;
    const int ntiles = 175 * 100;
    for (int i = blockIdx.x * 8 + wid; i < ntiles; i += gridDim.x * 8) {
        const int t = i / 175, ct = i % 175;
        v4f acc[8];
        #pragma unroll
        for (int m = 0; m < 8; ++m) acc[m] = (v4f)0.f;
        const size_t bb = (size_t)(ct * 16 + lo) * 832 + hi * 8;
        for (int kt = 0; kt < 4; ++kt) {
            const size_t bo = bb + kt * 32;
            v8s bh = *(const v8s*)(WH + bo);
            v8s bm = *(const v8s*)(WM + bo);
            v8s bl = *(const v8s*)(WL + bo);
            #pragma unroll
            for (int m = 0; m < 8; ++m) {
                const float* p = inputs + (size_t)(m * 16 + lo) * (T_ * E_)
                               + (size_t)t * E_ + kt * 32 + hi * 8;
                float v0[8];
                *(float4*)(v0)     = *(const float4*)(p);
                *(float4*)(v0 + 4) = *(const float4*)(p + 4);
                v8s ah, am, al;
                #pragma unroll
                for (int j = 0; j < 8; ++j) {
                    u16 H, M, L; split3f(v0[j], H, M, L);
                    ah[j] = (short)H; am[j] = (short)M; al[j] = (short)L;
                }
                acc[m] = __builtin_amdgcn_mfma_f32_16x16x32_bf16(ah, bh, acc[m], 0, 0, 0);
                acc[m] = __builtin_amdgcn_mfma_f32_16x16x32_bf16(ah, bm, acc[m], 0, 0, 0);
                acc[m] = __builtin_amdgcn_mfma_f32_16x16x32_bf16(am, bh, acc[m], 0, 0, 0);
                acc[m] = __builtin_amdgcn_mfma_f32_16x16x32_bf16(ah, bl, acc[m], 0, 0, 0);
                acc[m] = __builtin_amdgcn_mfma_f32_16x16x32_bf16(al, bh, acc[m], 0, 0, 0);
                acc[m] = __builtin_amdgcn_mfma_f32_16x16x32_bf16(am, bm, acc[m], 0, 0, 0);
            }
        }
        const int col = ct * 16 + lo;
        const float bb0 = b0[col];
        #pragma unroll
        for (int m = 0; m < 8; ++m)
            #pragma unroll
            for (int r = 0; r < 4; ++r) {
                int row = m * 16 + hi * 4 + r;
                NTS(&zx[((size_t)t * B_ + row) * 2800 + col], acc[m][r] + bb0);
            }
    }
}

// ---------------------------------------------------------------------------
// GEMM phase: Z[128,N] = concat(A1,A2) @ Wt^T (+ bias | + zadd).
// Per-wave 16-col x 64-row tile; depth-4 B ring + ping-pong A prefetch
// (r8-proven). z written nontemporal; zadd read nontemporal.
// ---------------------------------------------------------------------------
__device__ void gemm_phase(
    const u16* __restrict__ A1H, const u16* __restrict__ A1M,
    const u16* __restrict__ A1L, int lda1, int K1pad,
    const u16* __restrict__ A2H, const u16* __restrict__ A2M,
    const u16* __restrict__ A2L, int lda2,
    const u16* __restrict__ WH, const u16* __restrict__ WM,
    const u16* __restrict__ WL, int Kp, int NT,
    const float* __restrict__ bias, const float* __restrict__ zadd,
    float* __restrict__ z, int N)
{
    const int lane = threadIdx.x & 63, wid = threadIdx.x >> 6;
    const int lo = lane & 15, hi = lane >> 4;
    const int ntiles = (N >> 4) * 2;
    for (int i = wid * G_ + blockIdx.x; i < ntiles; i += NW_) {
        const int ct = i >> 1, r0 = (i & 1) * 64;
        v4f acc[4];
        #pragma unroll
        for (int m = 0; m < 4; ++m) acc[m] = (v4f)0.f;

        const size_t bb = (size_t)(ct * 16 + lo) * Kp + hi * 8;

        v8s BH[4], BM[4], BL[4];
        #pragma unroll
        for (int j = 0; j < 4; ++j) {
            const size_t o = bb + (size_t)((j < NT) ? j : 0) * 32;
            BH[j] = *(const v8s*)(WH + o);
            BM[j] = *(const v8s*)(WM + o);
            BL[j] = *(const v8s*)(WL + o);
        }
        v8s AH[2][4], AM[2][4], AL[2][4];
        #pragma unroll
        for (int m = 0; m < 4; ++m) {
            size_t ao = (size_t)(r0 + m * 16 + lo) * lda1 + hi * 8;
            AH[0][m] = *(const v8s*)(A1H + ao);
            AM[0][m] = *(const v8s*)(A1M + ao);
            AL[0][m] = *(const v8s*)(A1L + ao);
        }

        for (int kt0 = 0; kt0 < NT; kt0 += 4) {
            #pragma unroll
            for (int j = 0; j < 4; ++j) {
                const int kt = kt0 + j;
                if (kt < NT) {
                    const int cb = j & 1, nb = (j & 1) ^ 1;
                    const int ka = kt + 1;
                    if (ka < NT) {
                        const int kb2 = ka * 32;
                        const bool s1 = kb2 < K1pad;
                        const u16* pH = s1 ? A1H : A2H;
                        const u16* pM = s1 ? A1M : A2M;
                        const u16* pL = s1 ? A1L : A2L;
                        const int lda = s1 ? lda1 : lda2;
                        const int ko = s1 ? kb2 : kb2 - K1pad;
                        #pragma unroll
                        for (int m = 0; m < 4; ++m) {
                            size_t ao = (size_t)(r0 + m * 16 + lo) * lda + ko + hi * 8;
                            AH[nb][m] = *(const v8s*)(pH + ao);
                            AM[nb][m] = *(const v8s*)(pM + ao);
                            AL[nb][m] = *(const v8s*)(pL + ao);
                        }
                    }
                    #pragma unroll
                    for (int m = 0; m < 4; ++m) {
                        acc[m] = __builtin_amdgcn_mfma_f32_16x16x32_bf16(AH[cb][m], BH[j], acc[m], 0, 0, 0);
                        acc[m] = __builtin_amdgcn_mfma_f32_16x16x32_bf16(AH[cb][m], BM[j], acc[m], 0, 0, 0);
                        acc[m] = __builtin_amdgcn_mfma_f32_16x16x32_bf16(AM[cb][m], BH[j], acc[m], 0, 0, 0);
                        acc[m] = __builtin_amdgcn_mfma_f32_16x16x32_bf16(AH[cb][m], BL[j], acc[m], 0, 0, 0);
                        acc[m] = __builtin_amdgcn_mfma_f32_16x16x32_bf16(AL[cb][m], BH[j], acc[m], 0, 0, 0);
                        acc[m] = __builtin_amdgcn_mfma_f32_16x16x32_bf16(AM[cb][m], BM[j], acc[m], 0, 0, 0);
                    }
                    const int kn = kt + 4;
                    if (kn < NT) {
                        const size_t o = bb + (size_t)kn * 32;
                        BH[j] = *(const v8s*)(WH + o);
                        BM[j] = *(const v8s*)(WM + o);
                        BL[j] = *(const v8s*)(WL + o);
                    }
                }
            }
        }

        const int col = ct * 16 + lo;
        if (zadd) {
            #pragma unroll
            for (int m = 0; m < 4; ++m)
                #pragma unroll
                for (int r = 0; r < 4; ++r) {
                    int row = r0 + m * 16 + hi * 4 + r;
                    float za = NTL(&zadd[(size_t)row * N + col]);
                    NTS(&z[(size_t)row * N + col], acc[m][r] + za);
                }
        } else {
            const float bv = bias[col];
            #pragma unroll
            for (int m = 0; m < 4; ++m)
                #pragma unroll
                for (int r = 0; r < 4; ++r) {
                    int row = r0 + m * 16 + hi * 4 + r;
                    NTS(&z[(size_t)row * N + col], acc[m][r] + bv);
                }
        }
    }
}

// Block-wide sum over 512 threads (8 waves), broadcast.
__device__ __forceinline__ float blockSum(float v, volatile float* red) {
    #pragma unroll
    for (int off = 32; off > 0; off >>= 1) v += __shfl_down(v, off, 64);
    int w = threadIdx.x >> 6, lane = threadIdx.x & 63;
    __syncthreads();
    if (lane == 0) red[w] = v;
    __syncthreads();
    float r = 0.f;
    #pragma unroll
    for (int j = 0; j < 8; ++j) r += red[j];
    return r;
}

// ---------------------------------------------------------------------------
// Pointwise phase (512 thr): LN4 + gates + c-LN + zoneout; one row/block.
// z read nontemporal; all state/plane/hist writes nontemporal.
// ---------------------------------------------------------------------------
template <int FF>
__device__ void pw_phase(const float* __restrict__ z,
    const float* __restrict__ gg, const float* __restrict__ bg,
    const float* __restrict__ gc, const float* __restrict__ bc,
    float* __restrict__ h, float* __restrict__ c,
    u16* __restrict__ hpH, u16* __restrict__ hpM, u16* __restrict__ hpL,
    int hstride, u16* __restrict__ hist, int t, volatile float* red)
{
    const int tid = threadIdx.x;
    constexpr int NU = (FF + TPB_ - 1) / TPB_;
    for (int b = blockIdx.x; b < B_; b += G_) {
        const float* zr = z + (size_t)b * 4 * FF;
        float* hr = h + (size_t)b * FF;
        float* cr = c + (size_t)b * FF;

        float s[4] = {0, 0, 0, 0}, q[4] = {0, 0, 0, 0};
        #pragma unroll
        for (int i = 0; i < NU; ++i) {
            int u = tid + i * TPB_;
            if (u < FF) {
                #pragma unroll
                for (int g = 0; g < 4; ++g) {
                    float v = NTL(&zr[g * FF + u]);
                    s[g] += v; q[g] += v * v;
                }
            }
        }
        float mu[4], rs[4];
        #pragma unroll
        for (int g = 0; g < 4; ++g) {
            float S = blockSum(s[g], red);
            float Q = blockSum(q[g], red);
            mu[g] = S / FF;
            rs[g] = rsqrtf(Q / FF - mu[g] * mu[g] + 1e-5f);
        }

        float nc[NU], og[NU], ho[NU], co[NU];
        float cs = 0.f, cq = 0.f;
        #pragma unroll
        for (int i = 0; i < NU; ++i) {
            int u = tid + i * TPB_;
            if (u < FF) {
                float zi = (NTL(&zr[u])          - mu[0]) * rs[0] * gg[u]          + bg[u];
                float zj = (NTL(&zr[FF + u])     - mu[1]) * rs[1] * gg[FF + u]     + bg[FF + u];
                float zf = (NTL(&zr[2 * FF + u]) - mu[2]) * rs[2] * gg[2 * FF + u] + bg[2 * FF + u];
                float zo = (NTL(&zr[3 * FF + u]) - mu[3]) * rs[3] * gg[3 * FF + u] + bg[3 * FF + u];
                float cold = cr[u];
                float ncv = cold * sigm(zf + 1.0f) + sigm(zi) * tanhf(zj);
                nc[i] = ncv; og[i] = sigm(zo); co[i] = cold; ho[i] = hr[u];
                cs += ncv; cq += ncv * ncv;
            } else { nc[i] = 0.f; og[i] = 0.f; co[i] = 0.f; ho[i] = 0.f; }
        }
        float CS = blockSum(cs, red);
        float CQ = blockSum(cq, red);
        float muc = CS / FF;
        float rsc = rsqrtf(CQ / FF - muc * muc + 1e-5f);

        #pragma unroll
        for (int i = 0; i < NU; ++i) {
            int u = tid + i * TPB_;
            if (u < FF) {
                float nh = tanhf((nc[i] - muc) * rsc * gc[u] + bc[u]) * og[i];
                float hout = 0.9f * nh + 0.1f * ho[i];
                float cout = 0.5f * nc[i] + 0.5f * co[i];
                NTS(&hr[u], hout);
                NTS(&cr[u], cout);
                u16 H, M, L;
                split3f(hout, H, M, L);
                size_t po = (size_t)b * hstride + u;
                NTS(&hpH[po], H); NTS(&hpM[po], M); NTS(&hpL[po], L);
                if (hist) NTS(&hist[((size_t)b * T_ + t) * FP_ + u], H);
            }
        }
        if (hist && tid < FP_ - FF)
            NTS(&hist[((size_t)b * T_ + t) * FP_ + FF + tid], (u16)0);
    }
}

// ---------------------------------------------------------------------------
// Mega: init -> 100 x (GEMM0|PW0|GEMMS|PWS|GEMM1|PW1) -> states tail.
// ---------------------------------------------------------------------------
__global__ __launch_bounds__(TPB_, 2) void mega(
    const float* __restrict__ b0, const float* __restrict__ g0,
    const float* __restrict__ bg0, const float* __restrict__ gc0,
    const float* __restrict__ bc0,
    const float* __restrict__ b1, const float* __restrict__ g1,
    const float* __restrict__ bg1, const float* __restrict__ gc1,
    const float* __restrict__ bc1,
    const float* __restrict__ bS, const float* __restrict__ gS,
    const float* __restrict__ bgS, const float* __restrict__ gcS,
    const float* __restrict__ bcS,
    const float* __restrict__ zx,
    float* fh, float* fc, float* sh, float* sc, float* z, u16* hist,
    u16* fhH, u16* fhM, u16* fhL, u16* shH, u16* shM, u16* shL,
    u16* W0H, u16* W0M, u16* W0L, u16* WSH, u16* WSM, u16* WSL,
    u16* W1H, u16* W1M, u16* W1L,
    float* outTail, unsigned* flags, unsigned* go)
{
    __shared__ float red[8];
    const int gtid = blockIdx.x * TPB_ + threadIdx.x;
    unsigned tgt = 0;

    // init: zero f32 states and h/s planes (nontemporal)
    for (int i = gtid; i < 2 * B_ * F_ + 2 * B_ * S_; i += G_ * TPB_) NTS(&fh[i], 0.f);
    for (int i = gtid; i < 3 * B_ * FP_ + 3 * B_ * SP_; i += G_ * TPB_) NTS(&fhH[i], (u16)0);
    gbar(flags, go, ++tgt);

    for (int t = 0; t < T_; ++t) {
        // cell 0 (h-part only; x-part precomputed in zx): K=704
        gemm_phase(fhH, fhM, fhL, FP_, FP_, fhH, fhM, fhL, FP_,
                   W0H + 128, W0M + 128, W0L + 128, 832, FP_ / 32,
                   nullptr, zx + (size_t)t * B_ * 2800, z, 4 * F_);
        gbar(flags, go, ++tgt);
        pw_phase<F_>(z, g0, bg0, gc0, bc0, fh, fc, fhH, fhM, fhL, FP_, nullptr, 0, red);
        gbar(flags, go, ++tgt);
        // slow: A = [fh | sh], K = 1120
        gemm_phase(fhH, fhM, fhL, FP_, FP_, shH, shM, shL, SP_,
                   WSH, WSM, WSL, 1120, 1120 / 32, bS, nullptr, z, 4 * S_);
        gbar(flags, go, ++tgt);
        pw_phase<S_>(z, gS, bgS, gcS, bcS, sh, sc, shH, shM, shL, SP_, nullptr, 0, red);
        gbar(flags, go, ++tgt);
        // cell 1: A = [sh | fh], K = 1120
        gemm_phase(shH, shM, shL, SP_, SP_, fhH, fhM, fhL, FP_,
                   W1H, W1M, W1L, 1120, 1120 / 32, b1, nullptr, z, 4 * F_);
        gbar(flags, go, ++tgt);
        pw_phase<F_>(z, g1, bg1, gc1, bc1, fh, fc, fhH, fhM, fhL, FP_, hist, t, red);
        gbar(flags, go, ++tgt);
    }

    // tail: final states -> d_out tail
    const int NF = B_ * F_, NS = B_ * S_;
    for (int i = gtid; i < 2 * NF + 2 * NS; i += G_ * TPB_) {
        float v = (i < NF) ? fh[i] : (i < 2 * NF) ? fc[i - NF]
                : (i < 2 * NF + NS) ? sh[i - 2 * NF] : sc[i - 2 * NF - NS];
        NTS(&outTail[i], v);
    }
}

// ---------------------------------------------------------------------------
// Output projection (r5-proven): C = hist[12800,704] @ Wtout^T + bout
// ---------------------------------------------------------------------------
__global__ __launch_bounds__(512) void ogemm(
    const u16* __restrict__ A, const u16* __restrict__ Bt,
    const float* __restrict__ bias, float* __restrict__ C)
{
    const int N = V_;
    const int tid = threadIdx.x, lane = tid & 63, wid = tid >> 6;
    const int wm = wid >> 1, wn = wid & 1;
    const int row0 = blockIdx.y * 256 + wm * 64;
    const int col0 = blockIdx.x * 128 + wn * 64;
    const int lo = lane & 15, hi = lane >> 4;
    const int NT = FP_ / 32;

    v4f acc[4][4];
    #pragma unroll
    for (int i = 0; i < 4; ++i)
        #pragma unroll
        for (int j = 0; j < 4; ++j) acc[i][j] = (v4f)0.f;

    for (int kt = 0; kt < NT; ++kt) {
        const int kb = kt * 32 + hi * 8;
        v8s a[4], b[4];
        #pragma unroll
        for (int i = 0; i < 4; ++i) {
            a[i] = *(const v8s*)(A  + (size_t)(row0 + i * 16 + lo) * FP_ + kb);
            b[i] = *(const v8s*)(Bt + (size_t)(col0 + i * 16 + lo) * FP_ + kb);
        }
        #pragma unroll
        for (int mf = 0; mf < 4; ++mf)
            #pragma unroll
            for (int nf = 0; nf < 4; ++nf)
                acc[mf][nf] = __builtin_amdgcn_mfma_f32_16x16x32_bf16(a[mf], b[nf], acc[mf][nf], 0, 0, 0);
    }

    #pragma unroll
    for (int mf = 0; mf < 4; ++mf) {
        #pragma unroll
        for (int nf = 0; nf < 4; ++nf) {
            int col = col0 + nf * 16 + lo;
            if (col < N) {
                float bb = bias[col];
                #pragma unroll
                for (int r = 0; r < 4; ++r) {
                    int row = row0 + mf * 16 + hi * 4 + r;
                    C[(size_t)row * N + col] = acc[mf][nf][r] + bb;
                }
            }
        }
    }
}

extern "C" void kernel_launch(void* const* d_in, const int* in_sizes, int n_in,
                              void* d_out, int out_size, void* d_ws, size_t ws_size,
                              hipStream_t stream) {
    const float* inputs = (const float*)d_in[0];
    const float* W0   = (const float*)d_in[1];
    const float* b0   = (const float*)d_in[2];
    const float* g0   = (const float*)d_in[3];
    const float* bg0  = (const float*)d_in[4];
    const float* gc0  = (const float*)d_in[5];
    const float* bc0  = (const float*)d_in[6];
    const float* W1   = (const float*)d_in[7];
    const float* b1   = (const float*)d_in[8];
    const float* g1   = (const float*)d_in[9];
    const float* bg1  = (const float*)d_in[10];
    const float* gc1  = (const float*)d_in[11];
    const float* bc1  = (const float*)d_in[12];
    const float* WS   = (const float*)d_in[13];
    const float* bS   = (const float*)d_in[14];
    const float* gS   = (const float*)d_in[15];
    const float* bgS  = (const float*)d_in[16];
    const float* gcS  = (const float*)d_in[17];
    const float* bcS  = (const float*)d_in[18];
    const float* Wout = (const float*)d_in[19];
    const float* bout = (const float*)d_in[20];

    // ---- ws: states + z + hist + Wtout + flags/go (~34.9 MB, known-safe)
    float* ws = (float*)d_ws;
    float* fh = ws;
    float* fc = fh + B_ * F_;
    float* sh = fc + B_ * F_;
    float* sc = sh + B_ * S_;
    float* z  = sc + B_ * S_;
    u16* hist = (u16*)(z + (size_t)B_ * 4 * F_);
    u16* Wtout = hist + (size_t)12800 * FP_;
    unsigned* flags = (unsigned*)(Wtout + (size_t)10112 * FP_);   // G_*16 u32
    unsigned* go    = flags + G_ * 16;                            // own line

    // ---- d_out scratch (fully rewritten every call; dead before ogemm)
    const size_t P0 = (size_t)2816 * 832;
    const size_t PS = (size_t)1664 * 1120;
    const size_t P1 = (size_t)2816 * 1120;
    const size_t HF = (size_t)B_ * FP_;
    const size_t HS = (size_t)B_ * SP_;
    u16* dp  = (u16*)d_out;
    u16* W0H = dp;          u16* W0M = W0H + P0;  u16* W0L = W0M + P0;
    u16* WSH = W0L + P0;    u16* WSM = WSH + PS;  u16* WSL = WSM + PS;
    u16* W1H = WSL + PS;    u16* W1M = W1H + P1;  u16* W1L = W1M + P1;
    u16* fhH = W1L + P1;    u16* fhM = fhH + HF;  u16* fhL = fhM + HF;
    u16* shH = fhL + HF;    u16* shM = shH + HS;  u16* shL = shM + HS;
    float* zx = (float*)(shL + HS);               // 143.4 MB

    hipMemsetAsync(flags, 0, (G_ * 16 + 16) * sizeof(unsigned), stream);

    // weight transposes+splits
    wtrans3<<<dim3(88, 26), 256, 0, stream>>>(W0, E_ + F_, 4 * F_, W0H, W0M, W0L, 832, 128, 128);
    wtrans3<<<dim3(52, 35), 256, 0, stream>>>(WS, F_ + S_, 4 * S_, WSH, WSM, WSL, 1120, F_, FP_);
    wtrans3<<<dim3(88, 35), 256, 0, stream>>>(W1, S_ + F_, 4 * F_, W1H, W1M, W1L, 1120, S_, SP_);
    wtrans<<<dim3(316, 22), 256, 0, stream>>>(Wout, F_, V_, Wtout, FP_);

    // x-projection for all t (parallel)
    zxpre<<<2188, 512, 0, stream>>>(inputs, W0H, W0M, W0L, b0, zx);

    // recurrence
    mega<<<G_, TPB_, 0, stream>>>(
        b0, g0, bg0, gc0, bc0,
        b1, g1, bg1, gc1, bc1,
        bS, gS, bgS, gcS, bcS,
        zx,
        fh, fc, sh, sc, z, hist,
        fhH, fhM, fhL, shH, shM, shL,
        W0H, W0M, W0L, WSH, WSM, WSL, W1H, W1M, W1L,
        (float*)d_out + (size_t)B_ * T_ * V_, flags, go);

    // logits
    ogemm<<<dim3(79, 50), 512, 0, stream>>>(hist, Wtout, bout, (float*)d_out);
}

// Round 10
// 18917.728 us; speedup vs baseline: 2.7288x; 1.0009x over previous
//
#include <hip/hip_runtime.h>
#include <math.h>

// ---------------------------------------------------------------------------
// PTB LN-LSTM stack: B=128, T=100, E=128, F=700, S=400, V=10000.
// Round 10: fix the r8/r9 register-SPILL traffic. launch_bounds(512,2) capped
// VGPRs at 128; the depth-4 B-ring + A ping-pong (~200 regs live) spilled to
// scratch -> ~4.3GB extra WRITE + ~2GB extra FETCH per run (r7 wrote 0.7GB,
// r8/r9 wrote 5.01GB with identical logical stores). A 512-thread block is
// structurally 2 waves/SIMD, so (512,1) gives a 256-VGPR budget at the SAME
// occupancy. No arithmetic change: absmax must remain 0.03125.
// ---------------------------------------------------------------------------

#define B_ 128
#define T_ 100
#define E_ 128
#define F_ 700
#define S_ 400
#define V_ 10000

#define FP_ 704    // F padded
#define SP_ 416    // S padded
#define G_  256    // mega blocks
#define TPB_ 512   // threads per mega block (8 waves)
#define NW_ (G_ * 8)

using v8s = __attribute__((ext_vector_type(8))) short;
using v4f = __attribute__((ext_vector_type(4))) float;
typedef unsigned short u16;

#define NTS(p, v) __builtin_nontemporal_store((v), (p))
#define NTL(p)    __builtin_nontemporal_load((p))

__device__ __forceinline__ u16 f2bf(float x) {
    unsigned int u = __float_as_uint(x);
    u += 0x7FFFu + ((u >> 16) & 1u);
    return (u16)(u >> 16);
}
__device__ __forceinline__ float bf2f(u16 h) {
    return __uint_as_float(((unsigned int)h) << 16);
}
__device__ __forceinline__ void split3f(float x, u16& h, u16& m, u16& l) {
    h = f2bf(x); float r  = x - bf2f(h);
    m = f2bf(r); float r2 = r - bf2f(m);
    l = f2bf(r2);
}
__device__ __forceinline__ float sigm(float x) { return 1.0f / (1.0f + expf(-x)); }

// ---------------------------------------------------------------------------
// Grid barrier (r9-proven): release + arrive, early acquire overlapping the
// wait; block0 gathers RELAXED, publishes go; others poll go RELAXED.
// ---------------------------------------------------------------------------
__device__ __forceinline__ void gbar(unsigned* flags, unsigned* go, unsigned target) {
    __syncthreads();
    if (threadIdx.x == 0) {
        __threadfence();   // release
        __hip_atomic_store(flags + (size_t)blockIdx.x * 16, target,
                           __ATOMIC_RELEASE, __HIP_MEMORY_SCOPE_AGENT);
        __threadfence();   // acquire early: inv overlaps the wait
    }
    if (blockIdx.x == 0) {
        if (threadIdx.x < G_) {
            const unsigned* f = flags + (size_t)threadIdx.x * 16;
            while (__hip_atomic_load(f, __ATOMIC_RELAXED, __HIP_MEMORY_SCOPE_AGENT) < target)
                __builtin_amdgcn_s_sleep(1);
        }
        __syncthreads();
        if (threadIdx.x == 0)
            __hip_atomic_store(go, target, __ATOMIC_RELEASE, __HIP_MEMORY_SCOPE_AGENT);
    } else {
        if (threadIdx.x == 0) {
            while (__hip_atomic_load(go, __ATOMIC_RELAXED, __HIP_MEMORY_SCOPE_AGENT) < target)
                __builtin_amdgcn_s_sleep(1);
        }
    }
    __syncthreads();
}

// ---------------------------------------------------------------------------
// Standalone transpose+split kernels (r5-proven; full-coverage writes).
// ---------------------------------------------------------------------------
__global__ __launch_bounds__(256) void wtrans3(
    const float* __restrict__ W, int K, int N,
    u16* __restrict__ WtH, u16* __restrict__ WtM, u16* __restrict__ WtL,
    int Kp, int K1, int K1pad)
{
    __shared__ float t[32][33];
    const int c0 = blockIdx.x * 32, kp0 = blockIdx.y * 32;
    const int tx = threadIdx.x & 31, ty = threadIdx.x >> 5;
    #pragma unroll
    for (int i = 0; i < 4; ++i) {
        int kpos = kp0 + ty + i * 8, c = c0 + tx;
        int k = (kpos < K1) ? kpos : (kpos >= K1pad ? K1 + (kpos - K1pad) : -1);
        t[ty + i * 8][tx] = (k >= 0 && k < K && c < N) ? W[(size_t)k * N + c] : 0.f;
    }
    __syncthreads();
    #pragma unroll
    for (int i = 0; i < 4; ++i) {
        int r = c0 + ty + i * 8;
        u16 h, m, l;
        split3f(t[tx][ty + i * 8], h, m, l);
        size_t idx = (size_t)r * Kp + kp0 + tx;
        WtH[idx] = h; WtM[idx] = m; WtL[idx] = l;
    }
}

__global__ __launch_bounds__(256) void wtrans(
    const float* __restrict__ W, int K, int N,
    u16* __restrict__ Wt, int Kpad)
{
    __shared__ float t[32][33];
    const int c0 = blockIdx.x * 32, k0 = blockIdx.y * 32;
    const int tx = threadIdx.x & 31, ty = threadIdx.x >> 5;
    #pragma unroll
    for (int i = 0; i < 4; ++i) {
        int k = k0 + ty + i * 8, c = c0 + tx;
        t[ty + i * 8][tx] = (k < K && c < N) ? W[(size_t)k * N + c] : 0.f;
    }
    __syncthreads();
    #pragma unroll
    for (int i = 0; i < 4; ++i) {
        int r = c0 + ty + i * 8;
        Wt[(size_t)r * Kpad + k0 + tx] = f2bf(t[tx][ty + i * 8]);
    }
}

// ---------------------------------------------------------------------------
// zx precompute: zx[t][b][col] = x[b,t,:] @ W0[:128,col] + b0[col]
// (512,1): 256-VGPR budget, no spill.
// ---------------------------------------------------------------------------
__global__ __launch_bounds__(512, 1) void zxpre(
    const float* __restrict__ inputs,
    const u16* __restrict__ WH, const u16* __restrict__ WM,
    const u16* __restrict__ WL, const float* __restrict__ b0,
    float* __restrict__ zx)
{
    const int lane = threadIdx.x & 63, wid = threadIdx.x >> 6;
    const int lo = lane & 15, hi = lane >> 4;
    const int ntiles = 175 * 100;
    for (int i = blockIdx.x * 8 + wid; i < ntiles; i += gridDim.x * 8) {
        const int t = i / 175, ct = i % 175;
        v4f acc[8];
        #pragma unroll
        for (int m = 0; m < 8; ++m) acc[m] = (v4f)0.f;
        const size_t bb = (size_t)(ct * 16 + lo) * 832 + hi * 8;
        for (int kt = 0; kt < 4; ++kt) {
            const size_t bo = bb + kt * 32;
            v8s bh = *(const v8s*)(WH + bo);
            v8s bm = *(const v8s*)(WM + bo);
            v8s bl = *(const v8s*)(WL + bo);
            #pragma unroll
            for (int m = 0; m < 8; ++m) {
                const float* p = inputs + (size_t)(m * 16 + lo) * (T_ * E_)
                               + (size_t)t * E_ + kt * 32 + hi * 8;
                float v0[8];
                *(float4*)(v0)     = *(const float4*)(p);
                *(float4*)(v0 + 4) = *(const float4*)(p + 4);
                v8s ah, am, al;
                #pragma unroll
                for (int j = 0; j < 8; ++j) {
                    u16 H, M, L; split3f(v0[j], H, M, L);
                    ah[j] = (short)H; am[j] = (short)M; al[j] = (short)L;
                }
                acc[m] = __builtin_amdgcn_mfma_f32_16x16x32_bf16(ah, bh, acc[m], 0, 0, 0);
                acc[m] = __builtin_amdgcn_mfma_f32_16x16x32_bf16(ah, bm, acc[m], 0, 0, 0);
                acc[m] = __builtin_amdgcn_mfma_f32_16x16x32_bf16(am, bh, acc[m], 0, 0, 0);
                acc[m] = __builtin_amdgcn_mfma_f32_16x16x32_bf16(ah, bl, acc[m], 0, 0, 0);
                acc[m] = __builtin_amdgcn_mfma_f32_16x16x32_bf16(al, bh, acc[m], 0, 0, 0);
                acc[m] = __builtin_amdgcn_mfma_f32_16x16x32_bf16(am, bm, acc[m], 0, 0, 0);
            }
        }
        const int col = ct * 16 + lo;
        const float bb0 = b0[col];
        #pragma unroll
        for (int m = 0; m < 8; ++m)
            #pragma unroll
            for (int r = 0; r < 4; ++r) {
                int row = m * 16 + hi * 4 + r;
                NTS(&zx[((size_t)t * B_ + row) * 2800 + col], acc[m][r] + bb0);
            }
    }
}

// ---------------------------------------------------------------------------
// GEMM phase (r8 structure, now spill-free): depth-4 B ring + A ping-pong.
// ---------------------------------------------------------------------------
__device__ void gemm_phase(
    const u16* __restrict__ A1H, const u16* __restrict__ A1M,
    const u16* __restrict__ A1L, int lda1, int K1pad,
    const u16* __restrict__ A2H, const u16* __restrict__ A2M,
    const u16* __restrict__ A2L, int lda2,
    const u16* __restrict__ WH, const u16* __restrict__ WM,
    const u16* __restrict__ WL, int Kp, int NT,
    const float* __restrict__ bias, const float* __restrict__ zadd,
    float* __restrict__ z, int N)
{
    const int lane = threadIdx.x & 63, wid = threadIdx.x >> 6;
    const int lo = lane & 15, hi = lane >> 4;
    const int ntiles = (N >> 4) * 2;
    for (int i = wid * G_ + blockIdx.x; i < ntiles; i += NW_) {
        const int ct = i >> 1, r0 = (i & 1) * 64;
        v4f acc[4];
        #pragma unroll
        for (int m = 0; m < 4; ++m) acc[m] = (v4f)0.f;

        const size_t bb = (size_t)(ct * 16 + lo) * Kp + hi * 8;

        v8s BH[4], BM[4], BL[4];
        #pragma unroll
        for (int j = 0; j < 4; ++j) {
            const size_t o = bb + (size_t)((j < NT) ? j : 0) * 32;
            BH[j] = *(const v8s*)(WH + o);
            BM[j] = *(const v8s*)(WM + o);
            BL[j] = *(const v8s*)(WL + o);
        }
        v8s AH[2][4], AM[2][4], AL[2][4];
        #pragma unroll
        for (int m = 0; m < 4; ++m) {
            size_t ao = (size_t)(r0 + m * 16 + lo) * lda1 + hi * 8;
            AH[0][m] = *(const v8s*)(A1H + ao);
            AM[0][m] = *(const v8s*)(A1M + ao);
            AL[0][m] = *(const v8s*)(A1L + ao);
        }

        for (int kt0 = 0; kt0 < NT; kt0 += 4) {
            #pragma unroll
            for (int j = 0; j < 4; ++j) {
                const int kt = kt0 + j;
                if (kt < NT) {
                    const int cb = j & 1, nb = (j & 1) ^ 1;
                    const int ka = kt + 1;
                    if (ka < NT) {
                        const int kb2 = ka * 32;
                        const bool s1 = kb2 < K1pad;
                        const u16* pH = s1 ? A1H : A2H;
                        const u16* pM = s1 ? A1M : A2M;
                        const u16* pL = s1 ? A1L : A2L;
                        const int lda = s1 ? lda1 : lda2;
                        const int ko = s1 ? kb2 : kb2 - K1pad;
                        #pragma unroll
                        for (int m = 0; m < 4; ++m) {
                            size_t ao = (size_t)(r0 + m * 16 + lo) * lda + ko + hi * 8;
                            AH[nb][m] = *(const v8s*)(pH + ao);
                            AM[nb][m] = *(const v8s*)(pM + ao);
                            AL[nb][m] = *(const v8s*)(pL + ao);
                        }
                    }
                    #pragma unroll
                    for (int m = 0; m < 4; ++m) {
                        acc[m] = __builtin_amdgcn_mfma_f32_16x16x32_bf16(AH[cb][m], BH[j], acc[m], 0, 0, 0);
                        acc[m] = __builtin_amdgcn_mfma_f32_16x16x32_bf16(AH[cb][m], BM[j], acc[m], 0, 0, 0);
                        acc[m] = __builtin_amdgcn_mfma_f32_16x16x32_bf16(AM[cb][m], BH[j], acc[m], 0, 0, 0);
                        acc[m] = __builtin_amdgcn_mfma_f32_16x16x32_bf16(AH[cb][m], BL[j], acc[m], 0, 0, 0);
                        acc[m] = __builtin_amdgcn_mfma_f32_16x16x32_bf16(AL[cb][m], BH[j], acc[m], 0, 0, 0);
                        acc[m] = __builtin_amdgcn_mfma_f32_16x16x32_bf16(AM[cb][m], BM[j], acc[m], 0, 0, 0);
                    }
                    const int kn = kt + 4;
                    if (kn < NT) {
                        const size_t o = bb + (size_t)kn * 32;
                        BH[j] = *(const v8s*)(WH + o);
                        BM[j] = *(const v8s*)(WM + o);
                        BL[j] = *(const v8s*)(WL + o);
                    }
                }
            }
        }

        const int col = ct * 16 + lo;
        if (zadd) {
            #pragma unroll
            for (int m = 0; m < 4; ++m)
                #pragma unroll
                for (int r = 0; r < 4; ++r) {
                    int row = r0 + m * 16 + hi * 4 + r;
                    float za = NTL(&zadd[(size_t)row * N + col]);
                    NTS(&z[(size_t)row * N + col], acc[m][r] + za);
                }
        } else {
            const float bv = bias[col];
            #pragma unroll
            for (int m = 0; m < 4; ++m)
                #pragma unroll
                for (int r = 0; r < 4; ++r) {
                    int row = r0 + m * 16 + hi * 4 + r;
                    NTS(&z[(size_t)row * N + col], acc[m][r] + bv);
                }
        }
    }
}

// Block-wide sum over 512 threads (8 waves), broadcast.
__device__ __forceinline__ float blockSum(float v, volatile float* red) {
    #pragma unroll
    for (int off = 32; off > 0; off >>= 1) v += __shfl_down(v, off, 64);
    int w = threadIdx.x >> 6, lane = threadIdx.x & 63;
    __syncthreads();
    if (lane == 0) red[w] = v;
    __syncthreads();
    float r = 0.f;
    #pragma unroll
    for (int j = 0; j < 8; ++j) r += red[j];
    return r;
}

// ---------------------------------------------------------------------------
// Pointwise phase (512 thr): LN4 + gates + c-LN + zoneout; one row/block.
// ---------------------------------------------------------------------------
template <int FF>
__device__ void pw_phase(const float* __restrict__ z,
    const float* __restrict__ gg, const float* __restrict__ bg,
    const float* __restrict__ gc, const float* __restrict__ bc,
    float* __restrict__ h, float* __restrict__ c,
    u16* __restrict__ hpH, u16* __restrict__ hpM, u16* __restrict__ hpL,
    int hstride, u16* __restrict__ hist, int t, volatile float* red)
{
    const int tid = threadIdx.x;
    constexpr int NU = (FF + TPB_ - 1) / TPB_;
    for (int b = blockIdx.x; b < B_; b += G_) {
        const float* zr = z + (size_t)b * 4 * FF;
        float* hr = h + (size_t)b * FF;
        float* cr = c + (size_t)b * FF;

        float s[4] = {0, 0, 0, 0}, q[4] = {0, 0, 0, 0};
        #pragma unroll
        for (int i = 0; i < NU; ++i) {
            int u = tid + i * TPB_;
            if (u < FF) {
                #pragma unroll
                for (int g = 0; g < 4; ++g) {
                    float v = NTL(&zr[g * FF + u]);
                    s[g] += v; q[g] += v * v;
                }
            }
        }
        float mu[4], rs[4];
        #pragma unroll
        for (int g = 0; g < 4; ++g) {
            float S = blockSum(s[g], red);
            float Q = blockSum(q[g], red);
            mu[g] = S / FF;
            rs[g] = rsqrtf(Q / FF - mu[g] * mu[g] + 1e-5f);
        }

        float nc[NU], og[NU], ho[NU], co[NU];
        float cs = 0.f, cq = 0.f;
        #pragma unroll
        for (int i = 0; i < NU; ++i) {
            int u = tid + i * TPB_;
            if (u < FF) {
                float zi = (NTL(&zr[u])          - mu[0]) * rs[0] * gg[u]          + bg[u];
                float zj = (NTL(&zr[FF + u])     - mu[1]) * rs[1] * gg[FF + u]     + bg[FF + u];
                float zf = (NTL(&zr[2 * FF + u]) - mu[2]) * rs[2] * gg[2 * FF + u] + bg[2 * FF + u];
                float zo = (NTL(&zr[3 * FF + u]) - mu[3]) * rs[3] * gg[3 * FF + u] + bg[3 * FF + u];
                float cold = cr[u];
                float ncv = cold * sigm(zf + 1.0f) + sigm(zi) * tanhf(zj);
                nc[i] = ncv; og[i] = sigm(zo); co[i] = cold; ho[i] = hr[u];
                cs += ncv; cq += ncv * ncv;
            } else { nc[i] = 0.f; og[i] = 0.f; co[i] = 0.f; ho[i] = 0.f; }
        }
        float CS = blockSum(cs, red);
        float CQ = blockSum(cq, red);
        float muc = CS / FF;
        float rsc = rsqrtf(CQ / FF - muc * muc + 1e-5f);

        #pragma unroll
        for (int i = 0; i < NU; ++i) {
            int u = tid + i * TPB_;
            if (u < FF) {
                float nh = tanhf((nc[i] - muc) * rsc * gc[u] + bc[u]) * og[i];
                float hout = 0.9f * nh + 0.1f * ho[i];
                float cout = 0.5f * nc[i] + 0.5f * co[i];
                NTS(&hr[u], hout);
                NTS(&cr[u], cout);
                u16 H, M, L;
                split3f(hout, H, M, L);
                size_t po = (size_t)b * hstride + u;
                NTS(&hpH[po], H); NTS(&hpM[po], M); NTS(&hpL[po], L);
                if (hist) NTS(&hist[((size_t)b * T_ + t) * FP_ + u], H);
            }
        }
        if (hist && tid < FP_ - FF)
            NTS(&hist[((size_t)b * T_ + t) * FP_ + FF + tid], (u16)0);
    }
}

// ---------------------------------------------------------------------------
// Mega: init -> 100 x (GEMM0|PW0|GEMMS|PWS|GEMM1|PW1) -> states tail.
// (TPB_,1): 256-VGPR budget (block shape already implies 2 waves/SIMD).
// ---------------------------------------------------------------------------
__global__ __launch_bounds__(TPB_, 1) void mega(
    const float* __restrict__ b0, const float* __restrict__ g0,
    const float* __restrict__ bg0, const float* __restrict__ gc0,
    const float* __restrict__ bc0,
    const float* __restrict__ b1, const float* __restrict__ g1,
    const float* __restrict__ bg1, const float* __restrict__ gc1,
    const float* __restrict__ bc1,
    const float* __restrict__ bS, const float* __restrict__ gS,
    const float* __restrict__ bgS, const float* __restrict__ gcS,
    const float* __restrict__ bcS,
    const float* __restrict__ zx,
    float* fh, float* fc, float* sh, float* sc, float* z, u16* hist,
    u16* fhH, u16* fhM, u16* fhL, u16* shH, u16* shM, u16* shL,
    u16* W0H, u16* W0M, u16* W0L, u16* WSH, u16* WSM, u16* WSL,
    u16* W1H, u16* W1M, u16* W1L,
    float* outTail, unsigned* flags, unsigned* go)
{
    __shared__ float red[8];
    const int gtid = blockIdx.x * TPB_ + threadIdx.x;
    unsigned tgt = 0;

    for (int i = gtid; i < 2 * B_ * F_ + 2 * B_ * S_; i += G_ * TPB_) NTS(&fh[i], 0.f);
    for (int i = gtid; i < 3 * B_ * FP_ + 3 * B_ * SP_; i += G_ * TPB_) NTS(&fhH[i], (u16)0);
    gbar(flags, go, ++tgt);

    for (int t = 0; t < T_; ++t) {
        gemm_phase(fhH, fhM, fhL, FP_, FP_, fhH, fhM, fhL, FP_,
                   W0H + 128, W0M + 128, W0L + 128, 832, FP_ / 32,
                   nullptr, zx + (size_t)t * B_ * 2800, z, 4 * F_);
        gbar(flags, go, ++tgt);
        pw_phase<F_>(z, g0, bg0, gc0, bc0, fh, fc, fhH, fhM, fhL, FP_, nullptr, 0, red);
        gbar(flags, go, ++tgt);
        gemm_phase(fhH, fhM, fhL, FP_, FP_, shH, shM, shL, SP_,
                   WSH, WSM, WSL, 1120, 1120 / 32, bS, nullptr, z, 4 * S_);
        gbar(flags, go, ++tgt);
        pw_phase<S_>(z, gS, bgS, gcS, bcS, sh, sc, shH, shM, shL, SP_, nullptr, 0, red);
        gbar(flags, go, ++tgt);
        gemm_phase(shH, shM, shL, SP_, SP_, fhH, fhM, fhL, FP_,
                   W1H, W1M, W1L, 1120, 1120 / 32, b1, nullptr, z, 4 * F_);
        gbar(flags, go, ++tgt);
        pw_phase<F_>(z, g1, bg1, gc1, bc1, fh, fc, fhH, fhM, fhL, FP_, hist, t, red);
        gbar(flags, go, ++tgt);
    }

    const int NF = B_ * F_, NS = B_ * S_;
    for (int i = gtid; i < 2 * NF + 2 * NS; i += G_ * TPB_) {
        float v = (i < NF) ? fh[i] : (i < 2 * NF) ? fc[i - NF]
                : (i < 2 * NF + NS) ? sh[i - 2 * NF] : sc[i - 2 * NF - NS];
        NTS(&outTail[i], v);
    }
}

// ---------------------------------------------------------------------------
// Output projection (r5-proven): C = hist[12800,704] @ Wtout^T + bout
// ---------------------------------------------------------------------------
__global__ __launch_bounds__(512) void ogemm(
    const u16* __restrict__ A, const u16* __restrict__ Bt,
    const float* __restrict__ bias, float* __restrict__ C)
{
    const int N = V_;
    const int tid = threadIdx.x, lane = tid & 63, wid = tid >> 6;
    const int wm = wid >> 1, wn = wid & 1;
    const int row0 = blockIdx.y * 256 + wm * 64;
    const int col0 = blockIdx.x * 128 + wn * 64;
    const int lo = lane & 15, hi = lane >> 4;
    const int NT = FP_ / 32;

    v4f acc[4][4];
    #pragma unroll
    for (int i = 0; i < 4; ++i)
        #pragma unroll
        for (int j = 0; j < 4; ++j) acc[i][j] = (v4f)0.f;

    for (int kt = 0; kt < NT; ++kt) {
        const int kb = kt * 32 + hi * 8;
        v8s a[4], b[4];
        #pragma unroll
        for (int i = 0; i < 4; ++i) {
            a[i] = *(const v8s*)(A  + (size_t)(row0 + i * 16 + lo) * FP_ + kb);
            b[i] = *(const v8s*)(Bt + (size_t)(col0 + i * 16 + lo) * FP_ + kb);
        }
        #pragma unroll
        for (int mf = 0; mf < 4; ++mf)
            #pragma unroll
            for (int nf = 0; nf < 4; ++nf)
                acc[mf][nf] = __builtin_amdgcn_mfma_f32_16x16x32_bf16(a[mf], b[nf], acc[mf][nf], 0, 0, 0);
    }

    #pragma unroll
    for (int mf = 0; mf < 4; ++mf) {
        #pragma unroll
        for (int nf = 0; nf < 4; ++nf) {
            int col = col0 + nf * 16 + lo;
            if (col < N) {
                float bb = bias[col];
                #pragma unroll
                for (int r = 0; r < 4; ++r) {
                    int row = row0 + mf * 16 + hi * 4 + r;
                    C[(size_t)row * N + col] = acc[mf][nf][r] + bb;
                }
            }
        }
    }
}

extern "C" void kernel_launch(void* const* d_in, const int* in_sizes, int n_in,
                              void* d_out, int out_size, void* d_ws, size_t ws_size,
                              hipStream_t stream) {
    const float* inputs = (const float*)d_in[0];
    const float* W0   = (const float*)d_in[1];
    const float* b0   = (const float*)d_in[2];
    const float* g0   = (const float*)d_in[3];
    const float* bg0  = (const float*)d_in[4];
    const float* gc0  = (const float*)d_in[5];
    const float* bc0  = (const float*)d_in[6];
    const float* W1   = (const float*)d_in[7];
    const float* b1   = (const float*)d_in[8];
    const float* g1   = (const float*)d_in[9];
    const float* bg1  = (const float*)d_in[10];
    const float* gc1  = (const float*)d_in[11];
    const float* bc1  = (const float*)d_in[12];
    const float* WS   = (const float*)d_in[13];
    const float* bS   = (const float*)d_in[14];
    const float* gS   = (const float*)d_in[15];
    const float* bgS  = (const float*)d_in[16];
    const float* gcS  = (const float*)d_in[17];
    const float* bcS  = (const float*)d_in[18];
    const float* Wout = (const float*)d_in[19];
    const float* bout = (const float*)d_in[20];

    // ---- ws: states + z + hist + Wtout + flags/go (~34.9 MB, known-safe)
    float* ws = (float*)d_ws;
    float* fh = ws;
    float* fc = fh + B_ * F_;
    float* sh = fc + B_ * F_;
    float* sc = sh + B_ * S_;
    float* z  = sc + B_ * S_;
    u16* hist = (u16*)(z + (size_t)B_ * 4 * F_);
    u16* Wtout = hist + (size_t)12800 * FP_;
    unsigned* flags = (unsigned*)(Wtout + (size_t)10112 * FP_);
    unsigned* go    = flags + G_ * 16;

    // ---- d_out scratch (fully rewritten every call; dead before ogemm)
    const size_t P0 = (size_t)2816 * 832;
    const size_t PS = (size_t)1664 * 1120;
    const size_t P1 = (size_t)2816 * 1120;
    const size_t HF = (size_t)B_ * FP_;
    const size_t HS = (size_t)B_ * SP_;
    u16* dp  = (u16*)d_out;
    u16* W0H = dp;          u16* W0M = W0H + P0;  u16* W0L = W0M + P0;
    u16* WSH = W0L + P0;    u16* WSM = WSH + PS;  u16* WSL = WSM + PS;
    u16* W1H = WSL + PS;    u16* W1M = W1H + P1;  u16* W1L = W1M + P1;
    u16* fhH = W1L + P1;    u16* fhM = fhH + HF;  u16* fhL = fhM + HF;
    u16* shH = fhL + HF;    u16* shM = shH + HS;  u16* shL = shM + HS;
    float* zx = (float*)(shL + HS);

    hipMemsetAsync(flags, 0, (G_ * 16 + 16) * sizeof(unsigned), stream);

    wtrans3<<<dim3(88, 26), 256, 0, stream>>>(W0, E_ + F_, 4 * F_, W0H, W0M, W0L, 832, 128, 128);
    wtrans3<<<dim3(52, 35), 256, 0, stream>>>(WS, F_ + S_, 4 * S_, WSH, WSM, WSL, 1120, F_, FP_);
    wtrans3<<<dim3(88, 35), 256, 0, stream>>>(W1, S_ + F_, 4 * F_, W1H, W1M, W1L, 1120, S_, SP_);
    wtrans<<<dim3(316, 22), 256, 0, stream>>>(Wout, F_, V_, Wtout, FP_);

    zxpre<<<2188, 512, 0, stream>>>(inputs, W0H, W0M, W0L, b0, zx);

    mega<<<G_, TPB_, 0, stream>>>(
        b0, g0, bg0, gc0, bc0,
        b1, g1, bg1, gc1, bc1,
        bS, gS, bgS, gcS, bcS,
        zx,
        fh, fc, sh, sc, z, hist,
        fhH, fhM, fhL, shH, shM, shL,
        W0H, W0M, W0L, WSH, WSM, WSL, W1H, W1M, W1L,
        (float*)d_out + (size_t)B_ * T_ * V_, flags, go);

    ogemm<<<dim3(79, 50), 512, 0, stream>>>(hist, Wtout, bout, (float*)d_out);
}

// Round 11
// 18447.914 us; speedup vs baseline: 2.7983x; 1.0255x over previous
//
#include <hip/hip_runtime.h>
#include <math.h>

// ---------------------------------------------------------------------------
// PTB LN-LSTM stack: B=128, T=100, E=128, F=700, S=400, V=10000.
// Round 11: (a) LEAN gemm inner loop - single-step prefetch of A and B only
// (the r8 depth-4 ring + ping-pong is the suspected source of the 4.3GB/run
// of extra WRITE traffic: ~200 nominal VGPRs vs the 128 the allocator picks);
// (b) 16-row tiles (was 64) -> 1400/800/1400 tiles vs 2048 waves: 3-4x more
// waves fetching concurrently, MSHR-coalesced refill of the post-barrier-inv
// weight misses. Per-acc MFMA order unchanged -> absmax must stay 0.03125.
// ---------------------------------------------------------------------------

#define B_ 128
#define T_ 100
#define E_ 128
#define F_ 700
#define S_ 400
#define V_ 10000

#define FP_ 704    // F padded
#define SP_ 416    // S padded
#define G_  256    // mega blocks
#define TPB_ 512   // threads per mega block (8 waves)
#define NW_ (G_ * 8)

using v8s = __attribute__((ext_vector_type(8))) short;
using v4f = __attribute__((ext_vector_type(4))) float;
typedef unsigned short u16;

#define NTS(p, v) __builtin_nontemporal_store((v), (p))
#define NTL(p)    __builtin_nontemporal_load((p))

__device__ __forceinline__ u16 f2bf(float x) {
    unsigned int u = __float_as_uint(x);
    u += 0x7FFFu + ((u >> 16) & 1u);
    return (u16)(u >> 16);
}
__device__ __forceinline__ float bf2f(u16 h) {
    return __uint_as_float(((unsigned int)h) << 16);
}
__device__ __forceinline__ void split3f(float x, u16& h, u16& m, u16& l) {
    h = f2bf(x); float r  = x - bf2f(h);
    m = f2bf(r); float r2 = r - bf2f(m);
    l = f2bf(r2);
}
__device__ __forceinline__ float sigm(float x) { return 1.0f / (1.0f + expf(-x)); }

// ---------------------------------------------------------------------------
// Grid barrier (r9-proven): release + arrive, early acquire overlapping the
// wait; block0 gathers RELAXED, publishes go; others poll go RELAXED.
// ---------------------------------------------------------------------------
__device__ __forceinline__ void gbar(unsigned* flags, unsigned* go, unsigned target) {
    __syncthreads();
    if (threadIdx.x == 0) {
        __threadfence();   // release
        __hip_atomic_store(flags + (size_t)blockIdx.x * 16, target,
                           __ATOMIC_RELEASE, __HIP_MEMORY_SCOPE_AGENT);
        __threadfence();   // acquire early: inv overlaps the wait
    }
    if (blockIdx.x == 0) {
        if (threadIdx.x < G_) {
            const unsigned* f = flags + (size_t)threadIdx.x * 16;
            while (__hip_atomic_load(f, __ATOMIC_RELAXED, __HIP_MEMORY_SCOPE_AGENT) < target)
                __builtin_amdgcn_s_sleep(1);
        }
        __syncthreads();
        if (threadIdx.x == 0)
            __hip_atomic_store(go, target, __ATOMIC_RELEASE, __HIP_MEMORY_SCOPE_AGENT);
    } else {
        if (threadIdx.x == 0) {
            while (__hip_atomic_load(go, __ATOMIC_RELAXED, __HIP_MEMORY_SCOPE_AGENT) < target)
                __builtin_amdgcn_s_sleep(1);
        }
    }
    __syncthreads();
}

// ---------------------------------------------------------------------------
// Standalone transpose+split kernels (r5-proven; full-coverage writes).
// ---------------------------------------------------------------------------
__global__ __launch_bounds__(256) void wtrans3(
    const float* __restrict__ W, int K, int N,
    u16* __restrict__ WtH, u16* __restrict__ WtM, u16* __restrict__ WtL,
    int Kp, int K1, int K1pad)
{
    __shared__ float t[32][33];
    const int c0 = blockIdx.x * 32, kp0 = blockIdx.y * 32;
    const int tx = threadIdx.x & 31, ty = threadIdx.x >> 5;
    #pragma unroll
    for (int i = 0; i < 4; ++i) {
        int kpos = kp0 + ty + i * 8, c = c0 + tx;
        int k = (kpos < K1) ? kpos : (kpos >= K1pad ? K1 + (kpos - K1pad) : -1);
        t[ty + i * 8][tx] = (k >= 0 && k < K && c < N) ? W[(size_t)k * N + c] : 0.f;
    }
    __syncthreads();
    #pragma unroll
    for (int i = 0; i < 4; ++i) {
        int r = c0 + ty + i * 8;
        u16 h, m, l;
        split3f(t[tx][ty + i * 8], h, m, l);
        size_t idx = (size_t)r * Kp + kp0 + tx;
        WtH[idx] = h; WtM[idx] = m; WtL[idx] = l;
    }
}

__global__ __launch_bounds__(256) void wtrans(
    const float* __restrict__ W, int K, int N,
    u16* __restrict__ Wt, int Kpad)
{
    __shared__ float t[32][33];
    const int c0 = blockIdx.x * 32, k0 = blockIdx.y * 32;
    const int tx = threadIdx.x & 31, ty = threadIdx.x >> 5;
    #pragma unroll
    for (int i = 0; i < 4; ++i) {
        int k = k0 + ty + i * 8, c = c0 + tx;
        t[ty + i * 8][tx] = (k < K && c < N) ? W[(size_t)k * N + c] : 0.f;
    }
    __syncthreads();
    #pragma unroll
    for (int i = 0; i < 4; ++i) {
        int r = c0 + ty + i * 8;
        Wt[(size_t)r * Kpad + k0 + tx] = f2bf(t[tx][ty + i * 8]);
    }
}

// ---------------------------------------------------------------------------
// zx precompute: zx[t][b][col] = x[b,t,:] @ W0[:128,col] + b0[col]  (r7-proven)
// ---------------------------------------------------------------------------
__global__ __launch_bounds__(512, 1) void zxpre(
    const float* __restrict__ inputs,
    const u16* __restrict__ WH, const u16* __restrict__ WM,
    const u16* __restrict__ WL, const float* __restrict__ b0,
    float* __restrict__ zx)
{
    const int lane = threadIdx.x & 63, wid = threadIdx.x >> 6;
    const int lo = lane & 15, hi = lane >> 4;
    const int ntiles = 175 * 100;
    for (int i = blockIdx.x * 8 + wid; i < ntiles; i += gridDim.x * 8) {
        const int t = i / 175, ct = i % 175;
        v4f acc[8];
        #pragma unroll
        for (int m = 0; m < 8; ++m) acc[m] = (v4f)0.f;
        const size_t bb = (size_t)(ct * 16 + lo) * 832 + hi * 8;
        for (int kt = 0; kt < 4; ++kt) {
            const size_t bo = bb + kt * 32;
            v8s bh = *(const v8s*)(WH + bo);
            v8s bm = *(const v8s*)(WM + bo);
            v8s bl = *(const v8s*)(WL + bo);
            #pragma unroll
            for (int m = 0; m < 8; ++m) {
                const float* p = inputs + (size_t)(m * 16 + lo) * (T_ * E_)
                               + (size_t)t * E_ + kt * 32 + hi * 8;
                float v0[8];
                *(float4*)(v0)     = *(const float4*)(p);
                *(float4*)(v0 + 4) = *(const float4*)(p + 4);
                v8s ah, am, al;
                #pragma unroll
                for (int j = 0; j < 8; ++j) {
                    u16 H, M, L; split3f(v0[j], H, M, L);
                    ah[j] = (short)H; am[j] = (short)M; al[j] = (short)L;
                }
                acc[m] = __builtin_amdgcn_mfma_f32_16x16x32_bf16(ah, bh, acc[m], 0, 0, 0);
                acc[m] = __builtin_amdgcn_mfma_f32_16x16x32_bf16(ah, bm, acc[m], 0, 0, 0);
                acc[m] = __builtin_amdgcn_mfma_f32_16x16x32_bf16(am, bh, acc[m], 0, 0, 0);
                acc[m] = __builtin_amdgcn_mfma_f32_16x16x32_bf16(ah, bl, acc[m], 0, 0, 0);
                acc[m] = __builtin_amdgcn_mfma_f32_16x16x32_bf16(al, bh, acc[m], 0, 0, 0);
                acc[m] = __builtin_amdgcn_mfma_f32_16x16x32_bf16(am, bm, acc[m], 0, 0, 0);
            }
        }
        const int col = ct * 16 + lo;
        const float bb0 = b0[col];
        #pragma unroll
        for (int m = 0; m < 8; ++m)
            #pragma unroll
            for (int r = 0; r < 4; ++r) {
                int row = m * 16 + hi * 4 + r;
                NTS(&zx[((size_t)t * B_ + row) * 2800 + col], acc[m][r] + bb0);
            }
    }
}

// ---------------------------------------------------------------------------
// GEMM phase (LEAN): per-wave 16-col x 16-row tile; single-step prefetch of
// A and B plane fragments (~80 nominal VGPRs, no spill risk). Per-acc MFMA
// sequence over kt identical to r5-r10.
// ---------------------------------------------------------------------------
__device__ void gemm_phase(
    const u16* __restrict__ A1H, const u16* __restrict__ A1M,
    const u16* __restrict__ A1L, int lda1, int K1pad,
    const u16* __restrict__ A2H, const u16* __restrict__ A2M,
    const u16* __restrict__ A2L, int lda2,
    const u16* __restrict__ WH, const u16* __restrict__ WM,
    const u16* __restrict__ WL, int Kp, int NT,
    const float* __restrict__ bias, const float* __restrict__ zadd,
    float* __restrict__ z, int N)
{
    const int lane = threadIdx.x & 63, wid = threadIdx.x >> 6;
    const int lo = lane & 15, hi = lane >> 4;
    const int ntiles = (N >> 4) * 8;                // 16col x 16row tiles
    for (int i = wid * G_ + blockIdx.x; i < ntiles; i += NW_) {
        const int ct = i >> 3, r0 = (i & 7) * 16;
        v4f acc = (v4f)0.f;

        const size_t bb = (size_t)(ct * 16 + lo) * Kp + hi * 8;
        // kt = 0 fragments (kt0 is always inside segment 1)
        v8s bh = *(const v8s*)(WH + bb);
        v8s bm = *(const v8s*)(WM + bb);
        v8s bl = *(const v8s*)(WL + bb);
        const size_t a0 = (size_t)(r0 + lo) * lda1 + hi * 8;
        v8s ah = *(const v8s*)(A1H + a0);
        v8s am = *(const v8s*)(A1M + a0);
        v8s al = *(const v8s*)(A1L + a0);

        for (int kt = 0; kt < NT; ++kt) {
            v8s nbh = bh, nbm = bm, nbl = bl, nah = ah, nam = am, nal = al;
            if (kt + 1 < NT) {
                const size_t o = bb + (size_t)(kt + 1) * 32;
                nbh = *(const v8s*)(WH + o);
                nbm = *(const v8s*)(WM + o);
                nbl = *(const v8s*)(WL + o);
                const int kb2 = (kt + 1) * 32;
                const bool s1 = kb2 < K1pad;
                const u16* pH = s1 ? A1H : A2H;
                const u16* pM = s1 ? A1M : A2M;
                const u16* pL = s1 ? A1L : A2L;
                const size_t ao = (size_t)(r0 + lo) * (s1 ? lda1 : lda2)
                                + (s1 ? kb2 : kb2 - K1pad) + hi * 8;
                nah = *(const v8s*)(pH + ao);
                nam = *(const v8s*)(pM + ao);
                nal = *(const v8s*)(pL + ao);
            }
            acc = __builtin_amdgcn_mfma_f32_16x16x32_bf16(ah, bh, acc, 0, 0, 0);
            acc = __builtin_amdgcn_mfma_f32_16x16x32_bf16(ah, bm, acc, 0, 0, 0);
            acc = __builtin_amdgcn_mfma_f32_16x16x32_bf16(am, bh, acc, 0, 0, 0);
            acc = __builtin_amdgcn_mfma_f32_16x16x32_bf16(ah, bl, acc, 0, 0, 0);
            acc = __builtin_amdgcn_mfma_f32_16x16x32_bf16(al, bh, acc, 0, 0, 0);
            acc = __builtin_amdgcn_mfma_f32_16x16x32_bf16(am, bm, acc, 0, 0, 0);
            bh = nbh; bm = nbm; bl = nbl;
            ah = nah; am = nam; al = nal;
        }

        const int col = ct * 16 + lo;
        if (zadd) {
            #pragma unroll
            for (int r = 0; r < 4; ++r) {
                int row = r0 + hi * 4 + r;
                float za = NTL(&zadd[(size_t)row * N + col]);
                NTS(&z[(size_t)row * N + col], acc[r] + za);
            }
        } else {
            const float bv = bias[col];
            #pragma unroll
            for (int r = 0; r < 4; ++r) {
                int row = r0 + hi * 4 + r;
                NTS(&z[(size_t)row * N + col], acc[r] + bv);
            }
        }
    }
}

// Block-wide sum over 512 threads (8 waves), broadcast.
__device__ __forceinline__ float blockSum(float v, volatile float* red) {
    #pragma unroll
    for (int off = 32; off > 0; off >>= 1) v += __shfl_down(v, off, 64);
    int w = threadIdx.x >> 6, lane = threadIdx.x & 63;
    __syncthreads();
    if (lane == 0) red[w] = v;
    __syncthreads();
    float r = 0.f;
    #pragma unroll
    for (int j = 0; j < 8; ++j) r += red[j];
    return r;
}

// ---------------------------------------------------------------------------
// Pointwise phase (512 thr): LN4 + gates + c-LN + zoneout; one row/block.
// ---------------------------------------------------------------------------
template <int FF>
__device__ void pw_phase(const float* __restrict__ z,
    const float* __restrict__ gg, const float* __restrict__ bg,
    const float* __restrict__ gc, const float* __restrict__ bc,
    float* __restrict__ h, float* __restrict__ c,
    u16* __restrict__ hpH, u16* __restrict__ hpM, u16* __restrict__ hpL,
    int hstride, u16* __restrict__ hist, int t, volatile float* red)
{
    const int tid = threadIdx.x;
    constexpr int NU = (FF + TPB_ - 1) / TPB_;
    for (int b = blockIdx.x; b < B_; b += G_) {
        const float* zr = z + (size_t)b * 4 * FF;
        float* hr = h + (size_t)b * FF;
        float* cr = c + (size_t)b * FF;

        float s[4] = {0, 0, 0, 0}, q[4] = {0, 0, 0, 0};
        #pragma unroll
        for (int i = 0; i < NU; ++i) {
            int u = tid + i * TPB_;
            if (u < FF) {
                #pragma unroll
                for (int g = 0; g < 4; ++g) {
                    float v = NTL(&zr[g * FF + u]);
                    s[g] += v; q[g] += v * v;
                }
            }
        }
        float mu[4], rs[4];
        #pragma unroll
        for (int g = 0; g < 4; ++g) {
            float S = blockSum(s[g], red);
            float Q = blockSum(q[g], red);
            mu[g] = S / FF;
            rs[g] = rsqrtf(Q / FF - mu[g] * mu[g] + 1e-5f);
        }

        float nc[NU], og[NU], ho[NU], co[NU];
        float cs = 0.f, cq = 0.f;
        #pragma unroll
        for (int i = 0; i < NU; ++i) {
            int u = tid + i * TPB_;
            if (u < FF) {
                float zi = (NTL(&zr[u])          - mu[0]) * rs[0] * gg[u]          + bg[u];
                float zj = (NTL(&zr[FF + u])     - mu[1]) * rs[1] * gg[FF + u]     + bg[FF + u];
                float zf = (NTL(&zr[2 * FF + u]) - mu[2]) * rs[2] * gg[2 * FF + u] + bg[2 * FF + u];
                float zo = (NTL(&zr[3 * FF + u]) - mu[3]) * rs[3] * gg[3 * FF + u] + bg[3 * FF + u];
                float cold = cr[u];
                float ncv = cold * sigm(zf + 1.0f) + sigm(zi) * tanhf(zj);
                nc[i] = ncv; og[i] = sigm(zo); co[i] = cold; ho[i] = hr[u];
                cs += ncv; cq += ncv * ncv;
            } else { nc[i] = 0.f; og[i] = 0.f; co[i] = 0.f; ho[i] = 0.f; }
        }
        float CS = blockSum(cs, red);
        float CQ = blockSum(cq, red);
        float muc = CS / FF;
        float rsc = rsqrtf(CQ / FF - muc * muc + 1e-5f);

        #pragma unroll
        for (int i = 0; i < NU; ++i) {
            int u = tid + i * TPB_;
            if (u < FF) {
                float nh = tanhf((nc[i] - muc) * rsc * gc[u] + bc[u]) * og[i];
                float hout = 0.9f * nh + 0.1f * ho[i];
                float cout = 0.5f * nc[i] + 0.5f * co[i];
                NTS(&hr[u], hout);
                NTS(&cr[u], cout);
                u16 H, M, L;
                split3f(hout, H, M, L);
                size_t po = (size_t)b * hstride + u;
                NTS(&hpH[po], H); NTS(&hpM[po], M); NTS(&hpL[po], L);
                if (hist) NTS(&hist[((size_t)b * T_ + t) * FP_ + u], H);
            }
        }
        if (hist && tid < FP_ - FF)
            NTS(&hist[((size_t)b * T_ + t) * FP_ + FF + tid], (u16)0);
    }
}

// ---------------------------------------------------------------------------
// Mega: init -> 100 x (GEMM0|PW0|GEMMS|PWS|GEMM1|PW1) -> states tail.
// ---------------------------------------------------------------------------
__global__ __launch_bounds__(TPB_, 1) void mega(
    const float* __restrict__ b0, const float* __restrict__ g0,
    const float* __restrict__ bg0, const float* __restrict__ gc0,
    const float* __restrict__ bc0,
    const float* __restrict__ b1, const float* __restrict__ g1,
    const float* __restrict__ bg1, const float* __restrict__ gc1,
    const float* __restrict__ bc1,
    const float* __restrict__ bS, const float* __restrict__ gS,
    const float* __restrict__ bgS, const float* __restrict__ gcS,
    const float* __restrict__ bcS,
    const float* __restrict__ zx,
    float* fh, float* fc, float* sh, float* sc, float* z, u16* hist,
    u16* fhH, u16* fhM, u16* fhL, u16* shH, u16* shM, u16* shL,
    u16* W0H, u16* W0M, u16* W0L, u16* WSH, u16* WSM, u16* WSL,
    u16* W1H, u16* W1M, u16* W1L,
    float* outTail, unsigned* flags, unsigned* go)
{
    __shared__ float red[8];
    const int gtid = blockIdx.x * TPB_ + threadIdx.x;
    unsigned tgt = 0;

    for (int i = gtid; i < 2 * B_ * F_ + 2 * B_ * S_; i += G_ * TPB_) NTS(&fh[i], 0.f);
    for (int i = gtid; i < 3 * B_ * FP_ + 3 * B_ * SP_; i += G_ * TPB_) NTS(&fhH[i], (u16)0);
    gbar(flags, go, ++tgt);

    for (int t = 0; t < T_; ++t) {
        gemm_phase(fhH, fhM, fhL, FP_, FP_, fhH, fhM, fhL, FP_,
                   W0H + 128, W0M + 128, W0L + 128, 832, FP_ / 32,
                   nullptr, zx + (size_t)t * B_ * 2800, z, 4 * F_);
        gbar(flags, go, ++tgt);
        pw_phase<F_>(z, g0, bg0, gc0, bc0, fh, fc, fhH, fhM, fhL, FP_, nullptr, 0, red);
        gbar(flags, go, ++tgt);
        gemm_phase(fhH, fhM, fhL, FP_, FP_, shH, shM, shL, SP_,
                   WSH, WSM, WSL, 1120, 1120 / 32, bS, nullptr, z, 4 * S_);
        gbar(flags, go, ++tgt);
        pw_phase<S_>(z, gS, bgS, gcS, bcS, sh, sc, shH, shM, shL, SP_, nullptr, 0, red);
        gbar(flags, go, ++tgt);
        gemm_phase(shH, shM, shL, SP_, SP_, fhH, fhM, fhL, FP_,
                   W1H, W1M, W1L, 1120, 1120 / 32, b1, nullptr, z, 4 * F_);
        gbar(flags, go, ++tgt);
        pw_phase<F_>(z, g1, bg1, gc1, bc1, fh, fc, fhH, fhM, fhL, FP_, hist, t, red);
        gbar(flags, go, ++tgt);
    }

    const int NF = B_ * F_, NS = B_ * S_;
    for (int i = gtid; i < 2 * NF + 2 * NS; i += G_ * TPB_) {
        float v = (i < NF) ? fh[i] : (i < 2 * NF) ? fc[i - NF]
                : (i < 2 * NF + NS) ? sh[i - 2 * NF] : sc[i - 2 * NF - NS];
        NTS(&outTail[i], v);
    }
}

// ---------------------------------------------------------------------------
// Output projection (r5-proven): C = hist[12800,704] @ Wtout^T + bout
// ---------------------------------------------------------------------------
__global__ __launch_bounds__(512) void ogemm(
    const u16* __restrict__ A, const u16* __restrict__ Bt,
    const float* __restrict__ bias, float* __restrict__ C)
{
    const int N = V_;
    const int tid = threadIdx.x, lane = tid & 63, wid = tid >> 6;
    const int wm = wid >> 1, wn = wid & 1;
    const int row0 = blockIdx.y * 256 + wm * 64;
    const int col0 = blockIdx.x * 128 + wn * 64;
    const int lo = lane & 15, hi = lane >> 4;
    const int NT = FP_ / 32;

    v4f acc[4][4];
    #pragma unroll
    for (int i = 0; i < 4; ++i)
        #pragma unroll
        for (int j = 0; j < 4; ++j) acc[i][j] = (v4f)0.f;

    for (int kt = 0; kt < NT; ++kt) {
        const int kb = kt * 32 + hi * 8;
        v8s a[4], b[4];
        #pragma unroll
        for (int i = 0; i < 4; ++i) {
            a[i] = *(const v8s*)(A  + (size_t)(row0 + i * 16 + lo) * FP_ + kb);
            b[i] = *(const v8s*)(Bt + (size_t)(col0 + i * 16 + lo) * FP_ + kb);
        }
        #pragma unroll
        for (int mf = 0; mf < 4; ++mf)
            #pragma unroll
            for (int nf = 0; nf < 4; ++nf)
                acc[mf][nf] = __builtin_amdgcn_mfma_f32_16x16x32_bf16(a[mf], b[nf], acc[mf][nf], 0, 0, 0);
    }

    #pragma unroll
    for (int mf = 0; mf < 4; ++mf) {
        #pragma unroll
        for (int nf = 0; nf < 4; ++nf) {
            int col = col0 + nf * 16 + lo;
            if (col < N) {
                float bb = bias[col];
                #pragma unroll
                for (int r = 0; r < 4; ++r) {
                    int row = row0 + mf * 16 + hi * 4 + r;
                    C[(size_t)row * N + col] = acc[mf][nf][r] + bb;
                }
            }
        }
    }
}

extern "C" void kernel_launch(void* const* d_in, const int* in_sizes, int n_in,
                              void* d_out, int out_size, void* d_ws, size_t ws_size,
                              hipStream_t stream) {
    const float* inputs = (const float*)d_in[0];
    const float* W0   = (const float*)d_in[1];
    const float* b0   = (const float*)d_in[2];
    const float* g0   = (const float*)d_in[3];
    const float* bg0  = (const float*)d_in[4];
    const float* gc0  = (const float*)d_in[5];
    const float* bc0  = (const float*)d_in[6];
    const float* W1   = (const float*)d_in[7];
    const float* b1   = (const float*)d_in[8];
    const float* g1   = (const float*)d_in[9];
    const float* bg1  = (const float*)d_in[10];
    const float* gc1  = (const float*)d_in[11];
    const float* bc1  = (const float*)d_in[12];
    const float* WS   = (const float*)d_in[13];
    const float* bS   = (const float*)d_in[14];
    const float* gS   = (const float*)d_in[15];
    const float* bgS  = (const float*)d_in[16];
    const float* gcS  = (const float*)d_in[17];
    const float* bcS  = (const float*)d_in[18];
    const float* Wout = (const float*)d_in[19];
    const float* bout = (const float*)d_in[20];

    // ---- ws: states + z + hist + Wtout + flags/go (~34.9 MB, known-safe)
    float* ws = (float*)d_ws;
    float* fh = ws;
    float* fc = fh + B_ * F_;
    float* sh = fc + B_ * F_;
    float* sc = sh + B_ * S_;
    float* z  = sc + B_ * S_;
    u16* hist = (u16*)(z + (size_t)B_ * 4 * F_);
    u16* Wtout = hist + (size_t)12800 * FP_;
    unsigned* flags = (unsigned*)(Wtout + (size_t)10112 * FP_);
    unsigned* go    = flags + G_ * 16;

    // ---- d_out scratch (fully rewritten every call; dead before ogemm)
    const size_t P0 = (size_t)2816 * 832;
    const size_t PS = (size_t)1664 * 1120;
    const size_t P1 = (size_t)2816 * 1120;
    const size_t HF = (size_t)B_ * FP_;
    const size_t HS = (size_t)B_ * SP_;
    u16* dp  = (u16*)d_out;
    u16* W0H = dp;          u16* W0M = W0H + P0;  u16* W0L = W0M + P0;
    u16* WSH = W0L + P0;    u16* WSM = WSH + PS;  u16* WSL = WSM + PS;
    u16* W1H = WSL + PS;    u16* W1M = W1H + P1;  u16* W1L = W1M + P1;
    u16* fhH = W1L + P1;    u16* fhM = fhH + HF;  u16* fhL = fhM + HF;
    u16* shH = fhL + HF;    u16* shM = shH + HS;  u16* shL = shM + HS;
    float* zx = (float*)(shL + HS);

    hipMemsetAsync(flags, 0, (G_ * 16 + 16) * sizeof(unsigned), stream);

    wtrans3<<<dim3(88, 26), 256, 0, stream>>>(W0, E_ + F_, 4 * F_, W0H, W0M, W0L, 832, 128, 128);
    wtrans3<<<dim3(52, 35), 256, 0, stream>>>(WS, F_ + S_, 4 * S_, WSH, WSM, WSL, 1120, F_, FP_);
    wtrans3<<<dim3(88, 35), 256, 0, stream>>>(W1, S_ + F_, 4 * F_, W1H, W1M, W1L, 1120, S_, SP_);
    wtrans<<<dim3(316, 22), 256, 0, stream>>>(Wout, F_, V_, Wtout, FP_);

    zxpre<<<2188, 512, 0, stream>>>(inputs, W0H, W0M, W0L, b0, zx);

    mega<<<G_, TPB_, 0, stream>>>(
        b0, g0, bg0, gc0, bc0,
        b1, g1, bg1, gc1, bc1,
        bS, gS, bgS, gcS, bcS,
        zx,
        fh, fc, sh, sc, z, hist,
        fhH, fhM, fhL, shH, shM, shL,
        W0H, W0M, W0L, WSH, WSM, WSL, W1H, W1M, W1L,
        (float*)d_out + (size_t)B_ * T_ * V_, flags, go);

    ogemm<<<dim3(79, 50), 512, 0, stream>>>(hist, Wtout, bout, (float*)d_out);
}

// Round 12
// 17856.065 us; speedup vs baseline: 2.8911x; 1.0331x over previous
//
#include <hip/hip_runtime.h>
#include <math.h>

// ---------------------------------------------------------------------------
// PTB LN-LSTM stack: B=128, T=100, E=128, F=700, S=400, V=10000.
// Round 12: weights (H+M planes) live in LDS for the entire mega kernel.
// r11 measured 170MB/step of HBM/L3 FETCH at ~1TB/s = the whole step time:
// per-phase acquire-inv dropped the 41MB weight set from all 8 L2s and the
// scattered tiles refetched it ~4x. Now each block owns its 16-col weight
// tiles in LDS (27.6MB total across 256 blocks); only the L-planes (1 of 6
// products each) stream from global (13.6MB/step, block-exclusive).
// MFMA products and order unchanged -> absmax must stay exactly 0.03125.
// ---------------------------------------------------------------------------

#define B_ 128
#define T_ 100
#define E_ 128
#define F_ 700
#define S_ 400
#define V_ 10000

#define FP_ 704    // F padded
#define SP_ 416    // S padded
#define G_  256    // mega blocks
#define TPB_ 512   // threads per mega block (8 waves)

// LDS tile geometry: slab per kt = 16 cols x (64B H + 64B M) = 2048B
#define W0_TILE_B 45056    // 22 kt * 2048
#define KW_TILE_B 71680    // 35 kt * 2048
#define LDS_BYTES 143360   // max: two KW tiles

using v8s = __attribute__((ext_vector_type(8))) short;
using v4f = __attribute__((ext_vector_type(4))) float;
typedef unsigned short u16;

#define NTS(p, v) __builtin_nontemporal_store((v), (p))
#define NTL(p)    __builtin_nontemporal_load((p))

__device__ __forceinline__ u16 f2bf(float x) {
    unsigned int u = __float_as_uint(x);
    u += 0x7FFFu + ((u >> 16) & 1u);
    return (u16)(u >> 16);
}
__device__ __forceinline__ float bf2f(u16 h) {
    return __uint_as_float(((unsigned int)h) << 16);
}
__device__ __forceinline__ void split3f(float x, u16& h, u16& m, u16& l) {
    h = f2bf(x); float r  = x - bf2f(h);
    m = f2bf(r); float r2 = r - bf2f(m);
    l = f2bf(r2);
}
__device__ __forceinline__ float sigm(float x) { return 1.0f / (1.0f + expf(-x)); }

// ---------------------------------------------------------------------------
// Grid barrier (r9-proven).
// ---------------------------------------------------------------------------
__device__ __forceinline__ void gbar(unsigned* flags, unsigned* go, unsigned target) {
    __syncthreads();
    if (threadIdx.x == 0) {
        __threadfence();
        __hip_atomic_store(flags + (size_t)blockIdx.x * 16, target,
                           __ATOMIC_RELEASE, __HIP_MEMORY_SCOPE_AGENT);
        __threadfence();
    }
    if (blockIdx.x == 0) {
        if (threadIdx.x < G_) {
            const unsigned* f = flags + (size_t)threadIdx.x * 16;
            while (__hip_atomic_load(f, __ATOMIC_RELAXED, __HIP_MEMORY_SCOPE_AGENT) < target)
                __builtin_amdgcn_s_sleep(1);
        }
        __syncthreads();
        if (threadIdx.x == 0)
            __hip_atomic_store(go, target, __ATOMIC_RELEASE, __HIP_MEMORY_SCOPE_AGENT);
    } else {
        if (threadIdx.x == 0) {
            while (__hip_atomic_load(go, __ATOMIC_RELAXED, __HIP_MEMORY_SCOPE_AGENT) < target)
                __builtin_amdgcn_s_sleep(1);
        }
    }
    __syncthreads();
}

// ---------------------------------------------------------------------------
// Transpose+split kernels (r5-proven; full-coverage writes).
// ---------------------------------------------------------------------------
__global__ __launch_bounds__(256) void wtrans3(
    const float* __restrict__ W, int K, int N,
    u16* __restrict__ WtH, u16* __restrict__ WtM, u16* __restrict__ WtL,
    int Kp, int K1, int K1pad)
{
    __shared__ float t[32][33];
    const int c0 = blockIdx.x * 32, kp0 = blockIdx.y * 32;
    const int tx = threadIdx.x & 31, ty = threadIdx.x >> 5;
    #pragma unroll
    for (int i = 0; i < 4; ++i) {
        int kpos = kp0 + ty + i * 8, c = c0 + tx;
        int k = (kpos < K1) ? kpos : (kpos >= K1pad ? K1 + (kpos - K1pad) : -1);
        t[ty + i * 8][tx] = (k >= 0 && k < K && c < N) ? W[(size_t)k * N + c] : 0.f;
    }
    __syncthreads();
    #pragma unroll
    for (int i = 0; i < 4; ++i) {
        int r = c0 + ty + i * 8;
        u16 h, m, l;
        split3f(t[tx][ty + i * 8], h, m, l);
        size_t idx = (size_t)r * Kp + kp0 + tx;
        WtH[idx] = h; WtM[idx] = m; WtL[idx] = l;
    }
}

__global__ __launch_bounds__(256) void wtrans(
    const float* __restrict__ W, int K, int N,
    u16* __restrict__ Wt, int Kpad)
{
    __shared__ float t[32][33];
    const int c0 = blockIdx.x * 32, k0 = blockIdx.y * 32;
    const int tx = threadIdx.x & 31, ty = threadIdx.x >> 5;
    #pragma unroll
    for (int i = 0; i < 4; ++i) {
        int k = k0 + ty + i * 8, c = c0 + tx;
        t[ty + i * 8][tx] = (k < K && c < N) ? W[(size_t)k * N + c] : 0.f;
    }
    __syncthreads();
    #pragma unroll
    for (int i = 0; i < 4; ++i) {
        int r = c0 + ty + i * 8;
        Wt[(size_t)r * Kpad + k0 + tx] = f2bf(t[tx][ty + i * 8]);
    }
}

// ---------------------------------------------------------------------------
// zx precompute (r7-proven).
// ---------------------------------------------------------------------------
__global__ __launch_bounds__(512, 1) void zxpre(
    const float* __restrict__ inputs,
    const u16* __restrict__ WH, const u16* __restrict__ WM,
    const u16* __restrict__ WL, const float* __restrict__ b0,
    float* __restrict__ zx)
{
    const int lane = threadIdx.x & 63, wid = threadIdx.x >> 6;
    const int lo = lane & 15, hi = lane >> 4;
    const int ntiles = 175 * 100;
    for (int i = blockIdx.x * 8 + wid; i < ntiles; i += gridDim.x * 8) {
        const int t = i / 175, ct = i % 175;
        v4f acc[8];
        #pragma unroll
        for (int m = 0; m < 8; ++m) acc[m] = (v4f)0.f;
        const size_t bb = (size_t)(ct * 16 + lo) * 832 + hi * 8;
        for (int kt = 0; kt < 4; ++kt) {
            const size_t bo = bb + kt * 32;
            v8s bh = *(const v8s*)(WH + bo);
            v8s bm = *(const v8s*)(WM + bo);
            v8s bl = *(const v8s*)(WL + bo);
            #pragma unroll
            for (int m = 0; m < 8; ++m) {
                const float* p = inputs + (size_t)(m * 16 + lo) * (T_ * E_)
                               + (size_t)t * E_ + kt * 32 + hi * 8;
                float v0[8];
                *(float4*)(v0)     = *(const float4*)(p);
                *(float4*)(v0 + 4) = *(const float4*)(p + 4);
                v8s ah, am, al;
                #pragma unroll
                for (int j = 0; j < 8; ++j) {
                    u16 H, M, L; split3f(v0[j], H, M, L);
                    ah[j] = (short)H; am[j] = (short)M; al[j] = (short)L;
                }
                acc[m] = __builtin_amdgcn_mfma_f32_16x16x32_bf16(ah, bh, acc[m], 0, 0, 0);
                acc[m] = __builtin_amdgcn_mfma_f32_16x16x32_bf16(ah, bm, acc[m], 0, 0, 0);
                acc[m] = __builtin_amdgcn_mfma_f32_16x16x32_bf16(am, bh, acc[m], 0, 0, 0);
                acc[m] = __builtin_amdgcn_mfma_f32_16x16x32_bf16(ah, bl, acc[m], 0, 0, 0);
                acc[m] = __builtin_amdgcn_mfma_f32_16x16x32_bf16(al, bh, acc[m], 0, 0, 0);
                acc[m] = __builtin_amdgcn_mfma_f32_16x16x32_bf16(am, bm, acc[m], 0, 0, 0);
            }
        }
        const int col = ct * 16 + lo;
        const float bb0 = b0[col];
        #pragma unroll
        for (int m = 0; m < 8; ++m)
            #pragma unroll
            for (int r = 0; r < 4; ++r) {
                int row = m * 16 + hi * 4 + r;
                NTS(&zx[((size_t)t * B_ + row) * 2800 + col], acc[m][r] + bb0);
            }
    }
}

// ---------------------------------------------------------------------------
// Copy one 16-col weight tile (H+M planes) from global [col][Kp] into LDS
// slabs [kt][col*64B | 1024 + col*64B][chunk*16B].
// ---------------------------------------------------------------------------
__device__ void fill_tile(char* dst, const u16* __restrict__ H,
                          const u16* __restrict__ M, int Kp, int gcol0, int NT)
{
    const int n = 16 * NT * 4;
    for (int idx = threadIdx.x; idx < n; idx += TPB_) {
        const int c   = idx & 3;
        const int kt  = (idx >> 2) % NT;
        const int col = (idx >> 2) / NT;
        const size_t g = (size_t)(gcol0 + col) * Kp + kt * 32 + c * 8;
        const int o = kt * 2048 + col * 64 + c * 16;
        *(v8s*)(dst + o)        = *(const v8s*)(H + g);
        *(v8s*)(dst + o + 1024) = *(const v8s*)(M + g);
    }
}

// ---------------------------------------------------------------------------
// GEMM phase: this block's 16-col tile x 128 rows; wave w owns rows w*16..+15.
// B H/M fragments from LDS (conflict-free uniform-8 layout), B L fragment and
// A-plane fragments from global (1-step prefetch). MFMA order == r5-r11.
// ---------------------------------------------------------------------------
__device__ void gemm_lds(
    const char* lt, int NT,
    const u16* __restrict__ A1H, const u16* __restrict__ A1M,
    const u16* __restrict__ A1L, int lda1, int K1pad,
    const u16* __restrict__ A2H, const u16* __restrict__ A2M,
    const u16* __restrict__ A2L, int lda2,
    const u16* __restrict__ WL, int KpL, int col0,
    const float* __restrict__ bias, const float* __restrict__ zadd,
    float* __restrict__ z, int N)
{
    const int lane = threadIdx.x & 63;
    const int lo = lane & 15, hi = lane >> 4;
    const int r0 = (threadIdx.x >> 6) * 16;
    v4f acc = (v4f)0.f;
    const u16* blp = WL + (size_t)(col0 + lo) * KpL + hi * 8;

    // kt=0 prefetch (kt0 is always inside segment 1)
    size_t a0 = (size_t)(r0 + lo) * lda1 + hi * 8;
    v8s ah = *(const v8s*)(A1H + a0);
    v8s am = *(const v8s*)(A1M + a0);
    v8s al = *(const v8s*)(A1L + a0);
    v8s bl = *(const v8s*)(blp);

    for (int kt = 0; kt < NT; ++kt) {
        v8s nah = ah, nam = am, nal = al, nbl = bl;
        if (kt + 1 < NT) {
            const int kb2 = (kt + 1) * 32;
            const bool s1 = kb2 < K1pad;
            const u16* pH = s1 ? A1H : A2H;
            const u16* pM = s1 ? A1M : A2M;
            const u16* pL = s1 ? A1L : A2L;
            const size_t ao = (size_t)(r0 + lo) * (s1 ? lda1 : lda2)
                            + (s1 ? kb2 : kb2 - K1pad) + hi * 8;
            nah = *(const v8s*)(pH + ao);
            nam = *(const v8s*)(pM + ao);
            nal = *(const v8s*)(pL + ao);
            nbl = *(const v8s*)(blp + (kt + 1) * 32);
        }
        const int lb = kt * 2048 + lo * 64 + hi * 16;
        v8s bh = *(const v8s*)(lt + lb);
        v8s bm = *(const v8s*)(lt + lb + 1024);
        acc = __builtin_amdgcn_mfma_f32_16x16x32_bf16(ah, bh, acc, 0, 0, 0);
        acc = __builtin_amdgcn_mfma_f32_16x16x32_bf16(ah, bm, acc, 0, 0, 0);
        acc = __builtin_amdgcn_mfma_f32_16x16x32_bf16(am, bh, acc, 0, 0, 0);
        acc = __builtin_amdgcn_mfma_f32_16x16x32_bf16(ah, bl, acc, 0, 0, 0);
        acc = __builtin_amdgcn_mfma_f32_16x16x32_bf16(al, bh, acc, 0, 0, 0);
        acc = __builtin_amdgcn_mfma_f32_16x16x32_bf16(am, bm, acc, 0, 0, 0);
        ah = nah; am = nam; al = nal; bl = nbl;
    }

    const int col = col0 + lo;
    if (zadd) {
        #pragma unroll
        for (int r = 0; r < 4; ++r) {
            int row = r0 + hi * 4 + r;
            float za = NTL(&zadd[(size_t)row * N + col]);
            NTS(&z[(size_t)row * N + col], acc[r] + za);
        }
    } else {
        const float bv = bias[col];
        #pragma unroll
        for (int r = 0; r < 4; ++r) {
            int row = r0 + hi * 4 + r;
            NTS(&z[(size_t)row * N + col], acc[r] + bv);
        }
    }
}

// Block-wide sum over 512 threads (8 waves), broadcast.
__device__ __forceinline__ float blockSum(float v, volatile float* red) {
    #pragma unroll
    for (int off = 32; off > 0; off >>= 1) v += __shfl_down(v, off, 64);
    int w = threadIdx.x >> 6, lane = threadIdx.x & 63;
    __syncthreads();
    if (lane == 0) red[w] = v;
    __syncthreads();
    float r = 0.f;
    #pragma unroll
    for (int j = 0; j < 8; ++j) r += red[j];
    return r;
}

// ---------------------------------------------------------------------------
// Pointwise phase (unchanged r9).
// ---------------------------------------------------------------------------
template <int FF>
__device__ void pw_phase(const float* __restrict__ z,
    const float* __restrict__ gg, const float* __restrict__ bg,
    const float* __restrict__ gc, const float* __restrict__ bc,
    float* __restrict__ h, float* __restrict__ c,
    u16* __restrict__ hpH, u16* __restrict__ hpM, u16* __restrict__ hpL,
    int hstride, u16* __restrict__ hist, int t, volatile float* red)
{
    const int tid = threadIdx.x;
    constexpr int NU = (FF + TPB_ - 1) / TPB_;
    for (int b = blockIdx.x; b < B_; b += G_) {
        const float* zr = z + (size_t)b * 4 * FF;
        float* hr = h + (size_t)b * FF;
        float* cr = c + (size_t)b * FF;

        float s[4] = {0, 0, 0, 0}, q[4] = {0, 0, 0, 0};
        #pragma unroll
        for (int i = 0; i < NU; ++i) {
            int u = tid + i * TPB_;
            if (u < FF) {
                #pragma unroll
                for (int g = 0; g < 4; ++g) {
                    float v = NTL(&zr[g * FF + u]);
                    s[g] += v; q[g] += v * v;
                }
            }
        }
        float mu[4], rs[4];
        #pragma unroll
        for (int g = 0; g < 4; ++g) {
            float S = blockSum(s[g], red);
            float Q = blockSum(q[g], red);
            mu[g] = S / FF;
            rs[g] = rsqrtf(Q / FF - mu[g] * mu[g] + 1e-5f);
        }

        float nc[NU], og[NU], ho[NU], co[NU];
        float cs = 0.f, cq = 0.f;
        #pragma unroll
        for (int i = 0; i < NU; ++i) {
            int u = tid + i * TPB_;
            if (u < FF) {
                float zi = (NTL(&zr[u])          - mu[0]) * rs[0] * gg[u]          + bg[u];
                float zj = (NTL(&zr[FF + u])     - mu[1]) * rs[1] * gg[FF + u]     + bg[FF + u];
                float zf = (NTL(&zr[2 * FF + u]) - mu[2]) * rs[2] * gg[2 * FF + u] + bg[2 * FF + u];
                float zo = (NTL(&zr[3 * FF + u]) - mu[3]) * rs[3] * gg[3 * FF + u] + bg[3 * FF + u];
                float cold = cr[u];
                float ncv = cold * sigm(zf + 1.0f) + sigm(zi) * tanhf(zj);
                nc[i] = ncv; og[i] = sigm(zo); co[i] = cold; ho[i] = hr[u];
                cs += ncv; cq += ncv * ncv;
            } else { nc[i] = 0.f; og[i] = 0.f; co[i] = 0.f; ho[i] = 0.f; }
        }
        float CS = blockSum(cs, red);
        float CQ = blockSum(cq, red);
        float muc = CS / FF;
        float rsc = rsqrtf(CQ / FF - muc * muc + 1e-5f);

        #pragma unroll
        for (int i = 0; i < NU; ++i) {
            int u = tid + i * TPB_;
            if (u < FF) {
                float nh = tanhf((nc[i] - muc) * rsc * gc[u] + bc[u]) * og[i];
                float hout = 0.9f * nh + 0.1f * ho[i];
                float cout = 0.5f * nc[i] + 0.5f * co[i];
                NTS(&hr[u], hout);
                NTS(&cr[u], cout);
                u16 H, M, L;
                split3f(hout, H, M, L);
                size_t po = (size_t)b * hstride + u;
                NTS(&hpH[po], H); NTS(&hpM[po], M); NTS(&hpL[po], L);
                if (hist) NTS(&hist[((size_t)b * T_ + t) * FP_ + u], H);
            }
        }
        if (hist && tid < FP_ - FF)
            NTS(&hist[((size_t)b * T_ + t) * FP_ + FF + tid], (u16)0);
    }
}

// ---------------------------------------------------------------------------
// Mega: LDS-fill -> init -> 100 x (GEMM0|PW0|GEMMS|PWS|GEMM1|PW1) -> tail.
// Tile map: b<=155:{W0[b],W1[b]} 156..174:{W0[b],WS[b-156]}
//           175..193:{WS[b-156],W1[156+b-175]} 194..255:{WS[b-156]}
// ---------------------------------------------------------------------------
__global__ __launch_bounds__(TPB_, 1) void mega(
    const float* __restrict__ b0, const float* __restrict__ g0,
    const float* __restrict__ bg0, const float* __restrict__ gc0,
    const float* __restrict__ bc0,
    const float* __restrict__ b1, const float* __restrict__ g1,
    const float* __restrict__ bg1, const float* __restrict__ gc1,
    const float* __restrict__ bc1,
    const float* __restrict__ bS, const float* __restrict__ gS,
    const float* __restrict__ bgS, const float* __restrict__ gcS,
    const float* __restrict__ bcS,
    const float* __restrict__ zx,
    float* fh, float* fc, float* sh, float* sc, float* z, u16* hist,
    u16* fhH, u16* fhM, u16* fhL, u16* shH, u16* shM, u16* shL,
    u16* W0H, u16* W0M, u16* W0L, u16* WSH, u16* WSM, u16* WSL,
    u16* W1H, u16* W1M, u16* W1L,
    float* outTail, unsigned* flags, unsigned* go)
{
    extern __shared__ char lds[];
    __shared__ float red[8];
    const int b = blockIdx.x;
    const int gtid = blockIdx.x * TPB_ + threadIdx.x;
    unsigned tgt = 0;

    // ---- one-time LDS weight fill (own LDS only; first gbar syncs block)
    if (b <= 174) {
        fill_tile(lds, W0H + 128, W0M + 128, 832, b * 16, 22);
        if (b <= 155) fill_tile(lds + W0_TILE_B, W1H, W1M, 1120, b * 16, 35);
        else          fill_tile(lds + W0_TILE_B, WSH, WSM, 1120, (b - 156) * 16, 35);
    } else {
        fill_tile(lds, WSH, WSM, 1120, (b - 156) * 16, 35);
        if (b <= 193)
            fill_tile(lds + KW_TILE_B, W1H, W1M, 1120, (156 + b - 175) * 16, 35);
    }

    // ---- init: zero f32 states and h/s planes
    for (int i = gtid; i < 2 * B_ * F_ + 2 * B_ * S_; i += G_ * TPB_) NTS(&fh[i], 0.f);
    for (int i = gtid; i < 3 * B_ * FP_ + 3 * B_ * SP_; i += G_ * TPB_) NTS(&fhH[i], (u16)0);
    gbar(flags, go, ++tgt);

    for (int t = 0; t < T_; ++t) {
        // GEMM0: N=2800, K=704 (fh only; x-part in zx). Blocks 0..174.
        if (b <= 174)
            gemm_lds(lds, 22,
                     fhH, fhM, fhL, FP_, FP_, fhH, fhM, fhL, FP_,
                     W0L + 128, 832, b * 16,
                     nullptr, zx + (size_t)t * B_ * 2800, z, 2800);
        gbar(flags, go, ++tgt);
        pw_phase<F_>(z, g0, bg0, gc0, bc0, fh, fc, fhH, fhM, fhL, FP_, nullptr, 0, red);
        gbar(flags, go, ++tgt);
        // GEMMS: N=1600, K=1120, A=[fh|sh]. Blocks 156..255.
        if (b >= 156)
            gemm_lds(lds + (b <= 174 ? W0_TILE_B : 0), 35,
                     fhH, fhM, fhL, FP_, FP_, shH, shM, shL, SP_,
                     WSL, 1120, (b - 156) * 16,
                     bS, nullptr, z, 1600);
        gbar(flags, go, ++tgt);
        pw_phase<S_>(z, gS, bgS, gcS, bcS, sh, sc, shH, shM, shL, SP_, nullptr, 0, red);
        gbar(flags, go, ++tgt);
        // GEMM1: N=2800, K=1120, A=[sh|fh]. Blocks 0..155 and 175..193.
        if (b <= 155)
            gemm_lds(lds + W0_TILE_B, 35,
                     shH, shM, shL, SP_, SP_, fhH, fhM, fhL, FP_,
                     W1L, 1120, b * 16, b1, nullptr, z, 2800);
        else if (b >= 175 && b <= 193)
            gemm_lds(lds + KW_TILE_B, 35,
                     shH, shM, shL, SP_, SP_, fhH, fhM, fhL, FP_,
                     W1L, 1120, (156 + b - 175) * 16, b1, nullptr, z, 2800);
        gbar(flags, go, ++tgt);
        pw_phase<F_>(z, g1, bg1, gc1, bc1, fh, fc, fhH, fhM, fhL, FP_, hist, t, red);
        gbar(flags, go, ++tgt);
    }

    const int NF = B_ * F_, NS = B_ * S_;
    for (int i = gtid; i < 2 * NF + 2 * NS; i += G_ * TPB_) {
        float v = (i < NF) ? fh[i] : (i < 2 * NF) ? fc[i - NF]
                : (i < 2 * NF + NS) ? sh[i - 2 * NF] : sc[i - 2 * NF - NS];
        NTS(&outTail[i], v);
    }
}

// ---------------------------------------------------------------------------
// Output projection (r5-proven).
// ---------------------------------------------------------------------------
__global__ __launch_bounds__(512) void ogemm(
    const u16* __restrict__ A, const u16* __restrict__ Bt,
    const float* __restrict__ bias, float* __restrict__ C)
{
    const int N = V_;
    const int tid = threadIdx.x, lane = tid & 63, wid = tid >> 6;
    const int wm = wid >> 1, wn = wid & 1;
    const int row0 = blockIdx.y * 256 + wm * 64;
    const int col0 = blockIdx.x * 128 + wn * 64;
    const int lo = lane & 15, hi = lane >> 4;
    const int NT = FP_ / 32;

    v4f acc[4][4];
    #pragma unroll
    for (int i = 0; i < 4; ++i)
        #pragma unroll
        for (int j = 0; j < 4; ++j) acc[i][j] = (v4f)0.f;

    for (int kt = 0; kt < NT; ++kt) {
        const int kb = kt * 32 + hi * 8;
        v8s a[4], bfr[4];
        #pragma unroll
        for (int i = 0; i < 4; ++i) {
            a[i]   = *(const v8s*)(A  + (size_t)(row0 + i * 16 + lo) * FP_ + kb);
            bfr[i] = *(const v8s*)(Bt + (size_t)(col0 + i * 16 + lo) * FP_ + kb);
        }
        #pragma unroll
        for (int mf = 0; mf < 4; ++mf)
            #pragma unroll
            for (int nf = 0; nf < 4; ++nf)
                acc[mf][nf] = __builtin_amdgcn_mfma_f32_16x16x32_bf16(a[mf], bfr[nf], acc[mf][nf], 0, 0, 0);
    }

    #pragma unroll
    for (int mf = 0; mf < 4; ++mf) {
        #pragma unroll
        for (int nf = 0; nf < 4; ++nf) {
            int col = col0 + nf * 16 + lo;
            if (col < N) {
                float bb = bias[col];
                #pragma unroll
                for (int r = 0; r < 4; ++r) {
                    int row = row0 + mf * 16 + hi * 4 + r;
                    C[(size_t)row * N + col] = acc[mf][nf][r] + bb;
                }
            }
        }
    }
}

extern "C" void kernel_launch(void* const* d_in, const int* in_sizes, int n_in,
                              void* d_out, int out_size, void* d_ws, size_t ws_size,
                              hipStream_t stream) {
    const float* inputs = (const float*)d_in[0];
    const float* W0   = (const float*)d_in[1];
    const float* b0   = (const float*)d_in[2];
    const float* g0   = (const float*)d_in[3];
    const float* bg0  = (const float*)d_in[4];
    const float* gc0  = (const float*)d_in[5];
    const float* bc0  = (const float*)d_in[6];
    const float* W1   = (const float*)d_in[7];
    const float* b1   = (const float*)d_in[8];
    const float* g1   = (const float*)d_in[9];
    const float* bg1  = (const float*)d_in[10];
    const float* gc1  = (const float*)d_in[11];
    const float* bc1  = (const float*)d_in[12];
    const float* WS   = (const float*)d_in[13];
    const float* bS   = (const float*)d_in[14];
    const float* gS   = (const float*)d_in[15];
    const float* bgS  = (const float*)d_in[16];
    const float* gcS  = (const float*)d_in[17];
    const float* bcS  = (const float*)d_in[18];
    const float* Wout = (const float*)d_in[19];
    const float* bout = (const float*)d_in[20];

    // ---- ws: states + z + hist + Wtout + flags/go (~34.9 MB, known-safe)
    float* ws = (float*)d_ws;
    float* fh = ws;
    float* fc = fh + B_ * F_;
    float* sh = fc + B_ * F_;
    float* sc = sh + B_ * S_;
    float* z  = sc + B_ * S_;
    u16* hist = (u16*)(z + (size_t)B_ * 4 * F_);
    u16* Wtout = hist + (size_t)12800 * FP_;
    unsigned* flags = (unsigned*)(Wtout + (size_t)10112 * FP_);
    unsigned* go    = flags + G_ * 16;

    // ---- d_out scratch (fully rewritten every call; dead before ogemm)
    const size_t P0 = (size_t)2816 * 832;
    const size_t PS = (size_t)1664 * 1120;
    const size_t P1 = (size_t)2816 * 1120;
    const size_t HF = (size_t)B_ * FP_;
    const size_t HS = (size_t)B_ * SP_;
    u16* dp  = (u16*)d_out;
    u16* W0H = dp;          u16* W0M = W0H + P0;  u16* W0L = W0M + P0;
    u16* WSH = W0L + P0;    u16* WSM = WSH + PS;  u16* WSL = WSM + PS;
    u16* W1H = WSL + PS;    u16* W1M = W1H + P1;  u16* W1L = W1M + P1;
    u16* fhH = W1L + P1;    u16* fhM = fhH + HF;  u16* fhL = fhM + HF;
    u16* shH = fhL + HF;    u16* shM = shH + HS;  u16* shL = shM + HS;
    float* zx = (float*)(shL + HS);

    hipMemsetAsync(flags, 0, (G_ * 16 + 16) * sizeof(unsigned), stream);

    wtrans3<<<dim3(88, 26), 256, 0, stream>>>(W0, E_ + F_, 4 * F_, W0H, W0M, W0L, 832, 128, 128);
    wtrans3<<<dim3(52, 35), 256, 0, stream>>>(WS, F_ + S_, 4 * S_, WSH, WSM, WSL, 1120, F_, FP_);
    wtrans3<<<dim3(88, 35), 256, 0, stream>>>(W1, S_ + F_, 4 * F_, W1H, W1M, W1L, 1120, S_, SP_);
    wtrans<<<dim3(316, 22), 256, 0, stream>>>(Wout, F_, V_, Wtout, FP_);

    zxpre<<<2188, 512, 0, stream>>>(inputs, W0H, W0M, W0L, b0, zx);

    // allow >64KB dynamic LDS (deterministic, idempotent host-side call)
    hipFuncSetAttribute((const void*)mega,
                        hipFuncAttributeMaxDynamicSharedMemorySize, LDS_BYTES);

    mega<<<G_, TPB_, LDS_BYTES, stream>>>(
        b0, g0, bg0, gc0, bc0,
        b1, g1, bg1, gc1, bc1,
        bS, gS, bgS, gcS, bcS,
        zx,
        fh, fc, sh, sc, z, hist,
        fhH, fhM, fhL, shH, shM, shL,
        W0H, W0M, W0L, WSH, WSM, WSL, W1H, W1M, W1L,
        (float*)d_out + (size_t)B_ * T_ * V_, flags, go);

    ogemm<<<dim3(79, 50), 512, 0, stream>>>(hist, Wtout, bout, (float*)d_out);
}

// Round 13
// 17290.417 us; speedup vs baseline: 2.9857x; 1.0327x over previous
//
#include <hip/hip_runtime.h>
#include <math.h>

// ---------------------------------------------------------------------------
// PTB LN-LSTM stack: B=128, T=100, E=128, F=700, S=400, V=10000.
// Round 13: latency-chain fixes (r12 showed traffic is trivial: 1.6GB @96GB/s;
// phase time == NT serial L3/L2-cold round trips of the 1-deep prefetch):
//   (1) depth-3 register ring for A/L-plane loads (issue kt+3 after consuming
//       kt) -> ~12 serial RTs instead of 35 per GEMM phase.
//   (2) blockSum8: one syncthreads-pair for all 8 LN partials (PW had 8
//       sequential blockSums = ~20 syncthreads/phase).
// Weights stay in LDS (r12-proven). MFMA order unchanged -> absmax 0.03125.
// ---------------------------------------------------------------------------

#define B_ 128
#define T_ 100
#define E_ 128
#define F_ 700
#define S_ 400
#define V_ 10000

#define FP_ 704    // F padded
#define SP_ 416    // S padded
#define G_  256    // mega blocks
#define TPB_ 512   // threads per mega block (8 waves)

#define W0_TILE_B 45056    // 22 kt * 2048
#define KW_TILE_B 71680    // 35 kt * 2048
#define LDS_BYTES 143360   // max: two KW tiles

using v8s = __attribute__((ext_vector_type(8))) short;
using v4f = __attribute__((ext_vector_type(4))) float;
typedef unsigned short u16;

#define NTS(p, v) __builtin_nontemporal_store((v), (p))
#define NTL(p)    __builtin_nontemporal_load((p))

__device__ __forceinline__ u16 f2bf(float x) {
    unsigned int u = __float_as_uint(x);
    u += 0x7FFFu + ((u >> 16) & 1u);
    return (u16)(u >> 16);
}
__device__ __forceinline__ float bf2f(u16 h) {
    return __uint_as_float(((unsigned int)h) << 16);
}
__device__ __forceinline__ void split3f(float x, u16& h, u16& m, u16& l) {
    h = f2bf(x); float r  = x - bf2f(h);
    m = f2bf(r); float r2 = r - bf2f(m);
    l = f2bf(r2);
}
__device__ __forceinline__ float sigm(float x) { return 1.0f / (1.0f + expf(-x)); }

// ---------------------------------------------------------------------------
// Grid barrier (r9-proven, unchanged).
// ---------------------------------------------------------------------------
__device__ __forceinline__ void gbar(unsigned* flags, unsigned* go, unsigned target) {
    __syncthreads();
    if (threadIdx.x == 0) {
        __threadfence();
        __hip_atomic_store(flags + (size_t)blockIdx.x * 16, target,
                           __ATOMIC_RELEASE, __HIP_MEMORY_SCOPE_AGENT);
        __threadfence();
    }
    if (blockIdx.x == 0) {
        if (threadIdx.x < G_) {
            const unsigned* f = flags + (size_t)threadIdx.x * 16;
            while (__hip_atomic_load(f, __ATOMIC_RELAXED, __HIP_MEMORY_SCOPE_AGENT) < target)
                __builtin_amdgcn_s_sleep(1);
        }
        __syncthreads();
        if (threadIdx.x == 0)
            __hip_atomic_store(go, target, __ATOMIC_RELEASE, __HIP_MEMORY_SCOPE_AGENT);
    } else {
        if (threadIdx.x == 0) {
            while (__hip_atomic_load(go, __ATOMIC_RELAXED, __HIP_MEMORY_SCOPE_AGENT) < target)
                __builtin_amdgcn_s_sleep(1);
        }
    }
    __syncthreads();
}

// ---------------------------------------------------------------------------
// Transpose+split kernels (r5-proven; full-coverage writes).
// ---------------------------------------------------------------------------
__global__ __launch_bounds__(256) void wtrans3(
    const float* __restrict__ W, int K, int N,
    u16* __restrict__ WtH, u16* __restrict__ WtM, u16* __restrict__ WtL,
    int Kp, int K1, int K1pad)
{
    __shared__ float t[32][33];
    const int c0 = blockIdx.x * 32, kp0 = blockIdx.y * 32;
    const int tx = threadIdx.x & 31, ty = threadIdx.x >> 5;
    #pragma unroll
    for (int i = 0; i < 4; ++i) {
        int kpos = kp0 + ty + i * 8, c = c0 + tx;
        int k = (kpos < K1) ? kpos : (kpos >= K1pad ? K1 + (kpos - K1pad) : -1);
        t[ty + i * 8][tx] = (k >= 0 && k < K && c < N) ? W[(size_t)k * N + c] : 0.f;
    }
    __syncthreads();
    #pragma unroll
    for (int i = 0; i < 4; ++i) {
        int r = c0 + ty + i * 8;
        u16 h, m, l;
        split3f(t[tx][ty + i * 8], h, m, l);
        size_t idx = (size_t)r * Kp + kp0 + tx;
        WtH[idx] = h; WtM[idx] = m; WtL[idx] = l;
    }
}

__global__ __launch_bounds__(256) void wtrans(
    const float* __restrict__ W, int K, int N,
    u16* __restrict__ Wt, int Kpad)
{
    __shared__ float t[32][33];
    const int c0 = blockIdx.x * 32, k0 = blockIdx.y * 32;
    const int tx = threadIdx.x & 31, ty = threadIdx.x >> 5;
    #pragma unroll
    for (int i = 0; i < 4; ++i) {
        int k = k0 + ty + i * 8, c = c0 + tx;
        t[ty + i * 8][tx] = (k < K && c < N) ? W[(size_t)k * N + c] : 0.f;
    }
    __syncthreads();
    #pragma unroll
    for (int i = 0; i < 4; ++i) {
        int r = c0 + ty + i * 8;
        Wt[(size_t)r * Kpad + k0 + tx] = f2bf(t[tx][ty + i * 8]);
    }
}

// ---------------------------------------------------------------------------
// zx precompute (r7-proven).
// ---------------------------------------------------------------------------
__global__ __launch_bounds__(512, 1) void zxpre(
    const float* __restrict__ inputs,
    const u16* __restrict__ WH, const u16* __restrict__ WM,
    const u16* __restrict__ WL, const float* __restrict__ b0,
    float* __restrict__ zx)
{
    const int lane = threadIdx.x & 63, wid = threadIdx.x >> 6;
    const int lo = lane & 15, hi = lane >> 4;
    const int ntiles = 175 * 100;
    for (int i = blockIdx.x * 8 + wid; i < ntiles; i += gridDim.x * 8) {
        const int t = i / 175, ct = i % 175;
        v4f acc[8];
        #pragma unroll
        for (int m = 0; m < 8; ++m) acc[m] = (v4f)0.f;
        const size_t bb = (size_t)(ct * 16 + lo) * 832 + hi * 8;
        for (int kt = 0; kt < 4; ++kt) {
            const size_t bo = bb + kt * 32;
            v8s bh = *(const v8s*)(WH + bo);
            v8s bm = *(const v8s*)(WM + bo);
            v8s bl = *(const v8s*)(WL + bo);
            #pragma unroll
            for (int m = 0; m < 8; ++m) {
                const float* p = inputs + (size_t)(m * 16 + lo) * (T_ * E_)
                               + (size_t)t * E_ + kt * 32 + hi * 8;
                float v0[8];
                *(float4*)(v0)     = *(const float4*)(p);
                *(float4*)(v0 + 4) = *(const float4*)(p + 4);
                v8s ah, am, al;
                #pragma unroll
                for (int j = 0; j < 8; ++j) {
                    u16 H, M, L; split3f(v0[j], H, M, L);
                    ah[j] = (short)H; am[j] = (short)M; al[j] = (short)L;
                }
                acc[m] = __builtin_amdgcn_mfma_f32_16x16x32_bf16(ah, bh, acc[m], 0, 0, 0);
                acc[m] = __builtin_amdgcn_mfma_f32_16x16x32_bf16(ah, bm, acc[m], 0, 0, 0);
                acc[m] = __builtin_amdgcn_mfma_f32_16x16x32_bf16(am, bh, acc[m], 0, 0, 0);
                acc[m] = __builtin_amdgcn_mfma_f32_16x16x32_bf16(ah, bl, acc[m], 0, 0, 0);
                acc[m] = __builtin_amdgcn_mfma_f32_16x16x32_bf16(al, bh, acc[m], 0, 0, 0);
                acc[m] = __builtin_amdgcn_mfma_f32_16x16x32_bf16(am, bm, acc[m], 0, 0, 0);
            }
        }
        const int col = ct * 16 + lo;
        const float bb0 = b0[col];
        #pragma unroll
        for (int m = 0; m < 8; ++m)
            #pragma unroll
            for (int r = 0; r < 4; ++r) {
                int row = m * 16 + hi * 4 + r;
                NTS(&zx[((size_t)t * B_ + row) * 2800 + col], acc[m][r] + bb0);
            }
    }
}

// ---------------------------------------------------------------------------
// LDS weight-tile fill (r12-proven).
// ---------------------------------------------------------------------------
__device__ void fill_tile(char* dst, const u16* __restrict__ H,
                          const u16* __restrict__ M, int Kp, int gcol0, int NT)
{
    const int n = 16 * NT * 4;
    for (int idx = threadIdx.x; idx < n; idx += TPB_) {
        const int c   = idx & 3;
        const int kt  = (idx >> 2) % NT;
        const int col = (idx >> 2) / NT;
        const size_t g = (size_t)(gcol0 + col) * Kp + kt * 32 + c * 8;
        const int o = kt * 2048 + col * 64 + c * 16;
        *(v8s*)(dst + o)        = *(const v8s*)(H + g);
        *(v8s*)(dst + o + 1024) = *(const v8s*)(M + g);
    }
}

// ---------------------------------------------------------------------------
// GEMM phase with depth-3 A/L register ring. B H/M from LDS. MFMA order per
// acc identical to r5-r12 (sequential kt, 6 products per kt).
// ---------------------------------------------------------------------------
__device__ void gemm_lds(
    const char* lt, int NT,
    const u16* __restrict__ A1H, const u16* __restrict__ A1M,
    const u16* __restrict__ A1L, int lda1, int K1pad,
    const u16* __restrict__ A2H, const u16* __restrict__ A2M,
    const u16* __restrict__ A2L, int lda2,
    const u16* __restrict__ WL, int KpL, int col0,
    const float* __restrict__ bias, const float* __restrict__ zadd,
    float* __restrict__ z, int N)
{
    const int lane = threadIdx.x & 63;
    const int lo = lane & 15, hi = lane >> 4;
    const int r0 = (threadIdx.x >> 6) * 16;
    v4f acc = (v4f)0.f;
    const u16* blp = WL + (size_t)(col0 + lo) * KpL + hi * 8;
    const size_t arow = (size_t)(r0 + lo);

    v8s aH[3], aM[3], aL[3], bL[3];
    #pragma unroll
    for (int s = 0; s < 3; ++s) {
        const int kb2 = s * 32;
        const bool s1 = kb2 < K1pad;
        const size_t ao = arow * (s1 ? lda1 : lda2)
                        + (s1 ? kb2 : kb2 - K1pad) + hi * 8;
        aH[s] = *(const v8s*)((s1 ? A1H : A2H) + ao);
        aM[s] = *(const v8s*)((s1 ? A1M : A2M) + ao);
        aL[s] = *(const v8s*)((s1 ? A1L : A2L) + ao);
        bL[s] = *(const v8s*)(blp + kb2);
    }

    for (int kt0 = 0; kt0 < NT; kt0 += 3) {
        #pragma unroll
        for (int j = 0; j < 3; ++j) {
            const int kt = kt0 + j;
            if (kt < NT) {
                const int lb = kt * 2048 + lo * 64 + hi * 16;
                v8s bh = *(const v8s*)(lt + lb);
                v8s bm = *(const v8s*)(lt + lb + 1024);
                acc = __builtin_amdgcn_mfma_f32_16x16x32_bf16(aH[j], bh,    acc, 0, 0, 0);
                acc = __builtin_amdgcn_mfma_f32_16x16x32_bf16(aH[j], bm,    acc, 0, 0, 0);
                acc = __builtin_amdgcn_mfma_f32_16x16x32_bf16(aM[j], bh,    acc, 0, 0, 0);
                acc = __builtin_amdgcn_mfma_f32_16x16x32_bf16(aH[j], bL[j], acc, 0, 0, 0);
                acc = __builtin_amdgcn_mfma_f32_16x16x32_bf16(aL[j], bh,    acc, 0, 0, 0);
                acc = __builtin_amdgcn_mfma_f32_16x16x32_bf16(aM[j], bm,    acc, 0, 0, 0);
                const int kn = kt + 3;
                if (kn < NT) {
                    const int kb2 = kn * 32;
                    const bool s1 = kb2 < K1pad;
                    const size_t ao = arow * (s1 ? lda1 : lda2)
                                    + (s1 ? kb2 : kb2 - K1pad) + hi * 8;
                    aH[j] = *(const v8s*)((s1 ? A1H : A2H) + ao);
                    aM[j] = *(const v8s*)((s1 ? A1M : A2M) + ao);
                    aL[j] = *(const v8s*)((s1 ? A1L : A2L) + ao);
                    bL[j] = *(const v8s*)(blp + kb2);
                }
            }
        }
    }

    const int col = col0 + lo;
    if (zadd) {
        #pragma unroll
        for (int r = 0; r < 4; ++r) {
            int row = r0 + hi * 4 + r;
            float za = NTL(&zadd[(size_t)row * N + col]);
            NTS(&z[(size_t)row * N + col], acc[r] + za);
        }
    } else {
        const float bv = bias[col];
        #pragma unroll
        for (int r = 0; r < 4; ++r) {
            int row = r0 + hi * 4 + r;
            NTS(&z[(size_t)row * N + col], acc[r] + bv);
        }
    }
}

// ---------------------------------------------------------------------------
// Batched block reduction: reduces v[0..n) across 512 threads with ONE
// syncthreads pair. Per-value summation order identical to old blockSum
// (wave shfl chain, then red[0]+red[1]+...+red[7]).
// ---------------------------------------------------------------------------
template <int NV>
__device__ __forceinline__ void blockSumN(float* v, float* red) {
    const int w = threadIdx.x >> 6, lane = threadIdx.x & 63;
    #pragma unroll
    for (int k = 0; k < NV; ++k) {
        float x = v[k];
        #pragma unroll
        for (int off = 32; off > 0; off >>= 1) x += __shfl_down(x, off, 64);
        v[k] = x;
    }
    __syncthreads();
    if (lane == 0) {
        #pragma unroll
        for (int k = 0; k < NV; ++k) red[k * 8 + w] = v[k];
    }
    __syncthreads();
    #pragma unroll
    for (int k = 0; k < NV; ++k) {
        float r = 0.f;
        #pragma unroll
        for (int j = 0; j < 8; ++j) r += red[k * 8 + j];
        v[k] = r;
    }
    __syncthreads();   // protect red[] reuse across calls
}

// ---------------------------------------------------------------------------
// Pointwise phase (r9 math; batched reductions).
// ---------------------------------------------------------------------------
template <int FF>
__device__ void pw_phase(const float* __restrict__ z,
    const float* __restrict__ gg, const float* __restrict__ bg,
    const float* __restrict__ gc, const float* __restrict__ bc,
    float* __restrict__ h, float* __restrict__ c,
    u16* __restrict__ hpH, u16* __restrict__ hpM, u16* __restrict__ hpL,
    int hstride, u16* __restrict__ hist, int t, float* red)
{
    const int tid = threadIdx.x;
    constexpr int NU = (FF + TPB_ - 1) / TPB_;
    for (int b = blockIdx.x; b < B_; b += G_) {
        const float* zr = z + (size_t)b * 4 * FF;
        float* hr = h + (size_t)b * FF;
        float* cr = c + (size_t)b * FF;

        float sv[8] = {0, 0, 0, 0, 0, 0, 0, 0};   // s[0..3], q[0..3]
        #pragma unroll
        for (int i = 0; i < NU; ++i) {
            int u = tid + i * TPB_;
            if (u < FF) {
                #pragma unroll
                for (int g = 0; g < 4; ++g) {
                    float v = NTL(&zr[g * FF + u]);
                    sv[g] += v; sv[4 + g] += v * v;
                }
            }
        }
        blockSumN<8>(sv, red);
        float mu[4], rs[4];
        #pragma unroll
        for (int g = 0; g < 4; ++g) {
            mu[g] = sv[g] / FF;
            rs[g] = rsqrtf(sv[4 + g] / FF - mu[g] * mu[g] + 1e-5f);
        }

        float nc[NU], og[NU], ho[NU], co[NU];
        float cv[2] = {0, 0};   // cs, cq
        #pragma unroll
        for (int i = 0; i < NU; ++i) {
            int u = tid + i * TPB_;
            if (u < FF) {
                float zi = (NTL(&zr[u])          - mu[0]) * rs[0] * gg[u]          + bg[u];
                float zj = (NTL(&zr[FF + u])     - mu[1]) * rs[1] * gg[FF + u]     + bg[FF + u];
                float zf = (NTL(&zr[2 * FF + u]) - mu[2]) * rs[2] * gg[2 * FF + u] + bg[2 * FF + u];
                float zo = (NTL(&zr[3 * FF + u]) - mu[3]) * rs[3] * gg[3 * FF + u] + bg[3 * FF + u];
                float cold = cr[u];
                float ncv = cold * sigm(zf + 1.0f) + sigm(zi) * tanhf(zj);
                nc[i] = ncv; og[i] = sigm(zo); co[i] = cold; ho[i] = hr[u];
                cv[0] += ncv; cv[1] += ncv * ncv;
            } else { nc[i] = 0.f; og[i] = 0.f; co[i] = 0.f; ho[i] = 0.f; }
        }
        blockSumN<2>(cv, red);
        float muc = cv[0] / FF;
        float rsc = rsqrtf(cv[1] / FF - muc * muc + 1e-5f);

        #pragma unroll
        for (int i = 0; i < NU; ++i) {
            int u = tid + i * TPB_;
            if (u < FF) {
                float nh = tanhf((nc[i] - muc) * rsc * gc[u] + bc[u]) * og[i];
                float hout = 0.9f * nh + 0.1f * ho[i];
                float cout = 0.5f * nc[i] + 0.5f * co[i];
                NTS(&hr[u], hout);
                NTS(&cr[u], cout);
                u16 H, M, L;
                split3f(hout, H, M, L);
                size_t po = (size_t)b * hstride + u;
                NTS(&hpH[po], H); NTS(&hpM[po], M); NTS(&hpL[po], L);
                if (hist) NTS(&hist[((size_t)b * T_ + t) * FP_ + u], H);
            }
        }
        if (hist && tid < FP_ - FF)
            NTS(&hist[((size_t)b * T_ + t) * FP_ + FF + tid], (u16)0);
    }
}

// ---------------------------------------------------------------------------
// Mega: LDS-fill -> init -> 100 x (GEMM0|PW0|GEMMS|PWS|GEMM1|PW1) -> tail.
// Tile map: b<=155:{W0[b],W1[b]} 156..174:{W0[b],WS[b-156]}
//           175..193:{WS[b-156],W1[156+b-175]} 194..255:{WS[b-156]}
// ---------------------------------------------------------------------------
__global__ __launch_bounds__(TPB_) void mega(
    const float* __restrict__ b0, const float* __restrict__ g0,
    const float* __restrict__ bg0, const float* __restrict__ gc0,
    const float* __restrict__ bc0,
    const float* __restrict__ b1, const float* __restrict__ g1,
    const float* __restrict__ bg1, const float* __restrict__ gc1,
    const float* __restrict__ bc1,
    const float* __restrict__ bS, const float* __restrict__ gS,
    const float* __restrict__ bgS, const float* __restrict__ gcS,
    const float* __restrict__ bcS,
    const float* __restrict__ zx,
    float* fh, float* fc, float* sh, float* sc, float* z, u16* hist,
    u16* fhH, u16* fhM, u16* fhL, u16* shH, u16* shM, u16* shL,
    u16* W0H, u16* W0M, u16* W0L, u16* WSH, u16* WSM, u16* WSL,
    u16* W1H, u16* W1M, u16* W1L,
    float* outTail, unsigned* flags, unsigned* go)
{
    extern __shared__ char lds[];
    __shared__ float red[64];
    const int b = blockIdx.x;
    const int gtid = blockIdx.x * TPB_ + threadIdx.x;
    unsigned tgt = 0;

    // one-time LDS weight fill
    if (b <= 174) {
        fill_tile(lds, W0H + 128, W0M + 128, 832, b * 16, 22);
        if (b <= 155) fill_tile(lds + W0_TILE_B, W1H, W1M, 1120, b * 16, 35);
        else          fill_tile(lds + W0_TILE_B, WSH, WSM, 1120, (b - 156) * 16, 35);
    } else {
        fill_tile(lds, WSH, WSM, 1120, (b - 156) * 16, 35);
        if (b <= 193)
            fill_tile(lds + KW_TILE_B, W1H, W1M, 1120, (156 + b - 175) * 16, 35);
    }

    for (int i = gtid; i < 2 * B_ * F_ + 2 * B_ * S_; i += G_ * TPB_) NTS(&fh[i], 0.f);
    for (int i = gtid; i < 3 * B_ * FP_ + 3 * B_ * SP_; i += G_ * TPB_) NTS(&fhH[i], (u16)0);
    gbar(flags, go, ++tgt);

    for (int t = 0; t < T_; ++t) {
        if (b <= 174)
            gemm_lds(lds, 22,
                     fhH, fhM, fhL, FP_, FP_, fhH, fhM, fhL, FP_,
                     W0L + 128, 832, b * 16,
                     nullptr, zx + (size_t)t * B_ * 2800, z, 2800);
        gbar(flags, go, ++tgt);
        pw_phase<F_>(z, g0, bg0, gc0, bc0, fh, fc, fhH, fhM, fhL, FP_, nullptr, 0, red);
        gbar(flags, go, ++tgt);
        if (b >= 156)
            gemm_lds(lds + (b <= 174 ? W0_TILE_B : 0), 35,
                     fhH, fhM, fhL, FP_, FP_, shH, shM, shL, SP_,
                     WSL, 1120, (b - 156) * 16,
                     bS, nullptr, z, 1600);
        gbar(flags, go, ++tgt);
        pw_phase<S_>(z, gS, bgS, gcS, bcS, sh, sc, shH, shM, shL, SP_, nullptr, 0, red);
        gbar(flags, go, ++tgt);
        if (b <= 155)
            gemm_lds(lds + W0_TILE_B, 35,
                     shH, shM, shL, SP_, SP_, fhH, fhM, fhL, FP_,
                     W1L, 1120, b * 16, b1, nullptr, z, 2800);
        else if (b >= 175 && b <= 193)
            gemm_lds(lds + KW_TILE_B, 35,
                     shH, shM, shL, SP_, SP_, fhH, fhM, fhL, FP_,
                     W1L, 1120, (156 + b - 175) * 16, b1, nullptr, z, 2800);
        gbar(flags, go, ++tgt);
        pw_phase<F_>(z, g1, bg1, gc1, bc1, fh, fc, fhH, fhM, fhL, FP_, hist, t, red);
        gbar(flags, go, ++tgt);
    }

    const int NF = B_ * F_, NS = B_ * S_;
    for (int i = gtid; i < 2 * NF + 2 * NS; i += G_ * TPB_) {
        float v = (i < NF) ? fh[i] : (i < 2 * NF) ? fc[i - NF]
                : (i < 2 * NF + NS) ? sh[i - 2 * NF] : sc[i - 2 * NF - NS];
        NTS(&outTail[i], v);
    }
}

// ---------------------------------------------------------------------------
// Output projection (r5-proven).
// ---------------------------------------------------------------------------
__global__ __launch_bounds__(512) void ogemm(
    const u16* __restrict__ A, const u16* __restrict__ Bt,
    const float* __restrict__ bias, float* __restrict__ C)
{
    const int N = V_;
    const int tid = threadIdx.x, lane = tid & 63, wid = tid >> 6;
    const int wm = wid >> 1, wn = wid & 1;
    const int row0 = blockIdx.y * 256 + wm * 64;
    const int col0 = blockIdx.x * 128 + wn * 64;
    const int lo = lane & 15, hi = lane >> 4;
    const int NT = FP_ / 32;

    v4f acc[4][4];
    #pragma unroll
    for (int i = 0; i < 4; ++i)
        #pragma unroll
        for (int j = 0; j < 4; ++j) acc[i][j] = (v4f)0.f;

    for (int kt = 0; kt < NT; ++kt) {
        const int kb = kt * 32 + hi * 8;
        v8s a[4], bfr[4];
        #pragma unroll
        for (int i = 0; i < 4; ++i) {
            a[i]   = *(const v8s*)(A  + (size_t)(row0 + i * 16 + lo) * FP_ + kb);
            bfr[i] = *(const v8s*)(Bt + (size_t)(col0 + i * 16 + lo) * FP_ + kb);
        }
        #pragma unroll
        for (int mf = 0; mf < 4; ++mf)
            #pragma unroll
            for (int nf = 0; nf < 4; ++nf)
                acc[mf][nf] = __builtin_amdgcn_mfma_f32_16x16x32_bf16(a[mf], bfr[nf], acc[mf][nf], 0, 0, 0);
    }

    #pragma unroll
    for (int mf = 0; mf < 4; ++mf) {
        #pragma unroll
        for (int nf = 0; nf < 4; ++nf) {
            int col = col0 + nf * 16 + lo;
            if (col < N) {
                float bb = bias[col];
                #pragma unroll
                for (int r = 0; r < 4; ++r) {
                    int row = row0 + mf * 16 + hi * 4 + r;
                    C[(size_t)row * N + col] = acc[mf][nf][r] + bb;
                }
            }
        }
    }
}

extern "C" void kernel_launch(void* const* d_in, const int* in_sizes, int n_in,
                              void* d_out, int out_size, void* d_ws, size_t ws_size,
                              hipStream_t stream) {
    const float* inputs = (const float*)d_in[0];
    const float* W0   = (const float*)d_in[1];
    const float* b0   = (const float*)d_in[2];
    const float* g0   = (const float*)d_in[3];
    const float* bg0  = (const float*)d_in[4];
    const float* gc0  = (const float*)d_in[5];
    const float* bc0  = (const float*)d_in[6];
    const float* W1   = (const float*)d_in[7];
    const float* b1   = (const float*)d_in[8];
    const float* g1   = (const float*)d_in[9];
    const float* bg1  = (const float*)d_in[10];
    const float* gc1  = (const float*)d_in[11];
    const float* bc1  = (const float*)d_in[12];
    const float* WS   = (const float*)d_in[13];
    const float* bS   = (const float*)d_in[14];
    const float* gS   = (const float*)d_in[15];
    const float* bgS  = (const float*)d_in[16];
    const float* gcS  = (const float*)d_in[17];
    const float* bcS  = (const float*)d_in[18];
    const float* Wout = (const float*)d_in[19];
    const float* bout = (const float*)d_in[20];

    // ---- ws: states + z + hist + Wtout + flags/go (~34.9 MB, known-safe)
    float* ws = (float*)d_ws;
    float* fh = ws;
    float* fc = fh + B_ * F_;
    float* sh = fc + B_ * F_;
    float* sc = sh + B_ * S_;
    float* z  = sc + B_ * S_;
    u16* hist = (u16*)(z + (size_t)B_ * 4 * F_);
    u16* Wtout = hist + (size_t)12800 * FP_;
    unsigned* flags = (unsigned*)(Wtout + (size_t)10112 * FP_);
    unsigned* go    = flags + G_ * 16;

    // ---- d_out scratch (fully rewritten every call; dead before ogemm)
    const size_t P0 = (size_t)2816 * 832;
    const size_t PS = (size_t)1664 * 1120;
    const size_t P1 = (size_t)2816 * 1120;
    const size_t HF = (size_t)B_ * FP_;
    const size_t HS = (size_t)B_ * SP_;
    u16* dp  = (u16*)d_out;
    u16* W0H = dp;          u16* W0M = W0H + P0;  u16* W0L = W0M + P0;
    u16* WSH = W0L + P0;    u16* WSM = WSH + PS;  u16* WSL = WSM + PS;
    u16* W1H = WSL + PS;    u16* W1M = W1H + P1;  u16* W1L = W1M + P1;
    u16* fhH = W1L + P1;    u16* fhM = fhH + HF;  u16* fhL = fhM + HF;
    u16* shH = fhL + HF;    u16* shM = shH + HS;  u16* shL = shM + HS;
    float* zx = (float*)(shL + HS);

    hipMemsetAsync(flags, 0, (G_ * 16 + 16) * sizeof(unsigned), stream);

    wtrans3<<<dim3(88, 26), 256, 0, stream>>>(W0, E_ + F_, 4 * F_, W0H, W0M, W0L, 832, 128, 128);
    wtrans3<<<dim3(52, 35), 256, 0, stream>>>(WS, F_ + S_, 4 * S_, WSH, WSM, WSL, 1120, F_, FP_);
    wtrans3<<<dim3(88, 35), 256, 0, stream>>>(W1, S_ + F_, 4 * F_, W1H, W1M, W1L, 1120, S_, SP_);
    wtrans<<<dim3(316, 22), 256, 0, stream>>>(Wout, F_, V_, Wtout, FP_);

    zxpre<<<2188, 512, 0, stream>>>(inputs, W0H, W0M, W0L, b0, zx);

    hipFuncSetAttribute((const void*)mega,
                        hipFuncAttributeMaxDynamicSharedMemorySize, LDS_BYTES);

    mega<<<G_, TPB_, LDS_BYTES, stream>>>(
        b0, g0, bg0, gc0, bc0,
        b1, g1, bg1, gc1, bc1,
        bS, gS, bgS, gcS, bcS,
        zx,
        fh, fc, sh, sc, z, hist,
        fhH, fhM, fhL, shH, shM, shL,
        W0H, W0M, W0L, WSH, WSM, WSL, W1H, W1M, W1L,
        (float*)d_out + (size_t)B_ * T_ * V_, flags, go);

    ogemm<<<dim3(79, 50), 512, 0, stream>>>(hist, Wtout, bout, (float*)d_out);
}

// Round 14
// 11436.098 us; speedup vs baseline: 4.5141x; 1.5119x over previous
//
#include <hip/hip_runtime.h>
#include <math.h>

// ---------------------------------------------------------------------------
// PTB LN-LSTM stack: B=128, T=100, E=128, F=700, S=400, V=10000.
// Round 14: kill the barrier's cache-maintenance cost. r13 measured ~27us per
// phase with ~5us of work; the gbar executed FIVE L2-walk ops per barrier
// (2x threadfence = wbl2+inv each, + release-store wbl2, ~3-4us each).
// Now: ALL global stores in mega are write-through coherent (sc0 sc1) so L2
// is never dirty -> no wbl2 anywhere; barrier = vmcnt-drain + relaxed flag +
// ONE buffer_inv (overlapping the go-wait) + relaxed poll.
// Loads stay normal/cached (post-inv refill from L3 is fresh).
// GEMM/PW arithmetic untouched -> absmax must stay exactly 0.03125.
// ---------------------------------------------------------------------------

#define B_ 128
#define T_ 100
#define E_ 128
#define F_ 700
#define S_ 400
#define V_ 10000

#define FP_ 704    // F padded
#define SP_ 416    // S padded
#define G_  256    // mega blocks
#define TPB_ 512   // threads per mega block (8 waves)

#define W0_TILE_B 45056    // 22 kt * 2048
#define KW_TILE_B 71680    // 35 kt * 2048
#define LDS_BYTES 143360   // max: two KW tiles

using v8s = __attribute__((ext_vector_type(8))) short;
using v4f = __attribute__((ext_vector_type(4))) float;
typedef unsigned short u16;

#define NTL(p)    __builtin_nontemporal_load((p))

// Write-through device-coherent stores (never dirty L2).
__device__ __forceinline__ void stcohf(float* p, float v) {
    asm volatile("global_store_dword %0, %1, off sc0 sc1" :: "v"(p), "v"(v) : "memory");
}
__device__ __forceinline__ void stcohs(u16* p, u16 v) {
    unsigned w = v;
    asm volatile("global_store_short %0, %1, off sc0 sc1" :: "v"(p), "v"(w) : "memory");
}

__device__ __forceinline__ u16 f2bf(float x) {
    unsigned int u = __float_as_uint(x);
    u += 0x7FFFu + ((u >> 16) & 1u);
    return (u16)(u >> 16);
}
__device__ __forceinline__ float bf2f(u16 h) {
    return __uint_as_float(((unsigned int)h) << 16);
}
__device__ __forceinline__ void split3f(float x, u16& h, u16& m, u16& l) {
    h = f2bf(x); float r  = x - bf2f(h);
    m = f2bf(r); float r2 = r - bf2f(m);
    l = f2bf(r2);
}
__device__ __forceinline__ float sigm(float x) { return 1.0f / (1.0f + expf(-x)); }

// ---------------------------------------------------------------------------
// Fence-lean grid barrier.
//  - every wave drains its (write-through) stores: s_waitcnt vmcnt(0)
//  - arrive: RELAXED agent flag store (atomics operate at the coherence point)
//  - ONE buffer_inv sc0 sc1 per block, issued while waiting on `go`
//    (between inv and go the block touches only coherence-point atomics)
// ---------------------------------------------------------------------------
__device__ __forceinline__ void gbar(unsigned* flags, unsigned* go, unsigned target) {
    asm volatile("s_waitcnt vmcnt(0)" ::: "memory");
    __syncthreads();
    if (threadIdx.x == 0) {
        __hip_atomic_store(flags + (size_t)blockIdx.x * 16, target,
                           __ATOMIC_RELAXED, __HIP_MEMORY_SCOPE_AGENT);
        asm volatile("buffer_inv sc0 sc1" ::: "memory");
    }
    if (blockIdx.x == 0) {
        if (threadIdx.x < G_) {
            const unsigned* f = flags + (size_t)threadIdx.x * 16;
            while (__hip_atomic_load(f, __ATOMIC_RELAXED, __HIP_MEMORY_SCOPE_AGENT) < target)
                __builtin_amdgcn_s_sleep(1);
        }
        __syncthreads();
        if (threadIdx.x == 0)
            __hip_atomic_store(go, target, __ATOMIC_RELAXED, __HIP_MEMORY_SCOPE_AGENT);
    } else {
        if (threadIdx.x == 0) {
            while (__hip_atomic_load(go, __ATOMIC_RELAXED, __HIP_MEMORY_SCOPE_AGENT) < target)
                __builtin_amdgcn_s_sleep(1);
        }
    }
    __syncthreads();
}

// ---------------------------------------------------------------------------
// Transpose+split kernels (r5-proven; full-coverage writes).
// ---------------------------------------------------------------------------
__global__ __launch_bounds__(256) void wtrans3(
    const float* __restrict__ W, int K, int N,
    u16* __restrict__ WtH, u16* __restrict__ WtM, u16* __restrict__ WtL,
    int Kp, int K1, int K1pad)
{
    __shared__ float t[32][33];
    const int c0 = blockIdx.x * 32, kp0 = blockIdx.y * 32;
    const int tx = threadIdx.x & 31, ty = threadIdx.x >> 5;
    #pragma unroll
    for (int i = 0; i < 4; ++i) {
        int kpos = kp0 + ty + i * 8, c = c0 + tx;
        int k = (kpos < K1) ? kpos : (kpos >= K1pad ? K1 + (kpos - K1pad) : -1);
        t[ty + i * 8][tx] = (k >= 0 && k < K && c < N) ? W[(size_t)k * N + c] : 0.f;
    }
    __syncthreads();
    #pragma unroll
    for (int i = 0; i < 4; ++i) {
        int r = c0 + ty + i * 8;
        u16 h, m, l;
        split3f(t[tx][ty + i * 8], h, m, l);
        size_t idx = (size_t)r * Kp + kp0 + tx;
        WtH[idx] = h; WtM[idx] = m; WtL[idx] = l;
    }
}

__global__ __launch_bounds__(256) void wtrans(
    const float* __restrict__ W, int K, int N,
    u16* __restrict__ Wt, int Kpad)
{
    __shared__ float t[32][33];
    const int c0 = blockIdx.x * 32, k0 = blockIdx.y * 32;
    const int tx = threadIdx.x & 31, ty = threadIdx.x >> 5;
    #pragma unroll
    for (int i = 0; i < 4; ++i) {
        int k = k0 + ty + i * 8, c = c0 + tx;
        t[ty + i * 8][tx] = (k < K && c < N) ? W[(size_t)k * N + c] : 0.f;
    }
    __syncthreads();
    #pragma unroll
    for (int i = 0; i < 4; ++i) {
        int r = c0 + ty + i * 8;
        Wt[(size_t)r * Kpad + k0 + tx] = f2bf(t[tx][ty + i * 8]);
    }
}

// ---------------------------------------------------------------------------
// zx precompute (r7-proven).
// ---------------------------------------------------------------------------
__global__ __launch_bounds__(512, 1) void zxpre(
    const float* __restrict__ inputs,
    const u16* __restrict__ WH, const u16* __restrict__ WM,
    const u16* __restrict__ WL, const float* __restrict__ b0,
    float* __restrict__ zx)
{
    const int lane = threadIdx.x & 63, wid = threadIdx.x >> 6;
    const int lo = lane & 15, hi = lane >> 4;
    const int ntiles = 175 * 100;
    for (int i = blockIdx.x * 8 + wid; i < ntiles; i += gridDim.x * 8) {
        const int t = i / 175, ct = i % 175;
        v4f acc[8];
        #pragma unroll
        for (int m = 0; m < 8; ++m) acc[m] = (v4f)0.f;
        const size_t bb = (size_t)(ct * 16 + lo) * 832 + hi * 8;
        for (int kt = 0; kt < 4; ++kt) {
            const size_t bo = bb + kt * 32;
            v8s bh = *(const v8s*)(WH + bo);
            v8s bm = *(const v8s*)(WM + bo);
            v8s bl = *(const v8s*)(WL + bo);
            #pragma unroll
            for (int m = 0; m < 8; ++m) {
                const float* p = inputs + (size_t)(m * 16 + lo) * (T_ * E_)
                               + (size_t)t * E_ + kt * 32 + hi * 8;
                float v0[8];
                *(float4*)(v0)     = *(const float4*)(p);
                *(float4*)(v0 + 4) = *(const float4*)(p + 4);
                v8s ah, am, al;
                #pragma unroll
                for (int j = 0; j < 8; ++j) {
                    u16 H, M, L; split3f(v0[j], H, M, L);
                    ah[j] = (short)H; am[j] = (short)M; al[j] = (short)L;
                }
                acc[m] = __builtin_amdgcn_mfma_f32_16x16x32_bf16(ah, bh, acc[m], 0, 0, 0);
                acc[m] = __builtin_amdgcn_mfma_f32_16x16x32_bf16(ah, bm, acc[m], 0, 0, 0);
                acc[m] = __builtin_amdgcn_mfma_f32_16x16x32_bf16(am, bh, acc[m], 0, 0, 0);
                acc[m] = __builtin_amdgcn_mfma_f32_16x16x32_bf16(ah, bl, acc[m], 0, 0, 0);
                acc[m] = __builtin_amdgcn_mfma_f32_16x16x32_bf16(al, bh, acc[m], 0, 0, 0);
                acc[m] = __builtin_amdgcn_mfma_f32_16x16x32_bf16(am, bm, acc[m], 0, 0, 0);
            }
        }
        const int col = ct * 16 + lo;
        const float bb0 = b0[col];
        #pragma unroll
        for (int m = 0; m < 8; ++m)
            #pragma unroll
            for (int r = 0; r < 4; ++r) {
                int row = m * 16 + hi * 4 + r;
                zx[((size_t)t * B_ + row) * 2800 + col] = acc[m][r] + bb0;
            }
    }
}

// ---------------------------------------------------------------------------
// LDS weight-tile fill (r12-proven).
// ---------------------------------------------------------------------------
__device__ void fill_tile(char* dst, const u16* __restrict__ H,
                          const u16* __restrict__ M, int Kp, int gcol0, int NT)
{
    const int n = 16 * NT * 4;
    for (int idx = threadIdx.x; idx < n; idx += TPB_) {
        const int c   = idx & 3;
        const int kt  = (idx >> 2) % NT;
        const int col = (idx >> 2) / NT;
        const size_t g = (size_t)(gcol0 + col) * Kp + kt * 32 + c * 8;
        const int o = kt * 2048 + col * 64 + c * 16;
        *(v8s*)(dst + o)        = *(const v8s*)(H + g);
        *(v8s*)(dst + o + 1024) = *(const v8s*)(M + g);
    }
}

// ---------------------------------------------------------------------------
// GEMM phase (r13 structure: depth-3 A/L ring, B H/M from LDS).
// Only the z-stores changed (write-through coherent). MFMA order unchanged.
// ---------------------------------------------------------------------------
__device__ void gemm_lds(
    const char* lt, int NT,
    const u16* __restrict__ A1H, const u16* __restrict__ A1M,
    const u16* __restrict__ A1L, int lda1, int K1pad,
    const u16* __restrict__ A2H, const u16* __restrict__ A2M,
    const u16* __restrict__ A2L, int lda2,
    const u16* __restrict__ WL, int KpL, int col0,
    const float* __restrict__ bias, const float* __restrict__ zadd,
    float* __restrict__ z, int N)
{
    const int lane = threadIdx.x & 63;
    const int lo = lane & 15, hi = lane >> 4;
    const int r0 = (threadIdx.x >> 6) * 16;
    v4f acc = (v4f)0.f;
    const u16* blp = WL + (size_t)(col0 + lo) * KpL + hi * 8;
    const size_t arow = (size_t)(r0 + lo);

    v8s aH[3], aM[3], aL[3], bL[3];
    #pragma unroll
    for (int s = 0; s < 3; ++s) {
        const int kb2 = s * 32;
        const bool s1 = kb2 < K1pad;
        const size_t ao = arow * (s1 ? lda1 : lda2)
                        + (s1 ? kb2 : kb2 - K1pad) + hi * 8;
        aH[s] = *(const v8s*)((s1 ? A1H : A2H) + ao);
        aM[s] = *(const v8s*)((s1 ? A1M : A2M) + ao);
        aL[s] = *(const v8s*)((s1 ? A1L : A2L) + ao);
        bL[s] = *(const v8s*)(blp + kb2);
    }

    for (int kt0 = 0; kt0 < NT; kt0 += 3) {
        #pragma unroll
        for (int j = 0; j < 3; ++j) {
            const int kt = kt0 + j;
            if (kt < NT) {
                const int lb = kt * 2048 + lo * 64 + hi * 16;
                v8s bh = *(const v8s*)(lt + lb);
                v8s bm = *(const v8s*)(lt + lb + 1024);
                acc = __builtin_amdgcn_mfma_f32_16x16x32_bf16(aH[j], bh,    acc, 0, 0, 0);
                acc = __builtin_amdgcn_mfma_f32_16x16x32_bf16(aH[j], bm,    acc, 0, 0, 0);
                acc = __builtin_amdgcn_mfma_f32_16x16x32_bf16(aM[j], bh,    acc, 0, 0, 0);
                acc = __builtin_amdgcn_mfma_f32_16x16x32_bf16(aH[j], bL[j], acc, 0, 0, 0);
                acc = __builtin_amdgcn_mfma_f32_16x16x32_bf16(aL[j], bh,    acc, 0, 0, 0);
                acc = __builtin_amdgcn_mfma_f32_16x16x32_bf16(aM[j], bm,    acc, 0, 0, 0);
                const int kn = kt + 3;
                if (kn < NT) {
                    const int kb2 = kn * 32;
                    const bool s1 = kb2 < K1pad;
                    const size_t ao = arow * (s1 ? lda1 : lda2)
                                    + (s1 ? kb2 : kb2 - K1pad) + hi * 8;
                    aH[j] = *(const v8s*)((s1 ? A1H : A2H) + ao);
                    aM[j] = *(const v8s*)((s1 ? A1M : A2M) + ao);
                    aL[j] = *(const v8s*)((s1 ? A1L : A2L) + ao);
                    bL[j] = *(const v8s*)(blp + kb2);
                }
            }
        }
    }

    const int col = col0 + lo;
    if (zadd) {
        #pragma unroll
        for (int r = 0; r < 4; ++r) {
            int row = r0 + hi * 4 + r;
            float za = NTL(&zadd[(size_t)row * N + col]);
            stcohf(&z[(size_t)row * N + col], acc[r] + za);
        }
    } else {
        const float bv = bias[col];
        #pragma unroll
        for (int r = 0; r < 4; ++r) {
            int row = r0 + hi * 4 + r;
            stcohf(&z[(size_t)row * N + col], acc[r] + bv);
        }
    }
}

// ---------------------------------------------------------------------------
// Batched block reduction (r13-proven; order identical to r5-r13).
// ---------------------------------------------------------------------------
template <int NV>
__device__ __forceinline__ void blockSumN(float* v, float* red) {
    const int w = threadIdx.x >> 6, lane = threadIdx.x & 63;
    #pragma unroll
    for (int k = 0; k < NV; ++k) {
        float x = v[k];
        #pragma unroll
        for (int off = 32; off > 0; off >>= 1) x += __shfl_down(x, off, 64);
        v[k] = x;
    }
    __syncthreads();
    if (lane == 0) {
        #pragma unroll
        for (int k = 0; k < NV; ++k) red[k * 8 + w] = v[k];
    }
    __syncthreads();
    #pragma unroll
    for (int k = 0; k < NV; ++k) {
        float r = 0.f;
        #pragma unroll
        for (int j = 0; j < 8; ++j) r += red[k * 8 + j];
        v[k] = r;
    }
    __syncthreads();
}

// ---------------------------------------------------------------------------
// Pointwise phase (r13 math; all stores write-through coherent).
// ---------------------------------------------------------------------------
template <int FF>
__device__ void pw_phase(const float* __restrict__ z,
    const float* __restrict__ gg, const float* __restrict__ bg,
    const float* __restrict__ gc, const float* __restrict__ bc,
    float* __restrict__ h, float* __restrict__ c,
    u16* __restrict__ hpH, u16* __restrict__ hpM, u16* __restrict__ hpL,
    int hstride, u16* __restrict__ hist, int t, float* red)
{
    const int tid = threadIdx.x;
    constexpr int NU = (FF + TPB_ - 1) / TPB_;
    for (int b = blockIdx.x; b < B_; b += G_) {
        const float* zr = z + (size_t)b * 4 * FF;
        float* hr = h + (size_t)b * FF;
        float* cr = c + (size_t)b * FF;

        float sv[8] = {0, 0, 0, 0, 0, 0, 0, 0};
        #pragma unroll
        for (int i = 0; i < NU; ++i) {
            int u = tid + i * TPB_;
            if (u < FF) {
                #pragma unroll
                for (int g = 0; g < 4; ++g) {
                    float v = NTL(&zr[g * FF + u]);
                    sv[g] += v; sv[4 + g] += v * v;
                }
            }
        }
        blockSumN<8>(sv, red);
        float mu[4], rs[4];
        #pragma unroll
        for (int g = 0; g < 4; ++g) {
            mu[g] = sv[g] / FF;
            rs[g] = rsqrtf(sv[4 + g] / FF - mu[g] * mu[g] + 1e-5f);
        }

        float nc[NU], og[NU], ho[NU], co[NU];
        float cv[2] = {0, 0};
        #pragma unroll
        for (int i = 0; i < NU; ++i) {
            int u = tid + i * TPB_;
            if (u < FF) {
                float zi = (NTL(&zr[u])          - mu[0]) * rs[0] * gg[u]          + bg[u];
                float zj = (NTL(&zr[FF + u])     - mu[1]) * rs[1] * gg[FF + u]     + bg[FF + u];
                float zf = (NTL(&zr[2 * FF + u]) - mu[2]) * rs[2] * gg[2 * FF + u] + bg[2 * FF + u];
                float zo = (NTL(&zr[3 * FF + u]) - mu[3]) * rs[3] * gg[3 * FF + u] + bg[3 * FF + u];
                float cold = cr[u];
                float ncv = cold * sigm(zf + 1.0f) + sigm(zi) * tanhf(zj);
                nc[i] = ncv; og[i] = sigm(zo); co[i] = cold; ho[i] = hr[u];
                cv[0] += ncv; cv[1] += ncv * ncv;
            } else { nc[i] = 0.f; og[i] = 0.f; co[i] = 0.f; ho[i] = 0.f; }
        }
        blockSumN<2>(cv, red);
        float muc = cv[0] / FF;
        float rsc = rsqrtf(cv[1] / FF - muc * muc + 1e-5f);

        #pragma unroll
        for (int i = 0; i < NU; ++i) {
            int u = tid + i * TPB_;
            if (u < FF) {
                float nh = tanhf((nc[i] - muc) * rsc * gc[u] + bc[u]) * og[i];
                float hout = 0.9f * nh + 0.1f * ho[i];
                float cout = 0.5f * nc[i] + 0.5f * co[i];
                stcohf(&hr[u], hout);
                stcohf(&cr[u], cout);
                u16 H, M, L;
                split3f(hout, H, M, L);
                size_t po = (size_t)b * hstride + u;
                stcohs(&hpH[po], H); stcohs(&hpM[po], M); stcohs(&hpL[po], L);
                if (hist) stcohs(&hist[((size_t)b * T_ + t) * FP_ + u], H);
            }
        }
        if (hist && tid < FP_ - FF)
            stcohs(&hist[((size_t)b * T_ + t) * FP_ + FF + tid], (u16)0);
    }
}

// ---------------------------------------------------------------------------
// Mega: LDS-fill -> 100 x (GEMM0|PW0|GEMMS|PWS|GEMM1|PW1) -> tail.
// States/planes/hist pre-zeroed by host memsets (kernel-launch acquire).
// ---------------------------------------------------------------------------
__global__ __launch_bounds__(TPB_) void mega(
    const float* __restrict__ b0, const float* __restrict__ g0,
    const float* __restrict__ bg0, const float* __restrict__ gc0,
    const float* __restrict__ bc0,
    const float* __restrict__ b1, const float* __restrict__ g1,
    const float* __restrict__ bg1, const float* __restrict__ gc1,
    const float* __restrict__ bc1,
    const float* __restrict__ bS, const float* __restrict__ gS,
    const float* __restrict__ bgS, const float* __restrict__ gcS,
    const float* __restrict__ bcS,
    const float* __restrict__ zx,
    float* fh, float* fc, float* sh, float* sc, float* z, u16* hist,
    u16* fhH, u16* fhM, u16* fhL, u16* shH, u16* shM, u16* shL,
    u16* W0H, u16* W0M, u16* W0L, u16* WSH, u16* WSM, u16* WSL,
    u16* W1H, u16* W1M, u16* W1L,
    float* outTail, unsigned* flags, unsigned* go)
{
    extern __shared__ char lds[];
    __shared__ float red[64];
    const int b = blockIdx.x;
    const int gtid = blockIdx.x * TPB_ + threadIdx.x;
    unsigned tgt = 0;

    // one-time LDS weight fill (block-local; first gbar orders vs use anyway)
    if (b <= 174) {
        fill_tile(lds, W0H + 128, W0M + 128, 832, b * 16, 22);
        if (b <= 155) fill_tile(lds + W0_TILE_B, W1H, W1M, 1120, b * 16, 35);
        else          fill_tile(lds + W0_TILE_B, WSH, WSM, 1120, (b - 156) * 16, 35);
    } else {
        fill_tile(lds, WSH, WSM, 1120, (b - 156) * 16, 35);
        if (b <= 193)
            fill_tile(lds + KW_TILE_B, W1H, W1M, 1120, (156 + b - 175) * 16, 35);
    }
    __syncthreads();

    for (int t = 0; t < T_; ++t) {
        if (b <= 174)
            gemm_lds(lds, 22,
                     fhH, fhM, fhL, FP_, FP_, fhH, fhM, fhL, FP_,
                     W0L + 128, 832, b * 16,
                     nullptr, zx + (size_t)t * B_ * 2800, z, 2800);
        gbar(flags, go, ++tgt);
        pw_phase<F_>(z, g0, bg0, gc0, bc0, fh, fc, fhH, fhM, fhL, FP_, nullptr, 0, red);
        gbar(flags, go, ++tgt);
        if (b >= 156)
            gemm_lds(lds + (b <= 174 ? W0_TILE_B : 0), 35,
                     fhH, fhM, fhL, FP_, FP_, shH, shM, shL, SP_,
                     WSL, 1120, (b - 156) * 16,
                     bS, nullptr, z, 1600);
        gbar(flags, go, ++tgt);
        pw_phase<S_>(z, gS, bgS, gcS, bcS, sh, sc, shH, shM, shL, SP_, nullptr, 0, red);
        gbar(flags, go, ++tgt);
        if (b <= 155)
            gemm_lds(lds + W0_TILE_B, 35,
                     shH, shM, shL, SP_, SP_, fhH, fhM, fhL, FP_,
                     W1L, 1120, b * 16, b1, nullptr, z, 2800);
        else if (b >= 175 && b <= 193)
            gemm_lds(lds + KW_TILE_B, 35,
                     shH, shM, shL, SP_, SP_, fhH, fhM, fhL, FP_,
                     W1L, 1120, (156 + b - 175) * 16, b1, nullptr, z, 2800);
        gbar(flags, go, ++tgt);
        pw_phase<F_>(z, g1, bg1, gc1, bc1, fh, fc, fhH, fhM, fhL, FP_, hist, t, red);
        gbar(flags, go, ++tgt);
    }

    const int NF = B_ * F_, NS = B_ * S_;
    for (int i = gtid; i < 2 * NF + 2 * NS; i += G_ * TPB_) {
        float v = (i < NF) ? fh[i] : (i < 2 * NF) ? fc[i - NF]
                : (i < 2 * NF + NS) ? sh[i - 2 * NF] : sc[i - 2 * NF - NS];
        stcohf(&outTail[i], v);
    }
}

// ---------------------------------------------------------------------------
// Output projection (r5-proven).
// ---------------------------------------------------------------------------
__global__ __launch_bounds__(512) void ogemm(
    const u16* __restrict__ A, const u16* __restrict__ Bt,
    const float* __restrict__ bias, float* __restrict__ C)
{
    const int N = V_;
    const int tid = threadIdx.x, lane = tid & 63, wid = tid >> 6;
    const int wm = wid >> 1, wn = wid & 1;
    const int row0 = blockIdx.y * 256 + wm * 64;
    const int col0 = blockIdx.x * 128 + wn * 64;
    const int lo = lane & 15, hi = lane >> 4;
    const int NT = FP_ / 32;

    v4f acc[4][4];
    #pragma unroll
    for (int i = 0; i < 4; ++i)
        #pragma unroll
        for (int j = 0; j < 4; ++j) acc[i][j] = (v4f)0.f;

    for (int kt = 0; kt < NT; ++kt) {
        const int kb = kt * 32 + hi * 8;
        v8s a[4], bfr[4];
        #pragma unroll
        for (int i = 0; i < 4; ++i) {
            a[i]   = *(const v8s*)(A  + (size_t)(row0 + i * 16 + lo) * FP_ + kb);
            bfr[i] = *(const v8s*)(Bt + (size_t)(col0 + i * 16 + lo) * FP_ + kb);
        }
        #pragma unroll
        for (int mf = 0; mf < 4; ++mf)
            #pragma unroll
            for (int nf = 0; nf < 4; ++nf)
                acc[mf][nf] = __builtin_amdgcn_mfma_f32_16x16x32_bf16(a[mf], bfr[nf], acc[mf][nf], 0, 0, 0);
    }

    #pragma unroll
    for (int mf = 0; mf < 4; ++mf) {
        #pragma unroll
        for (int nf = 0; nf < 4; ++nf) {
            int col = col0 + nf * 16 + lo;
            if (col < N) {
                float bb = bias[col];
                #pragma unroll
                for (int r = 0; r < 4; ++r) {
                    int row = row0 + mf * 16 + hi * 4 + r;
                    C[(size_t)row * N + col] = acc[mf][nf][r] + bb;
                }
            }
        }
    }
}

extern "C" void kernel_launch(void* const* d_in, const int* in_sizes, int n_in,
                              void* d_out, int out_size, void* d_ws, size_t ws_size,
                              hipStream_t stream) {
    const float* inputs = (const float*)d_in[0];
    const float* W0   = (const float*)d_in[1];
    const float* b0   = (const float*)d_in[2];
    const float* g0   = (const float*)d_in[3];
    const float* bg0  = (const float*)d_in[4];
    const float* gc0  = (const float*)d_in[5];
    const float* bc0  = (const float*)d_in[6];
    const float* W1   = (const float*)d_in[7];
    const float* b1   = (const float*)d_in[8];
    const float* g1   = (const float*)d_in[9];
    const float* bg1  = (const float*)d_in[10];
    const float* gc1  = (const float*)d_in[11];
    const float* bc1  = (const float*)d_in[12];
    const float* WS   = (const float*)d_in[13];
    const float* bS   = (const float*)d_in[14];
    const float* gS   = (const float*)d_in[15];
    const float* bgS  = (const float*)d_in[16];
    const float* gcS  = (const float*)d_in[17];
    const float* bcS  = (const float*)d_in[18];
    const float* Wout = (const float*)d_in[19];
    const float* bout = (const float*)d_in[20];

    // ---- ws: states + z + hist + Wtout + flags/go (~34.9 MB, known-safe)
    float* ws = (float*)d_ws;
    float* fh = ws;
    float* fc = fh + B_ * F_;
    float* sh = fc + B_ * F_;
    float* sc = sh + B_ * S_;
    float* z  = sc + B_ * S_;
    u16* hist = (u16*)(z + (size_t)B_ * 4 * F_);
    u16* Wtout = hist + (size_t)12800 * FP_;
    unsigned* flags = (unsigned*)(Wtout + (size_t)10112 * FP_);
    unsigned* go    = flags + G_ * 16;

    // ---- d_out scratch (fully rewritten every call; dead before ogemm)
    const size_t P0 = (size_t)2816 * 832;
    const size_t PS = (size_t)1664 * 1120;
    const size_t P1 = (size_t)2816 * 1120;
    const size_t HF = (size_t)B_ * FP_;
    const size_t HS = (size_t)B_ * SP_;
    u16* dp  = (u16*)d_out;
    u16* W0H = dp;          u16* W0M = W0H + P0;  u16* W0L = W0M + P0;
    u16* WSH = W0L + P0;    u16* WSM = WSH + PS;  u16* WSL = WSM + PS;
    u16* W1H = WSL + PS;    u16* W1M = W1H + P1;  u16* W1L = W1M + P1;
    u16* fhH = W1L + P1;    u16* fhM = fhH + HF;  u16* fhL = fhM + HF;
    u16* shH = fhL + HF;    u16* shM = shH + HS;  u16* shL = shM + HS;
    float* zx = (float*)(shL + HS);

    hipMemsetAsync(flags, 0, (G_ * 16 + 16) * sizeof(unsigned), stream);
    // zero f32 states (fh..sc contiguous) and h/s bf16 planes (fhH..shL)
    hipMemsetAsync(fh, 0, (size_t)(2 * B_ * F_ + 2 * B_ * S_) * sizeof(float), stream);
    hipMemsetAsync(fhH, 0, (3 * HF + 3 * HS) * sizeof(u16), stream);

    wtrans3<<<dim3(88, 26), 256, 0, stream>>>(W0, E_ + F_, 4 * F_, W0H, W0M, W0L, 832, 128, 128);
    wtrans3<<<dim3(52, 35), 256, 0, stream>>>(WS, F_ + S_, 4 * S_, WSH, WSM, WSL, 1120, F_, FP_);
    wtrans3<<<dim3(88, 35), 256, 0, stream>>>(W1, S_ + F_, 4 * F_, W1H, W1M, W1L, 1120, S_, SP_);
    wtrans<<<dim3(316, 22), 256, 0, stream>>>(Wout, F_, V_, Wtout, FP_);

    zxpre<<<2188, 512, 0, stream>>>(inputs, W0H, W0M, W0L, b0, zx);

    hipFuncSetAttribute((const void*)mega,
                        hipFuncAttributeMaxDynamicSharedMemorySize, LDS_BYTES);

    mega<<<G_, TPB_, LDS_BYTES, stream>>>(
        b0, g0, bg0, gc0, bc0,
        b1, g1, bg1, gc1, bc1,
        bS, gS, bgS, gcS, bcS,
        zx,
        fh, fc, sh, sc, z, hist,
        fhH, fhM, fhL, shH, shM, shL,
        W0H, W0M, W0L, WSH, WSM, WSL, W1H, W1M, W1L,
        (float*)d_out + (size_t)B_ * T_ * V_, flags, go);

    ogemm<<<dim3(79, 50), 512, 0, stream>>>(hist, Wtout, bout, (float*)d_out);
}